// Round 9
// baseline (277.507 us; speedup 1.0000x reference)
//
#include <hip/hip_runtime.h>
#include <hip/hip_bf16.h>
#include <cstddef>
#include <math.h>

// ---------------------------------------------------------------------------
// Model constants
// ---------------------------------------------------------------------------
#define S_LEN 1024
#define D_DIM 128
#define H_HEADS 8
#define FF_DIM 2048
#define L_LAYERS 4
#define HID_DIM 768
#define LN_EPS 1e-5f

#define FF2_KS 4      // FF2 split-K chunks

typedef __attribute__((ext_vector_type(8))) short bf16x8;
typedef __attribute__((ext_vector_type(4))) float f32x4;

// ---------------------------------------------------------------------------
// Wave-level MFMA tile: 16 rows x (NT*16) cols (proven fragment layout).
// ---------------------------------------------------------------------------
template<int NT>
__device__ __forceinline__ void mfma_tile(
    const __hip_bfloat16* __restrict__ A, const __hip_bfloat16* __restrict__ W,
    int K, int m0, int n0, int kbeg, int kend, int lane, f32x4* acc)
{
    const int lr = lane & 15;
    const int lk = (lane >> 4) * 8;
    const __hip_bfloat16* Ap = A + (size_t)(m0 + lr) * K + lk;
    const __hip_bfloat16* Wp = W + (size_t)(n0 + lr) * K + lk;
    #pragma unroll 4
    for (int k = kbeg; k < kend; k += 32) {
        const bf16x8 a = *reinterpret_cast<const bf16x8*>(Ap + k);
        #pragma unroll
        for (int nt = 0; nt < NT; ++nt) {
            const bf16x8 b = *reinterpret_cast<const bf16x8*>(Wp + (size_t)nt * 16 * K + k);
            acc[nt] = __builtin_amdgcn_mfma_f32_16x16x32_bf16(a, b, acc[nt], 0, 0, 0);
        }
    }
}

// ---------------------------------------------------------------------------
// One-shot weight conversion fp32 -> bf16 (concatenated, proven).
// ---------------------------------------------------------------------------
__global__ __launch_bounds__(256) void wconv_kernel(
    const float* __restrict__ Wqkv, const float* __restrict__ Wo,
    const float* __restrict__ W1, const float* __restrict__ W2,
    const float* __restrict__ Wout, __hip_bfloat16* __restrict__ dst)
{
    const int i = blockIdx.x * 256 + threadIdx.x;   // float4 index, 0..614399
    const float* src;
    int off4;
    if (i < 49152)       { src = Wqkv; off4 = i; }
    else if (i < 65536)  { src = Wo;   off4 = i - 49152; }
    else if (i < 327680) { src = W1;   off4 = i - 65536; }
    else if (i < 589824) { src = W2;   off4 = i - 327680; }
    else                 { src = Wout; off4 = i - 589824; }
    const float4 v = reinterpret_cast<const float4*>(src)[off4];
    __hip_bfloat16* o = dst + (size_t)i * 4;
    o[0] = __float2bfloat16(v.x);
    o[1] = __float2bfloat16(v.y);
    o[2] = __float2bfloat16(v.z);
    o[3] = __float2bfloat16(v.w);
}

// ---------------------------------------------------------------------------
// embed + layer-0 QKV, fused (proven). 64 blocks x 1024 thr.
// ---------------------------------------------------------------------------
__global__ __launch_bounds__(1024, 1) void embed_qkv_kernel(
    const int* __restrict__ shot, const int* __restrict__ cam,
    const int* __restrict__ light, const int* __restrict__ tone,
    const int* __restrict__ rhythm, const int* __restrict__ trans,
    const float* __restrict__ motion, const float* __restrict__ focus,
    const float* __restrict__ E_shot, const float* __restrict__ E_cam,
    const float* __restrict__ E_light, const float* __restrict__ E_tone,
    const float* __restrict__ E_rhythm, const float* __restrict__ E_trans,
    const float* __restrict__ W_m1, const float* __restrict__ b_m1,
    const float* __restrict__ W_m2, const float* __restrict__ b_m2,
    const float* __restrict__ W_f, const float* __restrict__ b_f,
    const float* __restrict__ pos,
    const __hip_bfloat16* __restrict__ Wqkv0, const float* __restrict__ bqkv0,
    float* __restrict__ x, __hip_bfloat16* __restrict__ x_bf,
    __hip_bfloat16* __restrict__ qkv_bf)
{
    const int blk = blockIdx.x;
    const int tid = threadIdx.x;
    const int m0  = blk * 16;

    for (int e = tid; e < 16 * D_DIM; e += 1024) {
        const int s = m0 + (e >> 7);
        const int d = e & 127;
        const float4 mp = *reinterpret_cast<const float4*>(motion + s * 4);
        const float f0 = focus[s * 2 + 0], f1 = focus[s * 2 + 1];
        float acc = b_m2[d];
        const float* w2row = W_m2 + (size_t)d * 64;
        #pragma unroll 8
        for (int k2 = 0; k2 < 64; ++k2) {
            const float hk = b_m1[k2]
                + W_m1[k2 * 4 + 0] * mp.x + W_m1[k2 * 4 + 1] * mp.y
                + W_m1[k2 * 4 + 2] * mp.z + W_m1[k2 * 4 + 3] * mp.w;
            acc += w2row[k2] * fmaxf(hk, 0.0f);
        }
        acc += b_f[d] + W_f[d * 2 + 0] * f0 + W_f[d * 2 + 1] * f1;
        acc += E_shot  [(size_t)shot[s]   * D_DIM + d];
        acc += E_cam   [(size_t)cam[s]    * D_DIM + d];
        acc += E_light [(size_t)light[s]  * D_DIM + d];
        acc += E_tone  [(size_t)tone[s]   * D_DIM + d];
        acc += E_rhythm[(size_t)rhythm[s] * D_DIM + d];
        acc += E_trans [(size_t)trans[s]  * D_DIM + d];
        acc += pos[(size_t)s * D_DIM + d];
        const size_t gi = (size_t)s * D_DIM + d;
        x[gi] = acc;
        x_bf[gi] = __float2bfloat16(acc);
    }
    __syncthreads();

    const int wave = tid >> 6, lane = tid & 63;
    for (int u = wave; u < 12; u += 16) {
        const int n0 = u * 32;
        f32x4 acc[2] = {};
        mfma_tile<2>(x_bf, Wqkv0, 128, m0, n0, 0, 128, lane, acc);
        const int orow = m0 + (lane >> 4) * 4;
        #pragma unroll
        for (int h = 0; h < 2; ++h) {
            const int col = n0 + h * 16 + (lane & 15);
            const float bv = bqkv0[col];
            #pragma unroll
            for (int j = 0; j < 4; ++j)
                qkv_bf[(size_t)(orow + j) * 384 + col] =
                    __float2bfloat16(acc[h][j] + bv);
        }
    }
}

// ---------------------------------------------------------------------------
// Fused one-pass attention. grid (32 qblocks, 8 heads) = 256 blk x 256 thr.
// 8 lanes per q-row; lane c owns keys == c (mod 8); online softmax per lane;
// 3-round shfl_xor merge of the 8 lane-partials at the end.
// K/V staged per 256-key sub-chunk as f32, row pad 20 (16B-aligned; the 8
// chunk-lanes hit 8 distinct banks; same-chunk rows broadcast).
// ---------------------------------------------------------------------------
__global__ __launch_bounds__(256) void attn_kernel(
    const __hip_bfloat16* __restrict__ qkv, __hip_bfloat16* __restrict__ o)
{
    __shared__ float Ks[256 * 20];
    __shared__ float Vs[256 * 20];

    const int t    = threadIdx.x;
    const int qb   = blockIdx.x;
    const int head = blockIdx.y;
    const int row  = qb * 32 + (t >> 3);
    const int c    = t & 7;

    float q[16];
    {
        const __hip_bfloat16* qp = qkv + (size_t)row * 384 + head * 16;
        #pragma unroll
        for (int d = 0; d < 16; ++d)
            q[d] = __bfloat162float(qp[d]) * 0.25f;
    }

    float m = -INFINITY, l = 0.f;
    float O[16];
    #pragma unroll
    for (int d = 0; d < 16; ++d) O[d] = 0.f;

    for (int sc = 0; sc < 4; ++sc) {
        const int kb = sc * 256;
        __syncthreads();                       // LDS reuse guard
        for (int e = t; e < 256 * 16; e += 256) {
            const int kk = e >> 4, d = e & 15;
            const __hip_bfloat16* src = qkv + (size_t)(kb + kk) * 384 + head * 16 + d;
            Ks[kk * 20 + d] = __bfloat162float(src[128]);
            Vs[kk * 20 + d] = __bfloat162float(src[256]);
        }
        __syncthreads();

        for (int j0 = 0; j0 < 32; j0 += 8) {
            float sv[8];
            #pragma unroll
            for (int jj = 0; jj < 8; ++jj) {
                const float* kr = &Ks[(c + (j0 + jj) * 8) * 20];
                float a = 0.f;
                #pragma unroll
                for (int d = 0; d < 16; d += 4) {
                    const float4 kv4 = *reinterpret_cast<const float4*>(kr + d);
                    a += q[d] * kv4.x + q[d + 1] * kv4.y
                       + q[d + 2] * kv4.z + q[d + 3] * kv4.w;
                }
                sv[jj] = a;
            }
            float bm = sv[0];
            #pragma unroll
            for (int jj = 1; jj < 8; ++jj) bm = fmaxf(bm, sv[jj]);
            const float mn = fmaxf(m, bm);
            const float corr = __expf(m - mn);
            m = mn;
            l *= corr;
            #pragma unroll
            for (int d = 0; d < 16; ++d) O[d] *= corr;
            #pragma unroll
            for (int jj = 0; jj < 8; ++jj) {
                const float p = __expf(sv[jj] - m);
                l += p;
                const float* vr = &Vs[(c + (j0 + jj) * 8) * 20];
                #pragma unroll
                for (int d = 0; d < 16; d += 4) {
                    const float4 vv = *reinterpret_cast<const float4*>(vr + d);
                    O[d]     += p * vv.x;
                    O[d + 1] += p * vv.y;
                    O[d + 2] += p * vv.z;
                    O[d + 3] += p * vv.w;
                }
            }
        }
    }

    // merge the 8 chunk-lane partials (chunk bits = lane bits 0..2)
    #pragma unroll
    for (int off = 1; off <= 4; off <<= 1) {
        const float m2 = __shfl_xor(m, off);
        const float l2 = __shfl_xor(l, off);
        const float mn = fmaxf(m, m2);
        const float ca = __expf(m - mn);
        const float cb = __expf(m2 - mn);
        #pragma unroll
        for (int d = 0; d < 16; ++d)
            O[d] = O[d] * ca + __shfl_xor(O[d], off) * cb;
        l = l * ca + l2 * cb;
        m = mn;
    }

    const float inv = 1.f / l;
    __hip_bfloat16* op = o + (size_t)row * D_DIM + head * 16 + 2 * c;
    op[0] = __float2bfloat16(O[2 * c] * inv);
    op[1] = __float2bfloat16(O[2 * c + 1] * inv);
}

// ---------------------------------------------------------------------------
// Wo + residual + LN1 fused (proven R8). 64 blocks x 512 thr.
// ---------------------------------------------------------------------------
__global__ __launch_bounds__(512) void wo_ln1_kernel(
    const __hip_bfloat16* __restrict__ attn_bf,
    const __hip_bfloat16* __restrict__ Wo_i, const float* __restrict__ bo_i,
    float* __restrict__ x, __hip_bfloat16* __restrict__ x_bf,
    const float* __restrict__ g, const float* __restrict__ b)
{
    __shared__ float lds_wo[16][132];

    const int blk  = blockIdx.x;
    const int tid  = threadIdx.x;
    const int wave = tid >> 6;
    const int lane = tid & 63;
    const int m0   = blk * 16;

    {
        f32x4 acc[1] = {};
        mfma_tile<1>(attn_bf, Wo_i, 128, m0, wave * 16, 0, 128, lane, acc);
        const int orow = (lane >> 4) * 4;
        const int col  = wave * 16 + (lane & 15);
        #pragma unroll
        for (int j = 0; j < 4; ++j)
            lds_wo[orow + j][col] = acc[0][j];
    }
    __syncthreads();

    #pragma unroll
    for (int rr = 0; rr < 2; ++rr) {
        const int rloc = wave + rr * 8;
        const int d0 = lane * 2;
        const size_t i0 = (size_t)(m0 + rloc) * D_DIM + d0;
        float v0 = x[i0]     + lds_wo[rloc][d0]     + bo_i[d0];
        float v1 = x[i0 + 1] + lds_wo[rloc][d0 + 1] + bo_i[d0 + 1];
        float s = v0 + v1;
        #pragma unroll
        for (int off = 32; off >= 1; off >>= 1) s += __shfl_xor(s, off);
        const float mu = s * (1.0f / 128.0f);
        const float q0 = v0 - mu, q1 = v1 - mu;
        float qs = q0 * q0 + q1 * q1;
        #pragma unroll
        for (int off = 32; off >= 1; off >>= 1) qs += __shfl_xor(qs, off);
        const float rs = rsqrtf(qs * (1.0f / 128.0f) + LN_EPS);
        const float r0 = q0 * rs * g[d0] + b[d0];
        const float r1 = q1 * rs * g[d0 + 1] + b[d0 + 1];
        x[i0] = r0;     x[i0 + 1] = r1;
        x_bf[i0] = __float2bfloat16(r0);
        x_bf[i0 + 1] = __float2bfloat16(r1);
    }
}

// ---------------------------------------------------------------------------
// FF1 (proven): 32x64 tile, 4 waves 2x2. grid (32, 32) = 1024 blocks.
// ---------------------------------------------------------------------------
__global__ __launch_bounds__(256) void ff1_kernel(
    const __hip_bfloat16* __restrict__ A, const __hip_bfloat16* __restrict__ W,
    const float* __restrict__ bias, __hip_bfloat16* __restrict__ C)
{
    const int t = threadIdx.x;
    const int w  = t >> 6;
    const int l  = t & 63;
    const int m0 = blockIdx.y * 32 + (w & 1) * 16;
    const int n0 = blockIdx.x * 64 + (w >> 1) * 32;

    f32x4 acc[2] = {};
    mfma_tile<2>(A, W, 128, m0, n0, 0, 128, l, acc);

    const int orow = m0 + (l >> 4) * 4;
    #pragma unroll
    for (int nt = 0; nt < 2; ++nt) {
        const int col = n0 + nt * 16 + (l & 15);
        const float bv = bias[col];
        #pragma unroll
        for (int j = 0; j < 4; ++j)
            C[(size_t)(orow + j) * FF_DIM + col] =
                __float2bfloat16(fmaxf(acc[nt][j] + bv, 0.f));
    }
}

// ---------------------------------------------------------------------------
// FF2 split-K partials: KC=512 compile-time. grid (2, 32, 4) = 256 blocks.
// ---------------------------------------------------------------------------
template<int KC>
__global__ __launch_bounds__(256) void ff2_sk_kernel(
    const __hip_bfloat16* __restrict__ A, const __hip_bfloat16* __restrict__ W,
    float* __restrict__ P)
{
    const int t = threadIdx.x;
    const int w  = t >> 6;
    const int l  = t & 63;
    const int lr = l & 15;
    const int lk = (l >> 4) * 8;
    const int m0 = blockIdx.y * 32 + (w & 1) * 16;
    const int n0 = blockIdx.x * 64 + (w >> 1) * 32;
    const int kbeg = blockIdx.z * KC;

    f32x4 acc[2] = {};
    const __hip_bfloat16* Ap = A + (size_t)(m0 + lr) * FF_DIM + lk + kbeg;
    const __hip_bfloat16* Wp = W + (size_t)(n0 + lr) * FF_DIM + lk + kbeg;
    #pragma unroll 4
    for (int k = 0; k < KC; k += 32) {
        const bf16x8 a = *reinterpret_cast<const bf16x8*>(Ap + k);
        #pragma unroll
        for (int nt = 0; nt < 2; ++nt) {
            const bf16x8 bb = *reinterpret_cast<const bf16x8*>(Wp + (size_t)nt * 16 * FF_DIM + k);
            acc[nt] = __builtin_amdgcn_mfma_f32_16x16x32_bf16(a, bb, acc[nt], 0, 0, 0);
        }
    }

    float* Pz = P + (size_t)blockIdx.z * (S_LEN * D_DIM);
    const int orow = m0 + (l >> 4) * 4;
    #pragma unroll
    for (int nt = 0; nt < 2; ++nt) {
        const int col = n0 + nt * 16 + (l & 15);
        #pragma unroll
        for (int j = 0; j < 4; ++j)
            Pz[(size_t)(orow + j) * D_DIM + col] = acc[nt][j];
    }
}

// ---------------------------------------------------------------------------
// LN2 (+FF2_KS partials + bias) then next-layer QKV (or out-proj if LAST).
// 64 blocks x 512 thr (proven R8 structure).
// ---------------------------------------------------------------------------
template<int LAST>
__global__ __launch_bounds__(512) void ln2_qkv_kernel(
    const float* __restrict__ P, const float* __restrict__ b2_i,
    float* __restrict__ x, __hip_bfloat16* __restrict__ x_bf,
    const float* __restrict__ g, const float* __restrict__ b,
    const __hip_bfloat16* __restrict__ Wn, const float* __restrict__ bn,
    __hip_bfloat16* __restrict__ qkv_bf, float* __restrict__ out)
{
    const int blk  = blockIdx.x;
    const int tid  = threadIdx.x;
    const int wave = tid >> 6;
    const int lane = tid & 63;
    const int m0   = blk * 16;

    #pragma unroll
    for (int rr = 0; rr < 2; ++rr) {
        const int rloc = wave + rr * 8;
        const int d0 = lane * 2;
        const size_t i0 = (size_t)(m0 + rloc) * D_DIM + d0;
        float v0 = x[i0]     + b2_i[d0];
        float v1 = x[i0 + 1] + b2_i[d0 + 1];
        #pragma unroll
        for (int p = 0; p < FF2_KS; ++p) {
            v0 += P[(size_t)p * (S_LEN * D_DIM) + i0];
            v1 += P[(size_t)p * (S_LEN * D_DIM) + i0 + 1];
        }
        float s = v0 + v1;
        #pragma unroll
        for (int off = 32; off >= 1; off >>= 1) s += __shfl_xor(s, off);
        const float mu = s * (1.0f / 128.0f);
        const float q0 = v0 - mu, q1 = v1 - mu;
        float qs = q0 * q0 + q1 * q1;
        #pragma unroll
        for (int off = 32; off >= 1; off >>= 1) qs += __shfl_xor(qs, off);
        const float rs = rsqrtf(qs * (1.0f / 128.0f) + LN_EPS);
        const float r0 = q0 * rs * g[d0] + b[d0];
        const float r1 = q1 * rs * g[d0 + 1] + b[d0 + 1];
        x[i0] = r0;     x[i0 + 1] = r1;
        x_bf[i0] = __float2bfloat16(r0);
        x_bf[i0 + 1] = __float2bfloat16(r1);
    }
    __syncthreads();

    if (!LAST) {
        for (int u = wave; u < 12; u += 8) {
            const int n0 = u * 32;
            f32x4 acc[2] = {};
            mfma_tile<2>(x_bf, Wn, 128, m0, n0, 0, 128, lane, acc);
            const int orow = m0 + (lane >> 4) * 4;
            #pragma unroll
            for (int h = 0; h < 2; ++h) {
                const int col = n0 + h * 16 + (lane & 15);
                const float bv = bn[col];
                #pragma unroll
                for (int j = 0; j < 4; ++j)
                    qkv_bf[(size_t)(orow + j) * 384 + col] =
                        __float2bfloat16(acc[h][j] + bv);
            }
        }
    } else {
        for (int u = wave; u < 24; u += 8) {
            const int n0 = u * 32;
            f32x4 acc[2] = {};
            mfma_tile<2>(x_bf, Wn, 128, m0, n0, 0, 128, lane, acc);
            const int orow = m0 + (lane >> 4) * 4;
            #pragma unroll
            for (int h = 0; h < 2; ++h) {
                const int col = n0 + h * 16 + (lane & 15);
                const float bv = bn[col];
                #pragma unroll
                for (int j = 0; j < 4; ++j)
                    out[(size_t)(orow + j) * HID_DIM + col] = acc[h][j] + bv;
            }
        }
        if (tid < 16)
            out[(size_t)S_LEN * HID_DIM + m0 + tid] = 0.0f;
    }
}

// ---------------------------------------------------------------------------
// Host launch: 22 dispatches.
// ---------------------------------------------------------------------------
extern "C" void kernel_launch(void* const* d_in, const int* in_sizes, int n_in,
                              void* d_out, int out_size, void* d_ws, size_t ws_size,
                              hipStream_t stream)
{
    const int*   shot    = (const int*)  d_in[0];
    const int*   cam     = (const int*)  d_in[1];
    const int*   light   = (const int*)  d_in[2];
    const int*   tone    = (const int*)  d_in[3];
    const int*   rhythm  = (const int*)  d_in[4];
    const int*   trans   = (const int*)  d_in[5];
    const float* motion  = (const float*)d_in[6];
    const float* focus   = (const float*)d_in[7];
    const float* E_shot  = (const float*)d_in[8];
    const float* E_cam   = (const float*)d_in[9];
    const float* E_light = (const float*)d_in[10];
    const float* E_tone  = (const float*)d_in[11];
    const float* E_rhyth = (const float*)d_in[12];
    const float* E_trans = (const float*)d_in[13];
    const float* W_m1    = (const float*)d_in[14];
    const float* b_m1    = (const float*)d_in[15];
    const float* W_m2    = (const float*)d_in[16];
    const float* b_m2    = (const float*)d_in[17];
    const float* W_f     = (const float*)d_in[18];
    const float* b_f     = (const float*)d_in[19];
    const float* pos     = (const float*)d_in[20];
    const float* Wqkv    = (const float*)d_in[21];
    const float* bqkv    = (const float*)d_in[22];
    const float* Wo      = (const float*)d_in[23];
    const float* bo      = (const float*)d_in[24];
    const float* W1      = (const float*)d_in[25];
    const float* b1      = (const float*)d_in[26];
    const float* W2      = (const float*)d_in[27];
    const float* b2      = (const float*)d_in[28];
    const float* ln1_g   = (const float*)d_in[29];
    const float* ln1_b   = (const float*)d_in[30];
    const float* ln2_g   = (const float*)d_in[31];
    const float* ln2_b   = (const float*)d_in[32];
    const float* W_out   = (const float*)d_in[33];
    const float* b_out   = (const float*)d_in[34];

    float* out = (float*)d_out;

    // workspace layout
    float* ws = (float*)d_ws;
    float* x  = ws;                                 // 131072 f32
    float* P  = x + S_LEN * D_DIM;                  // 4*131072 (FF2 partials)
    __hip_bfloat16* bfb = (__hip_bfloat16*)(P + FF2_KS * S_LEN * D_DIM);
    __hip_bfloat16* wqkv_bf = bfb;                  // [4][384][128]
    __hip_bfloat16* wo_bf   = wqkv_bf + 196608;     // [4][128][128]
    __hip_bfloat16* w1_bf   = wo_bf   + 65536;      // [4][2048][128]
    __hip_bfloat16* w2_bf   = w1_bf   + 1048576;    // [4][128][2048]
    __hip_bfloat16* wout_bf = w2_bf   + 1048576;    // [768][128]
    __hip_bfloat16* x_bf    = wout_bf + 98304;      // [1024][128]
    __hip_bfloat16* qkv_bf  = x_bf    + 131072;     // [1024][384]
    __hip_bfloat16* attn_bf = qkv_bf  + 393216;     // [1024][128]
    __hip_bfloat16* hbuf_bf = attn_bf + 131072;     // [1024][2048]

    // 1) weights -> bf16
    wconv_kernel<<<2400, 256, 0, stream>>>(Wqkv, Wo, W1, W2, W_out, bfb);

    // 2) embed + layer-0 qkv
    embed_qkv_kernel<<<64, 1024, 0, stream>>>(
        shot, cam, light, tone, rhythm, trans, motion, focus,
        E_shot, E_cam, E_light, E_tone, E_rhyth, E_trans,
        W_m1, b_m1, W_m2, b_m2, W_f, b_f, pos,
        wqkv_bf, bqkv, x, x_bf, qkv_bf);

    // 3) layers: 5 dispatches each
    for (int li = 0; li < L_LAYERS; ++li) {
        const __hip_bfloat16* Wo_i = wo_bf + (size_t)li * D_DIM * D_DIM;
        const __hip_bfloat16* W1_i = w1_bf + (size_t)li * FF_DIM * D_DIM;
        const __hip_bfloat16* W2_i = w2_bf + (size_t)li * D_DIM * FF_DIM;
        const float* bo_i = bo + (size_t)li * D_DIM;
        const float* b1_i = b1 + (size_t)li * FF_DIM;
        const float* b2_i = b2 + (size_t)li * D_DIM;
        const float* l1g = ln1_g + (size_t)li * D_DIM;
        const float* l1b = ln1_b + (size_t)li * D_DIM;
        const float* l2g = ln2_g + (size_t)li * D_DIM;
        const float* l2b = ln2_b + (size_t)li * D_DIM;

        attn_kernel<<<dim3(32, H_HEADS), 256, 0, stream>>>(qkv_bf, attn_bf);

        wo_ln1_kernel<<<64, 512, 0, stream>>>(
            attn_bf, Wo_i, bo_i, x, x_bf, l1g, l1b);

        ff1_kernel<<<dim3(FF_DIM / 64, S_LEN / 32), 256, 0, stream>>>(
            x_bf, W1_i, b1_i, hbuf_bf);

        ff2_sk_kernel<512><<<dim3(D_DIM / 64, S_LEN / 32, FF2_KS), 256, 0, stream>>>(
            hbuf_bf, W2_i, P);

        if (li < L_LAYERS - 1) {
            const __hip_bfloat16* Wn = wqkv_bf + (size_t)(li + 1) * 3 * D_DIM * D_DIM;
            const float* bn = bqkv + (size_t)(li + 1) * 3 * D_DIM;
            ln2_qkv_kernel<0><<<64, 512, 0, stream>>>(
                P, b2_i, x, x_bf, l2g, l2b, Wn, bn, qkv_bf, nullptr);
        } else {
            ln2_qkv_kernel<1><<<64, 512, 0, stream>>>(
                P, b2_i, x, x_bf, l2g, l2b, wout_bf, b_out, nullptr, out);
        }
    }
}

// Round 10
// 246.870 us; speedup vs baseline: 1.1241x; 1.1241x over previous
//
#include <hip/hip_runtime.h>
#include <hip/hip_bf16.h>
#include <cstddef>
#include <math.h>

// ---------------------------------------------------------------------------
// Model constants
// ---------------------------------------------------------------------------
#define S_LEN 1024
#define D_DIM 128
#define H_HEADS 8
#define FF_DIM 2048
#define L_LAYERS 4
#define HID_DIM 768
#define LN_EPS 1e-5f

#define ATT_KS 8                  // attention K-split chunks
#define ATT_KCH (S_LEN / ATT_KS)  // 128 keys per chunk
#define FF2_KS 8                  // FF2 split-K chunks (proven R8)

typedef __attribute__((ext_vector_type(8))) short bf16x8;
typedef __attribute__((ext_vector_type(4))) float f32x4;

// ---------------------------------------------------------------------------
// Wave-level MFMA tile: 16 rows x (NT*16) cols (proven fragment layout:
// A row = l&15, k-offset = (l>>4)*8; C/D row = (l>>4)*4+j, col = l&15).
// ---------------------------------------------------------------------------
template<int NT>
__device__ __forceinline__ void mfma_tile(
    const __hip_bfloat16* __restrict__ A, const __hip_bfloat16* __restrict__ W,
    int K, int m0, int n0, int kbeg, int kend, int lane, f32x4* acc)
{
    const int lr = lane & 15;
    const int lk = (lane >> 4) * 8;
    const __hip_bfloat16* Ap = A + (size_t)(m0 + lr) * K + lk;
    const __hip_bfloat16* Wp = W + (size_t)(n0 + lr) * K + lk;
    #pragma unroll 4
    for (int k = kbeg; k < kend; k += 32) {
        const bf16x8 a = *reinterpret_cast<const bf16x8*>(Ap + k);
        #pragma unroll
        for (int nt = 0; nt < NT; ++nt) {
            const bf16x8 b = *reinterpret_cast<const bf16x8*>(Wp + (size_t)nt * 16 * K + k);
            acc[nt] = __builtin_amdgcn_mfma_f32_16x16x32_bf16(a, b, acc[nt], 0, 0, 0);
        }
    }
}

// ---------------------------------------------------------------------------
// One-shot weight conversion fp32 -> bf16 (concatenated, proven).
// ---------------------------------------------------------------------------
__global__ __launch_bounds__(256) void wconv_kernel(
    const float* __restrict__ Wqkv, const float* __restrict__ Wo,
    const float* __restrict__ W1, const float* __restrict__ W2,
    const float* __restrict__ Wout, __hip_bfloat16* __restrict__ dst)
{
    const int i = blockIdx.x * 256 + threadIdx.x;   // float4 index, 0..614399
    const float* src;
    int off4;
    if (i < 49152)       { src = Wqkv; off4 = i; }
    else if (i < 65536)  { src = Wo;   off4 = i - 49152; }
    else if (i < 327680) { src = W1;   off4 = i - 65536; }
    else if (i < 589824) { src = W2;   off4 = i - 327680; }
    else                 { src = Wout; off4 = i - 589824; }
    const float4 v = reinterpret_cast<const float4*>(src)[off4];
    __hip_bfloat16* o = dst + (size_t)i * 4;
    o[0] = __float2bfloat16(v.x);
    o[1] = __float2bfloat16(v.y);
    o[2] = __float2bfloat16(v.z);
    o[3] = __float2bfloat16(v.w);
}

// ---------------------------------------------------------------------------
// embed + layer-0 QKV, fused (proven). 64 blocks x 1024 thr.
// ---------------------------------------------------------------------------
__global__ __launch_bounds__(1024, 1) void embed_qkv_kernel(
    const int* __restrict__ shot, const int* __restrict__ cam,
    const int* __restrict__ light, const int* __restrict__ tone,
    const int* __restrict__ rhythm, const int* __restrict__ trans,
    const float* __restrict__ motion, const float* __restrict__ focus,
    const float* __restrict__ E_shot, const float* __restrict__ E_cam,
    const float* __restrict__ E_light, const float* __restrict__ E_tone,
    const float* __restrict__ E_rhythm, const float* __restrict__ E_trans,
    const float* __restrict__ W_m1, const float* __restrict__ b_m1,
    const float* __restrict__ W_m2, const float* __restrict__ b_m2,
    const float* __restrict__ W_f, const float* __restrict__ b_f,
    const float* __restrict__ pos,
    const __hip_bfloat16* __restrict__ Wqkv0, const float* __restrict__ bqkv0,
    float* __restrict__ x, __hip_bfloat16* __restrict__ x_bf,
    __hip_bfloat16* __restrict__ qkv_bf)
{
    const int blk = blockIdx.x;
    const int tid = threadIdx.x;
    const int m0  = blk * 16;

    for (int e = tid; e < 16 * D_DIM; e += 1024) {
        const int s = m0 + (e >> 7);
        const int d = e & 127;
        const float4 mp = *reinterpret_cast<const float4*>(motion + s * 4);
        const float f0 = focus[s * 2 + 0], f1 = focus[s * 2 + 1];
        float acc = b_m2[d];
        const float* w2row = W_m2 + (size_t)d * 64;
        #pragma unroll 8
        for (int k2 = 0; k2 < 64; ++k2) {
            const float hk = b_m1[k2]
                + W_m1[k2 * 4 + 0] * mp.x + W_m1[k2 * 4 + 1] * mp.y
                + W_m1[k2 * 4 + 2] * mp.z + W_m1[k2 * 4 + 3] * mp.w;
            acc += w2row[k2] * fmaxf(hk, 0.0f);
        }
        acc += b_f[d] + W_f[d * 2 + 0] * f0 + W_f[d * 2 + 1] * f1;
        acc += E_shot  [(size_t)shot[s]   * D_DIM + d];
        acc += E_cam   [(size_t)cam[s]    * D_DIM + d];
        acc += E_light [(size_t)light[s]  * D_DIM + d];
        acc += E_tone  [(size_t)tone[s]   * D_DIM + d];
        acc += E_rhythm[(size_t)rhythm[s] * D_DIM + d];
        acc += E_trans [(size_t)trans[s]  * D_DIM + d];
        acc += pos[(size_t)s * D_DIM + d];
        const size_t gi = (size_t)s * D_DIM + d;
        x[gi] = acc;
        x_bf[gi] = __float2bfloat16(acc);
    }
    __syncthreads();

    const int wave = tid >> 6, lane = tid & 63;
    for (int u = wave; u < 12; u += 16) {
        const int n0 = u * 32;
        f32x4 acc[2] = {};
        mfma_tile<2>(x_bf, Wqkv0, 128, m0, n0, 0, 128, lane, acc);
        const int orow = m0 + (lane >> 4) * 4;
        #pragma unroll
        for (int h = 0; h < 2; ++h) {
            const int col = n0 + h * 16 + (lane & 15);
            const float bv = bqkv0[col];
            #pragma unroll
            for (int j = 0; j < 4; ++j)
                qkv_bf[(size_t)(orow + j) * 384 + col] =
                    __float2bfloat16(acc[h][j] + bv);
        }
    }
}

// ---------------------------------------------------------------------------
// Attention split-K partials (proven R4/R8). grid (8, 4, 8) = 256 blk x 256.
// ---------------------------------------------------------------------------
__global__ __launch_bounds__(256) void attn_part_kernel(
    const __hip_bfloat16* __restrict__ qkv,
    float* __restrict__ pm, float* __restrict__ pl, float* __restrict__ po)
{
    __shared__ float Ks[ATT_KCH * 16];
    __shared__ float Vs[ATT_KCH * 16];

    const int t     = threadIdx.x;
    const int chunk = blockIdx.x;
    const int qb    = blockIdx.y;
    const int head  = blockIdx.z;
    const int kbase = chunk * ATT_KCH;

    {
        const int row  = t >> 1;
        const int half = (t & 1) * 8;
        const __hip_bfloat16* src = qkv + (size_t)(kbase + row) * 384 + head * 16 + half;
        #pragma unroll
        for (int j = 0; j < 8; ++j)
            Ks[row * 16 + half + j] = __bfloat162float(src[128 + j]);
        #pragma unroll
        for (int j = 0; j < 8; ++j)
            Vs[row * 16 + half + j] = __bfloat162float(src[256 + j]);
    }

    const int qrow = qb * 256 + t;
    float q[16];
    {
        const __hip_bfloat16* qp = qkv + (size_t)qrow * 384 + head * 16;
        #pragma unroll
        for (int d = 0; d < 16; ++d)
            q[d] = __bfloat162float(qp[d]) * 0.25f;
    }
    __syncthreads();

    float m = -INFINITY, l = 0.f;
    float O[16];
    #pragma unroll
    for (int d = 0; d < 16; ++d) O[d] = 0.f;

    for (int j0 = 0; j0 < ATT_KCH; j0 += 8) {
        float sv[8];
        #pragma unroll
        for (int jj = 0; jj < 8; ++jj) {
            const float* kr = &Ks[(j0 + jj) * 16];
            float a = 0.f;
            #pragma unroll
            for (int d = 0; d < 16; d += 4) {
                const float4 kv = *reinterpret_cast<const float4*>(kr + d);
                a += q[d] * kv.x + q[d + 1] * kv.y
                   + q[d + 2] * kv.z + q[d + 3] * kv.w;
            }
            sv[jj] = a;
        }
        float bm = sv[0];
        #pragma unroll
        for (int jj = 1; jj < 8; ++jj) bm = fmaxf(bm, sv[jj]);
        const float mn = fmaxf(m, bm);
        const float corr = __expf(m - mn);
        m = mn;
        l *= corr;
        #pragma unroll
        for (int d = 0; d < 16; ++d) O[d] *= corr;
        #pragma unroll
        for (int jj = 0; jj < 8; ++jj) {
            const float p = __expf(sv[jj] - m);
            l += p;
            const float* vr = &Vs[(j0 + jj) * 16];
            #pragma unroll
            for (int d = 0; d < 16; ++d) O[d] += p * vr[d];
        }
    }

    const int pidx = ((chunk * H_HEADS + head) << 10) + qrow;
    pm[pidx] = m;
    pl[pidx] = l;
    #pragma unroll
    for (int d = 0; d < 16; d += 4)
        *reinterpret_cast<float4*>(&po[(size_t)pidx * 16 + d]) =
            make_float4(O[d], O[d + 1], O[d + 2], O[d + 3]);
}

// ---------------------------------------------------------------------------
// comb + Wo + residual + LN1 fused. 64 blocks x 1024 thr (16 waves).
// comb (row-local, ported from refcheck-proven R7 chain) -> att rows in LDS
// (bf16, row pad 136 -> 16B-aligned b128 frags, 2-lanes/bank free) ->
// Wo MFMA (waves 0-7) -> LN1 (16 waves, one row each, single round).
// ---------------------------------------------------------------------------
__global__ __launch_bounds__(1024, 1) void comb_wo_ln1_kernel(
    const float* __restrict__ pm, const float* __restrict__ pl,
    const float* __restrict__ po,
    const __hip_bfloat16* __restrict__ Wo_i, const float* __restrict__ bo_i,
    float* __restrict__ x, __hip_bfloat16* __restrict__ x_bf,
    const float* __restrict__ g, const float* __restrict__ b)
{
    __shared__ __hip_bfloat16 att[16][136];   // attn rows (pad 136: 272B rows)
    __shared__ float lds_wo[16][132];         // Wo output

    const int tid  = threadIdx.x;
    const int wave = tid >> 6;
    const int lane = tid & 63;
    const int m0   = blockIdx.x * 16;

    // ---- combine partials for this block's 16 rows (1024 = 128 units x 8) ----
    {
        const int unit = tid >> 3;            // (rloc, head)
        const int rloc = unit >> 3;
        const int head = unit & 7;
        const int row  = m0 + rloc;
        const int d0   = (tid & 7) * 2;

        float mg = -INFINITY;
        #pragma unroll
        for (int c = 0; c < ATT_KS; ++c)
            mg = fmaxf(mg, pm[((c * H_HEADS + head) << 10) + row]);
        float lg = 0.f, O0 = 0.f, O1 = 0.f;
        #pragma unroll
        for (int c = 0; c < ATT_KS; ++c) {
            const int pidx = ((c * H_HEADS + head) << 10) + row;
            const float w = __expf(pm[pidx] - mg);
            lg += pl[pidx] * w;
            O0 += w * po[(size_t)pidx * 16 + d0];
            O1 += w * po[(size_t)pidx * 16 + d0 + 1];
        }
        const float inv = 1.f / lg;
        att[rloc][head * 16 + d0]     = __float2bfloat16(O0 * inv);
        att[rloc][head * 16 + d0 + 1] = __float2bfloat16(O1 * inv);
    }
    __syncthreads();

    // ---- Wo: waves 0-7, each a 16x16 col-unit, A-frags from LDS ----
    if (wave < 8) {
        const int lr = lane & 15;
        const int lk = (lane >> 4) * 8;
        const int n0 = wave * 16;
        f32x4 acc = {};
        const __hip_bfloat16* Wp = Wo_i + (size_t)(n0 + lr) * 128 + lk;
        #pragma unroll
        for (int k = 0; k < 128; k += 32) {
            const bf16x8 a = *reinterpret_cast<const bf16x8*>(&att[lr][lk + k]);
            const bf16x8 bb = *reinterpret_cast<const bf16x8*>(Wp + k);
            acc = __builtin_amdgcn_mfma_f32_16x16x32_bf16(a, bb, acc, 0, 0, 0);
        }
        const int orow = (lane >> 4) * 4;
        const int col  = n0 + lr;
        #pragma unroll
        for (int j = 0; j < 4; ++j)
            lds_wo[orow + j][col] = acc[j];
    }
    __syncthreads();

    // ---- LN1: 16 waves, one row each ----
    {
        const int rloc = wave;
        const int d0 = lane * 2;
        const size_t i0 = (size_t)(m0 + rloc) * D_DIM + d0;
        float v0 = x[i0]     + lds_wo[rloc][d0]     + bo_i[d0];
        float v1 = x[i0 + 1] + lds_wo[rloc][d0 + 1] + bo_i[d0 + 1];
        float s = v0 + v1;
        #pragma unroll
        for (int off = 32; off >= 1; off >>= 1) s += __shfl_xor(s, off);
        const float mu = s * (1.0f / 128.0f);
        const float q0 = v0 - mu, q1 = v1 - mu;
        float qs = q0 * q0 + q1 * q1;
        #pragma unroll
        for (int off = 32; off >= 1; off >>= 1) qs += __shfl_xor(qs, off);
        const float rs = rsqrtf(qs * (1.0f / 128.0f) + LN_EPS);
        const float r0 = q0 * rs * g[d0] + b[d0];
        const float r1 = q1 * rs * g[d0 + 1] + b[d0 + 1];
        x[i0] = r0;     x[i0 + 1] = r1;
        x_bf[i0] = __float2bfloat16(r0);
        x_bf[i0 + 1] = __float2bfloat16(r1);
    }
}

// ---------------------------------------------------------------------------
// FF1 (proven): 32x64 tile, 4 waves 2x2. grid (32, 32) = 1024 blocks.
// ---------------------------------------------------------------------------
__global__ __launch_bounds__(256) void ff1_kernel(
    const __hip_bfloat16* __restrict__ A, const __hip_bfloat16* __restrict__ W,
    const float* __restrict__ bias, __hip_bfloat16* __restrict__ C)
{
    const int t = threadIdx.x;
    const int w  = t >> 6;
    const int l  = t & 63;
    const int m0 = blockIdx.y * 32 + (w & 1) * 16;
    const int n0 = blockIdx.x * 64 + (w >> 1) * 32;

    f32x4 acc[2] = {};
    mfma_tile<2>(A, W, 128, m0, n0, 0, 128, l, acc);

    const int orow = m0 + (l >> 4) * 4;
    #pragma unroll
    for (int nt = 0; nt < 2; ++nt) {
        const int col = n0 + nt * 16 + (l & 15);
        const float bv = bias[col];
        #pragma unroll
        for (int j = 0; j < 4; ++j)
            C[(size_t)(orow + j) * FF_DIM + col] =
                __float2bfloat16(fmaxf(acc[nt][j] + bv, 0.f));
    }
}

// ---------------------------------------------------------------------------
// FF2 split-K partials: KC=256 compile-time (proven R8).
// grid (2, 32, 8) = 512 blocks. P[z][M,N] f32.
// ---------------------------------------------------------------------------
template<int KC>
__global__ __launch_bounds__(256) void ff2_sk_kernel(
    const __hip_bfloat16* __restrict__ A, const __hip_bfloat16* __restrict__ W,
    float* __restrict__ P)
{
    const int t = threadIdx.x;
    const int w  = t >> 6;
    const int l  = t & 63;
    const int lr = l & 15;
    const int lk = (l >> 4) * 8;
    const int m0 = blockIdx.y * 32 + (w & 1) * 16;
    const int n0 = blockIdx.x * 64 + (w >> 1) * 32;
    const int kbeg = blockIdx.z * KC;

    f32x4 acc[2] = {};
    const __hip_bfloat16* Ap = A + (size_t)(m0 + lr) * FF_DIM + lk + kbeg;
    const __hip_bfloat16* Wp = W + (size_t)(n0 + lr) * FF_DIM + lk + kbeg;
    #pragma unroll
    for (int k = 0; k < KC; k += 32) {
        const bf16x8 a = *reinterpret_cast<const bf16x8*>(Ap + k);
        #pragma unroll
        for (int nt = 0; nt < 2; ++nt) {
            const bf16x8 bb = *reinterpret_cast<const bf16x8*>(Wp + (size_t)nt * 16 * FF_DIM + k);
            acc[nt] = __builtin_amdgcn_mfma_f32_16x16x32_bf16(a, bb, acc[nt], 0, 0, 0);
        }
    }

    float* Pz = P + (size_t)blockIdx.z * (S_LEN * D_DIM);
    const int orow = m0 + (l >> 4) * 4;
    #pragma unroll
    for (int nt = 0; nt < 2; ++nt) {
        const int col = n0 + nt * 16 + (l & 15);
        #pragma unroll
        for (int j = 0; j < 4; ++j)
            Pz[(size_t)(orow + j) * D_DIM + col] = acc[nt][j];
    }
}

// ---------------------------------------------------------------------------
// LN2 (+8 partials + bias) then next-layer QKV (or out-proj if LAST).
// 64 blocks x 1024 thr (16 waves): LN single round; QKV 12 units in 1 round.
// ---------------------------------------------------------------------------
template<int LAST>
__global__ __launch_bounds__(1024, 1) void ln2_qkv_kernel(
    const float* __restrict__ P, const float* __restrict__ b2_i,
    float* __restrict__ x, __hip_bfloat16* __restrict__ x_bf,
    const float* __restrict__ g, const float* __restrict__ b,
    const __hip_bfloat16* __restrict__ Wn, const float* __restrict__ bn,
    __hip_bfloat16* __restrict__ qkv_bf, float* __restrict__ out)
{
    const int tid  = threadIdx.x;
    const int wave = tid >> 6;
    const int lane = tid & 63;
    const int m0   = blockIdx.x * 16;

    // ---- LN2: 16 waves, one row each ----
    {
        const int rloc = wave;
        const int d0 = lane * 2;
        const size_t i0 = (size_t)(m0 + rloc) * D_DIM + d0;
        float v0 = x[i0]     + b2_i[d0];
        float v1 = x[i0 + 1] + b2_i[d0 + 1];
        #pragma unroll
        for (int p = 0; p < FF2_KS; ++p) {
            v0 += P[(size_t)p * (S_LEN * D_DIM) + i0];
            v1 += P[(size_t)p * (S_LEN * D_DIM) + i0 + 1];
        }
        float s = v0 + v1;
        #pragma unroll
        for (int off = 32; off >= 1; off >>= 1) s += __shfl_xor(s, off);
        const float mu = s * (1.0f / 128.0f);
        const float q0 = v0 - mu, q1 = v1 - mu;
        float qs = q0 * q0 + q1 * q1;
        #pragma unroll
        for (int off = 32; off >= 1; off >>= 1) qs += __shfl_xor(qs, off);
        const float rs = rsqrtf(qs * (1.0f / 128.0f) + LN_EPS);
        const float r0 = q0 * rs * g[d0] + b[d0];
        const float r1 = q1 * rs * g[d0 + 1] + b[d0 + 1];
        x[i0] = r0;     x[i0 + 1] = r1;
        x_bf[i0] = __float2bfloat16(r0);
        x_bf[i0 + 1] = __float2bfloat16(r1);
    }
    __syncthreads();

    if (!LAST) {
        // next-layer QKV: 12 units, 16 waves -> single round
        if (wave < 12) {
            const int n0 = wave * 32;
            f32x4 acc[2] = {};
            mfma_tile<2>(x_bf, Wn, 128, m0, n0, 0, 128, lane, acc);
            const int orow = m0 + (lane >> 4) * 4;
            #pragma unroll
            for (int h = 0; h < 2; ++h) {
                const int col = n0 + h * 16 + (lane & 15);
                const float bv = bn[col];
                #pragma unroll
                for (int j = 0; j < 4; ++j)
                    qkv_bf[(size_t)(orow + j) * 384 + col] =
                        __float2bfloat16(acc[h][j] + bv);
            }
        }
    } else {
        // out-proj: 24 units over 16 waves -> <=2 rounds
        #pragma unroll
        for (int r = 0; r < 2; ++r) {
            const int u = wave + r * 16;
            if (u < 24) {
                const int n0 = u * 32;
                f32x4 acc[2] = {};
                mfma_tile<2>(x_bf, Wn, 128, m0, n0, 0, 128, lane, acc);
                const int orow = m0 + (lane >> 4) * 4;
                #pragma unroll
                for (int h = 0; h < 2; ++h) {
                    const int col = n0 + h * 16 + (lane & 15);
                    const float bv = bn[col];
                    #pragma unroll
                    for (int j = 0; j < 4; ++j)
                        out[(size_t)(orow + j) * HID_DIM + col] = acc[h][j] + bv;
                }
            }
        }
        if (tid < 16)
            out[(size_t)S_LEN * HID_DIM + m0 + tid] = 0.0f;
    }
}

// ---------------------------------------------------------------------------
// Host launch: 22 dispatches.
// ---------------------------------------------------------------------------
extern "C" void kernel_launch(void* const* d_in, const int* in_sizes, int n_in,
                              void* d_out, int out_size, void* d_ws, size_t ws_size,
                              hipStream_t stream)
{
    const int*   shot    = (const int*)  d_in[0];
    const int*   cam     = (const int*)  d_in[1];
    const int*   light   = (const int*)  d_in[2];
    const int*   tone    = (const int*)  d_in[3];
    const int*   rhythm  = (const int*)  d_in[4];
    const int*   trans   = (const int*)  d_in[5];
    const float* motion  = (const float*)d_in[6];
    const float* focus   = (const float*)d_in[7];
    const float* E_shot  = (const float*)d_in[8];
    const float* E_cam   = (const float*)d_in[9];
    const float* E_light = (const float*)d_in[10];
    const float* E_tone  = (const float*)d_in[11];
    const float* E_rhyth = (const float*)d_in[12];
    const float* E_trans = (const float*)d_in[13];
    const float* W_m1    = (const float*)d_in[14];
    const float* b_m1    = (const float*)d_in[15];
    const float* W_m2    = (const float*)d_in[16];
    const float* b_m2    = (const float*)d_in[17];
    const float* W_f     = (const float*)d_in[18];
    const float* b_f     = (const float*)d_in[19];
    const float* pos     = (const float*)d_in[20];
    const float* Wqkv    = (const float*)d_in[21];
    const float* bqkv    = (const float*)d_in[22];
    const float* Wo      = (const float*)d_in[23];
    const float* bo      = (const float*)d_in[24];
    const float* W1      = (const float*)d_in[25];
    const float* b1      = (const float*)d_in[26];
    const float* W2      = (const float*)d_in[27];
    const float* b2      = (const float*)d_in[28];
    const float* ln1_g   = (const float*)d_in[29];
    const float* ln1_b   = (const float*)d_in[30];
    const float* ln2_g   = (const float*)d_in[31];
    const float* ln2_b   = (const float*)d_in[32];
    const float* W_out   = (const float*)d_in[33];
    const float* b_out   = (const float*)d_in[34];

    float* out = (float*)d_out;

    // workspace layout
    float* ws = (float*)d_ws;
    float* x  = ws;                                 // 131072 f32
    float* pm = x  + S_LEN * D_DIM;                 // 65536
    float* pl = pm + ATT_KS * H_HEADS * S_LEN;      // 65536
    float* po = pl + ATT_KS * H_HEADS * S_LEN;      // 1048576
    float* P  = po + ATT_KS * H_HEADS * S_LEN * 16; // 8*131072 (FF2 partials)
    __hip_bfloat16* bfb = (__hip_bfloat16*)(P + FF2_KS * S_LEN * D_DIM);
    __hip_bfloat16* wqkv_bf = bfb;                  // [4][384][128]
    __hip_bfloat16* wo_bf   = wqkv_bf + 196608;     // [4][128][128]
    __hip_bfloat16* w1_bf   = wo_bf   + 65536;      // [4][2048][128]
    __hip_bfloat16* w2_bf   = w1_bf   + 1048576;    // [4][128][2048]
    __hip_bfloat16* wout_bf = w2_bf   + 1048576;    // [768][128]
    __hip_bfloat16* x_bf    = wout_bf + 98304;      // [1024][128]
    __hip_bfloat16* qkv_bf  = x_bf    + 131072;     // [1024][384]
    __hip_bfloat16* hbuf_bf = qkv_bf  + 393216;     // [1024][2048]

    // 1) weights -> bf16
    wconv_kernel<<<2400, 256, 0, stream>>>(Wqkv, Wo, W1, W2, W_out, bfb);

    // 2) embed + layer-0 qkv
    embed_qkv_kernel<<<64, 1024, 0, stream>>>(
        shot, cam, light, tone, rhythm, trans, motion, focus,
        E_shot, E_cam, E_light, E_tone, E_rhyth, E_trans,
        W_m1, b_m1, W_m2, b_m2, W_f, b_f, pos,
        wqkv_bf, bqkv, x, x_bf, qkv_bf);

    // 3) layers: 5 dispatches each
    for (int li = 0; li < L_LAYERS; ++li) {
        const __hip_bfloat16* Wo_i = wo_bf + (size_t)li * D_DIM * D_DIM;
        const __hip_bfloat16* W1_i = w1_bf + (size_t)li * FF_DIM * D_DIM;
        const __hip_bfloat16* W2_i = w2_bf + (size_t)li * D_DIM * FF_DIM;
        const float* bo_i = bo + (size_t)li * D_DIM;
        const float* b1_i = b1 + (size_t)li * FF_DIM;
        const float* b2_i = b2 + (size_t)li * D_DIM;
        const float* l1g = ln1_g + (size_t)li * D_DIM;
        const float* l1b = ln1_b + (size_t)li * D_DIM;
        const float* l2g = ln2_g + (size_t)li * D_DIM;
        const float* l2b = ln2_b + (size_t)li * D_DIM;

        attn_part_kernel<<<dim3(ATT_KS, 4, H_HEADS), 256, 0, stream>>>(
            qkv_bf, pm, pl, po);

        comb_wo_ln1_kernel<<<64, 1024, 0, stream>>>(
            pm, pl, po, Wo_i, bo_i, x, x_bf, l1g, l1b);

        ff1_kernel<<<dim3(FF_DIM / 64, S_LEN / 32), 256, 0, stream>>>(
            x_bf, W1_i, b1_i, hbuf_bf);

        ff2_sk_kernel<256><<<dim3(D_DIM / 64, S_LEN / 32, FF2_KS), 256, 0, stream>>>(
            hbuf_bf, W2_i, P);

        if (li < L_LAYERS - 1) {
            const __hip_bfloat16* Wn = wqkv_bf + (size_t)(li + 1) * 3 * D_DIM * D_DIM;
            const float* bn = bqkv + (size_t)(li + 1) * 3 * D_DIM;
            ln2_qkv_kernel<0><<<64, 1024, 0, stream>>>(
                P, b2_i, x, x_bf, l2g, l2b, Wn, bn, qkv_bf, nullptr);
        } else {
            ln2_qkv_kernel<1><<<64, 1024, 0, stream>>>(
                P, b2_i, x, x_bf, l2g, l2b, wout_bf, b_out, nullptr, out);
        }
    }
}

// Round 11
// 216.629 us; speedup vs baseline: 1.2810x; 1.1396x over previous
//
#include <hip/hip_runtime.h>
#include <hip/hip_bf16.h>
#include <cstddef>
#include <math.h>

// ---------------------------------------------------------------------------
// Model constants
// ---------------------------------------------------------------------------
#define S_LEN 1024
#define D_DIM 128
#define H_HEADS 8
#define FF_DIM 2048
#define L_LAYERS 4
#define HID_DIM 768
#define LN_EPS 1e-5f

#define ATT_KS 8                  // attention K-split chunks
#define ATT_KCH (S_LEN / ATT_KS)  // 128 keys per chunk
#define FF2_KS 4                  // FF2 split-K chunks (fused kernel z-dim)
#define FF_KC (FF_DIM / FF2_KS)   // 512 h-cols per fused block

typedef __attribute__((ext_vector_type(8))) short bf16x8;
typedef __attribute__((ext_vector_type(4))) float f32x4;

// ---------------------------------------------------------------------------
// Wave-level MFMA tile: 16 rows x (NT*16) cols (proven fragment layout:
// A row = l&15, k-offset = (l>>4)*8; C/D row = (l>>4)*4+j, col = l&15).
// ---------------------------------------------------------------------------
template<int NT>
__device__ __forceinline__ void mfma_tile(
    const __hip_bfloat16* __restrict__ A, const __hip_bfloat16* __restrict__ W,
    int K, int m0, int n0, int kbeg, int kend, int lane, f32x4* acc)
{
    const int lr = lane & 15;
    const int lk = (lane >> 4) * 8;
    const __hip_bfloat16* Ap = A + (size_t)(m0 + lr) * K + lk;
    const __hip_bfloat16* Wp = W + (size_t)(n0 + lr) * K + lk;
    #pragma unroll 4
    for (int k = kbeg; k < kend; k += 32) {
        const bf16x8 a = *reinterpret_cast<const bf16x8*>(Ap + k);
        #pragma unroll
        for (int nt = 0; nt < NT; ++nt) {
            const bf16x8 b = *reinterpret_cast<const bf16x8*>(Wp + (size_t)nt * 16 * K + k);
            acc[nt] = __builtin_amdgcn_mfma_f32_16x16x32_bf16(a, b, acc[nt], 0, 0, 0);
        }
    }
}

// ---------------------------------------------------------------------------
// One-shot weight conversion fp32 -> bf16 (concatenated, proven).
// ---------------------------------------------------------------------------
__global__ __launch_bounds__(256) void wconv_kernel(
    const float* __restrict__ Wqkv, const float* __restrict__ Wo,
    const float* __restrict__ W1, const float* __restrict__ W2,
    const float* __restrict__ Wout, __hip_bfloat16* __restrict__ dst)
{
    const int i = blockIdx.x * 256 + threadIdx.x;   // float4 index, 0..614399
    const float* src;
    int off4;
    if (i < 49152)       { src = Wqkv; off4 = i; }
    else if (i < 65536)  { src = Wo;   off4 = i - 49152; }
    else if (i < 327680) { src = W1;   off4 = i - 65536; }
    else if (i < 589824) { src = W2;   off4 = i - 327680; }
    else                 { src = Wout; off4 = i - 589824; }
    const float4 v = reinterpret_cast<const float4*>(src)[off4];
    __hip_bfloat16* o = dst + (size_t)i * 4;
    o[0] = __float2bfloat16(v.x);
    o[1] = __float2bfloat16(v.y);
    o[2] = __float2bfloat16(v.z);
    o[3] = __float2bfloat16(v.w);
}

// ---------------------------------------------------------------------------
// embed + layer-0 QKV, fused (proven). 64 blocks x 1024 thr.
// ---------------------------------------------------------------------------
__global__ __launch_bounds__(1024, 1) void embed_qkv_kernel(
    const int* __restrict__ shot, const int* __restrict__ cam,
    const int* __restrict__ light, const int* __restrict__ tone,
    const int* __restrict__ rhythm, const int* __restrict__ trans,
    const float* __restrict__ motion, const float* __restrict__ focus,
    const float* __restrict__ E_shot, const float* __restrict__ E_cam,
    const float* __restrict__ E_light, const float* __restrict__ E_tone,
    const float* __restrict__ E_rhythm, const float* __restrict__ E_trans,
    const float* __restrict__ W_m1, const float* __restrict__ b_m1,
    const float* __restrict__ W_m2, const float* __restrict__ b_m2,
    const float* __restrict__ W_f, const float* __restrict__ b_f,
    const float* __restrict__ pos,
    const __hip_bfloat16* __restrict__ Wqkv0, const float* __restrict__ bqkv0,
    float* __restrict__ x, __hip_bfloat16* __restrict__ x_bf,
    __hip_bfloat16* __restrict__ qkv_bf)
{
    const int blk = blockIdx.x;
    const int tid = threadIdx.x;
    const int m0  = blk * 16;

    for (int e = tid; e < 16 * D_DIM; e += 1024) {
        const int s = m0 + (e >> 7);
        const int d = e & 127;
        const float4 mp = *reinterpret_cast<const float4*>(motion + s * 4);
        const float f0 = focus[s * 2 + 0], f1 = focus[s * 2 + 1];
        float acc = b_m2[d];
        const float* w2row = W_m2 + (size_t)d * 64;
        #pragma unroll 8
        for (int k2 = 0; k2 < 64; ++k2) {
            const float hk = b_m1[k2]
                + W_m1[k2 * 4 + 0] * mp.x + W_m1[k2 * 4 + 1] * mp.y
                + W_m1[k2 * 4 + 2] * mp.z + W_m1[k2 * 4 + 3] * mp.w;
            acc += w2row[k2] * fmaxf(hk, 0.0f);
        }
        acc += b_f[d] + W_f[d * 2 + 0] * f0 + W_f[d * 2 + 1] * f1;
        acc += E_shot  [(size_t)shot[s]   * D_DIM + d];
        acc += E_cam   [(size_t)cam[s]    * D_DIM + d];
        acc += E_light [(size_t)light[s]  * D_DIM + d];
        acc += E_tone  [(size_t)tone[s]   * D_DIM + d];
        acc += E_rhythm[(size_t)rhythm[s] * D_DIM + d];
        acc += E_trans [(size_t)trans[s]  * D_DIM + d];
        acc += pos[(size_t)s * D_DIM + d];
        const size_t gi = (size_t)s * D_DIM + d;
        x[gi] = acc;
        x_bf[gi] = __float2bfloat16(acc);
    }
    __syncthreads();

    const int wave = tid >> 6, lane = tid & 63;
    for (int u = wave; u < 12; u += 16) {
        const int n0 = u * 32;
        f32x4 acc[2] = {};
        mfma_tile<2>(x_bf, Wqkv0, 128, m0, n0, 0, 128, lane, acc);
        const int orow = m0 + (lane >> 4) * 4;
        #pragma unroll
        for (int h = 0; h < 2; ++h) {
            const int col = n0 + h * 16 + (lane & 15);
            const float bv = bqkv0[col];
            #pragma unroll
            for (int j = 0; j < 4; ++j)
                qkv_bf[(size_t)(orow + j) * 384 + col] =
                    __float2bfloat16(acc[h][j] + bv);
        }
    }
}

// ---------------------------------------------------------------------------
// Attention split-K partials (proven R4/R8). grid (8, 4, 8) = 256 blk x 256.
// ---------------------------------------------------------------------------
__global__ __launch_bounds__(256) void attn_part_kernel(
    const __hip_bfloat16* __restrict__ qkv,
    float* __restrict__ pm, float* __restrict__ pl, float* __restrict__ po)
{
    __shared__ float Ks[ATT_KCH * 16];
    __shared__ float Vs[ATT_KCH * 16];

    const int t     = threadIdx.x;
    const int chunk = blockIdx.x;
    const int qb    = blockIdx.y;
    const int head  = blockIdx.z;
    const int kbase = chunk * ATT_KCH;

    {
        const int row  = t >> 1;
        const int half = (t & 1) * 8;
        const __hip_bfloat16* src = qkv + (size_t)(kbase + row) * 384 + head * 16 + half;
        #pragma unroll
        for (int j = 0; j < 8; ++j)
            Ks[row * 16 + half + j] = __bfloat162float(src[128 + j]);
        #pragma unroll
        for (int j = 0; j < 8; ++j)
            Vs[row * 16 + half + j] = __bfloat162float(src[256 + j]);
    }

    const int qrow = qb * 256 + t;
    float q[16];
    {
        const __hip_bfloat16* qp = qkv + (size_t)qrow * 384 + head * 16;
        #pragma unroll
        for (int d = 0; d < 16; ++d)
            q[d] = __bfloat162float(qp[d]) * 0.25f;
    }
    __syncthreads();

    float m = -INFINITY, l = 0.f;
    float O[16];
    #pragma unroll
    for (int d = 0; d < 16; ++d) O[d] = 0.f;

    for (int j0 = 0; j0 < ATT_KCH; j0 += 8) {
        float sv[8];
        #pragma unroll
        for (int jj = 0; jj < 8; ++jj) {
            const float* kr = &Ks[(j0 + jj) * 16];
            float a = 0.f;
            #pragma unroll
            for (int d = 0; d < 16; d += 4) {
                const float4 kv = *reinterpret_cast<const float4*>(kr + d);
                a += q[d] * kv.x + q[d + 1] * kv.y
                   + q[d + 2] * kv.z + q[d + 3] * kv.w;
            }
            sv[jj] = a;
        }
        float bm = sv[0];
        #pragma unroll
        for (int jj = 1; jj < 8; ++jj) bm = fmaxf(bm, sv[jj]);
        const float mn = fmaxf(m, bm);
        const float corr = __expf(m - mn);
        m = mn;
        l *= corr;
        #pragma unroll
        for (int d = 0; d < 16; ++d) O[d] *= corr;
        #pragma unroll
        for (int jj = 0; jj < 8; ++jj) {
            const float p = __expf(sv[jj] - m);
            l += p;
            const float* vr = &Vs[(j0 + jj) * 16];
            #pragma unroll
            for (int d = 0; d < 16; ++d) O[d] += p * vr[d];
        }
    }

    const int pidx = ((chunk * H_HEADS + head) << 10) + qrow;
    pm[pidx] = m;
    pl[pidx] = l;
    #pragma unroll
    for (int d = 0; d < 16; d += 4)
        *reinterpret_cast<float4*>(&po[(size_t)pidx * 16 + d]) =
            make_float4(O[d], O[d + 1], O[d + 2], O[d + 3]);
}

// ---------------------------------------------------------------------------
// comb + Wo + residual + LN1 fused (proven R10). 64 blocks x 1024 thr.
// ---------------------------------------------------------------------------
__global__ __launch_bounds__(1024, 1) void comb_wo_ln1_kernel(
    const float* __restrict__ pm, const float* __restrict__ pl,
    const float* __restrict__ po,
    const __hip_bfloat16* __restrict__ Wo_i, const float* __restrict__ bo_i,
    float* __restrict__ x, __hip_bfloat16* __restrict__ x_bf,
    const float* __restrict__ g, const float* __restrict__ b)
{
    __shared__ __hip_bfloat16 att[16][136];   // attn rows (pad 136: 272B rows)
    __shared__ float lds_wo[16][132];         // Wo output

    const int tid  = threadIdx.x;
    const int wave = tid >> 6;
    const int lane = tid & 63;
    const int m0   = blockIdx.x * 16;

    // ---- combine partials for this block's 16 rows (1024 = 128 units x 8) ----
    {
        const int unit = tid >> 3;            // (rloc, head)
        const int rloc = unit >> 3;
        const int head = unit & 7;
        const int row  = m0 + rloc;
        const int d0   = (tid & 7) * 2;

        float mg = -INFINITY;
        #pragma unroll
        for (int c = 0; c < ATT_KS; ++c)
            mg = fmaxf(mg, pm[((c * H_HEADS + head) << 10) + row]);
        float lg = 0.f, O0 = 0.f, O1 = 0.f;
        #pragma unroll
        for (int c = 0; c < ATT_KS; ++c) {
            const int pidx = ((c * H_HEADS + head) << 10) + row;
            const float w = __expf(pm[pidx] - mg);
            lg += pl[pidx] * w;
            O0 += w * po[(size_t)pidx * 16 + d0];
            O1 += w * po[(size_t)pidx * 16 + d0 + 1];
        }
        const float inv = 1.f / lg;
        att[rloc][head * 16 + d0]     = __float2bfloat16(O0 * inv);
        att[rloc][head * 16 + d0 + 1] = __float2bfloat16(O1 * inv);
    }
    __syncthreads();

    // ---- Wo: waves 0-7, each a 16x16 col-unit, A-frags from LDS ----
    if (wave < 8) {
        const int lr = lane & 15;
        const int lk = (lane >> 4) * 8;
        const int n0 = wave * 16;
        f32x4 acc = {};
        const __hip_bfloat16* Wp = Wo_i + (size_t)(n0 + lr) * 128 + lk;
        #pragma unroll
        for (int k = 0; k < 128; k += 32) {
            const bf16x8 a = *reinterpret_cast<const bf16x8*>(&att[lr][lk + k]);
            const bf16x8 bb = *reinterpret_cast<const bf16x8*>(Wp + k);
            acc = __builtin_amdgcn_mfma_f32_16x16x32_bf16(a, bb, acc, 0, 0, 0);
        }
        const int orow = (lane >> 4) * 4;
        const int col  = n0 + lr;
        #pragma unroll
        for (int j = 0; j < 4; ++j)
            lds_wo[orow + j][col] = acc[j];
    }
    __syncthreads();

    // ---- LN1: 16 waves, one row each ----
    {
        const int rloc = wave;
        const int d0 = lane * 2;
        const size_t i0 = (size_t)(m0 + rloc) * D_DIM + d0;
        float v0 = x[i0]     + lds_wo[rloc][d0]     + bo_i[d0];
        float v1 = x[i0 + 1] + lds_wo[rloc][d0 + 1] + bo_i[d0 + 1];
        float s = v0 + v1;
        #pragma unroll
        for (int off = 32; off >= 1; off >>= 1) s += __shfl_xor(s, off);
        const float mu = s * (1.0f / 128.0f);
        const float q0 = v0 - mu, q1 = v1 - mu;
        float qs = q0 * q0 + q1 * q1;
        #pragma unroll
        for (int off = 32; off >= 1; off >>= 1) qs += __shfl_xor(qs, off);
        const float rs = rsqrtf(qs * (1.0f / 128.0f) + LN_EPS);
        const float r0 = q0 * rs * g[d0] + b[d0];
        const float r1 = q1 * rs * g[d0 + 1] + b[d0 + 1];
        x[i0] = r0;     x[i0 + 1] = r1;
        x_bf[i0] = __float2bfloat16(r0);
        x_bf[i0 + 1] = __float2bfloat16(r1);
    }
}

// ---------------------------------------------------------------------------
// FF1 -> LDS -> FF2-partial fused. grid (64 m-tiles, FF2_KS z) = 256 blocks,
// 256 thr (4 waves). Phase 1: h[16][512] = relu(x @ W1^T + b1) for this
// block's rows/cols, bf16 in LDS (row stride 520 bf16 = 1040 B, 16B-aligned).
// Phase 2: P[z] = h_lds @ W2[:, kb..kb+512]^T (K=512 from LDS A-frags).
// Removes the hbuf global round-trip and one dispatch per layer.
// ---------------------------------------------------------------------------
__global__ __launch_bounds__(256) void ff_fused_kernel(
    const __hip_bfloat16* __restrict__ x_bf,
    const __hip_bfloat16* __restrict__ W1_i, const float* __restrict__ b1_i,
    const __hip_bfloat16* __restrict__ W2_i, float* __restrict__ P)
{
    __shared__ __hip_bfloat16 h[16][FF_KC + 8];   // 16 x 520 bf16 = 16.6 KB

    const int t    = threadIdx.x;
    const int wave = t >> 6;
    const int lane = t & 63;
    const int lr   = lane & 15;
    const int lk   = (lane >> 4) * 8;
    const int m0   = blockIdx.x * 16;
    const int kb   = blockIdx.y * FF_KC;   // h-col base == FF2 k base

    // ---- phase 1: FF1 (+bias+ReLU) -> LDS. 16 units of 16x32 over 4 waves.
    #pragma unroll
    for (int r = 0; r < FF_KC / 32 / 4; ++r) {
        const int u  = wave + r * 4;
        const int n0 = kb + u * 32;
        f32x4 acc[2] = {};
        mfma_tile<2>(x_bf, W1_i, 128, m0, n0, 0, 128, lane, acc);
        const int orow = (lane >> 4) * 4;
        #pragma unroll
        for (int hh = 0; hh < 2; ++hh) {
            const int colg = n0 + hh * 16 + lr;      // global col (bias)
            const int coll = colg - kb;              // local LDS col
            const float bv = b1_i[colg];
            #pragma unroll
            for (int j = 0; j < 4; ++j)
                h[orow + j][coll] =
                    __float2bfloat16(fmaxf(acc[hh][j] + bv, 0.f));
        }
    }
    __syncthreads();

    // ---- phase 2: FF2 partial [16 x 128], K = FF_KC from LDS ----
    {
        const int n0 = wave * 32;
        f32x4 acc[2] = {};
        const __hip_bfloat16* Wp = W2_i + (size_t)(n0 + lr) * FF_DIM + kb + lk;
        #pragma unroll 4
        for (int k = 0; k < FF_KC; k += 32) {
            const bf16x8 a = *reinterpret_cast<const bf16x8*>(&h[lr][lk + k]);
            #pragma unroll
            for (int nt = 0; nt < 2; ++nt) {
                const bf16x8 bb =
                    *reinterpret_cast<const bf16x8*>(Wp + (size_t)nt * 16 * FF_DIM + k);
                acc[nt] = __builtin_amdgcn_mfma_f32_16x16x32_bf16(a, bb, acc[nt], 0, 0, 0);
            }
        }
        float* Pz = P + (size_t)blockIdx.y * (S_LEN * D_DIM);
        const int orow = m0 + (lane >> 4) * 4;
        #pragma unroll
        for (int nt = 0; nt < 2; ++nt) {
            const int col = n0 + nt * 16 + lr;
            #pragma unroll
            for (int j = 0; j < 4; ++j)
                Pz[(size_t)(orow + j) * D_DIM + col] = acc[nt][j];
        }
    }
}

// ---------------------------------------------------------------------------
// LN2 (+FF2_KS partials + bias) then next-layer QKV (or out-proj if LAST).
// 64 blocks x 1024 thr (proven R10).
// ---------------------------------------------------------------------------
template<int LAST>
__global__ __launch_bounds__(1024, 1) void ln2_qkv_kernel(
    const float* __restrict__ P, const float* __restrict__ b2_i,
    float* __restrict__ x, __hip_bfloat16* __restrict__ x_bf,
    const float* __restrict__ g, const float* __restrict__ b,
    const __hip_bfloat16* __restrict__ Wn, const float* __restrict__ bn,
    __hip_bfloat16* __restrict__ qkv_bf, float* __restrict__ out)
{
    const int tid  = threadIdx.x;
    const int wave = tid >> 6;
    const int lane = tid & 63;
    const int m0   = blockIdx.x * 16;

    // ---- LN2: 16 waves, one row each ----
    {
        const int rloc = wave;
        const int d0 = lane * 2;
        const size_t i0 = (size_t)(m0 + rloc) * D_DIM + d0;
        float v0 = x[i0]     + b2_i[d0];
        float v1 = x[i0 + 1] + b2_i[d0 + 1];
        #pragma unroll
        for (int p = 0; p < FF2_KS; ++p) {
            v0 += P[(size_t)p * (S_LEN * D_DIM) + i0];
            v1 += P[(size_t)p * (S_LEN * D_DIM) + i0 + 1];
        }
        float s = v0 + v1;
        #pragma unroll
        for (int off = 32; off >= 1; off >>= 1) s += __shfl_xor(s, off);
        const float mu = s * (1.0f / 128.0f);
        const float q0 = v0 - mu, q1 = v1 - mu;
        float qs = q0 * q0 + q1 * q1;
        #pragma unroll
        for (int off = 32; off >= 1; off >>= 1) qs += __shfl_xor(qs, off);
        const float rs = rsqrtf(qs * (1.0f / 128.0f) + LN_EPS);
        const float r0 = q0 * rs * g[d0] + b[d0];
        const float r1 = q1 * rs * g[d0 + 1] + b[d0 + 1];
        x[i0] = r0;     x[i0 + 1] = r1;
        x_bf[i0] = __float2bfloat16(r0);
        x_bf[i0 + 1] = __float2bfloat16(r1);
    }
    __syncthreads();

    if (!LAST) {
        // next-layer QKV: 12 units, 16 waves -> single round
        if (wave < 12) {
            const int n0 = wave * 32;
            f32x4 acc[2] = {};
            mfma_tile<2>(x_bf, Wn, 128, m0, n0, 0, 128, lane, acc);
            const int orow = m0 + (lane >> 4) * 4;
            #pragma unroll
            for (int h = 0; h < 2; ++h) {
                const int col = n0 + h * 16 + (lane & 15);
                const float bv = bn[col];
                #pragma unroll
                for (int j = 0; j < 4; ++j)
                    qkv_bf[(size_t)(orow + j) * 384 + col] =
                        __float2bfloat16(acc[h][j] + bv);
            }
        }
    } else {
        // out-proj: 24 units over 16 waves -> <=2 rounds
        #pragma unroll
        for (int r = 0; r < 2; ++r) {
            const int u = wave + r * 16;
            if (u < 24) {
                const int n0 = u * 32;
                f32x4 acc[2] = {};
                mfma_tile<2>(x_bf, Wn, 128, m0, n0, 0, 128, lane, acc);
                const int orow = m0 + (lane >> 4) * 4;
                #pragma unroll
                for (int h = 0; h < 2; ++h) {
                    const int col = n0 + h * 16 + (lane & 15);
                    const float bv = bn[col];
                    #pragma unroll
                    for (int j = 0; j < 4; ++j)
                        out[(size_t)(orow + j) * HID_DIM + col] = acc[h][j] + bv;
                }
            }
        }
        if (tid < 16)
            out[(size_t)S_LEN * HID_DIM + m0 + tid] = 0.0f;
    }
}

// ---------------------------------------------------------------------------
// Host launch: 18 dispatches.
// ---------------------------------------------------------------------------
extern "C" void kernel_launch(void* const* d_in, const int* in_sizes, int n_in,
                              void* d_out, int out_size, void* d_ws, size_t ws_size,
                              hipStream_t stream)
{
    const int*   shot    = (const int*)  d_in[0];
    const int*   cam     = (const int*)  d_in[1];
    const int*   light   = (const int*)  d_in[2];
    const int*   tone    = (const int*)  d_in[3];
    const int*   rhythm  = (const int*)  d_in[4];
    const int*   trans   = (const int*)  d_in[5];
    const float* motion  = (const float*)d_in[6];
    const float* focus   = (const float*)d_in[7];
    const float* E_shot  = (const float*)d_in[8];
    const float* E_cam   = (const float*)d_in[9];
    const float* E_light = (const float*)d_in[10];
    const float* E_tone  = (const float*)d_in[11];
    const float* E_rhyth = (const float*)d_in[12];
    const float* E_trans = (const float*)d_in[13];
    const float* W_m1    = (const float*)d_in[14];
    const float* b_m1    = (const float*)d_in[15];
    const float* W_m2    = (const float*)d_in[16];
    const float* b_m2    = (const float*)d_in[17];
    const float* W_f     = (const float*)d_in[18];
    const float* b_f     = (const float*)d_in[19];
    const float* pos     = (const float*)d_in[20];
    const float* Wqkv    = (const float*)d_in[21];
    const float* bqkv    = (const float*)d_in[22];
    const float* Wo      = (const float*)d_in[23];
    const float* bo      = (const float*)d_in[24];
    const float* W1      = (const float*)d_in[25];
    const float* b1      = (const float*)d_in[26];
    const float* W2      = (const float*)d_in[27];
    const float* b2      = (const float*)d_in[28];
    const float* ln1_g   = (const float*)d_in[29];
    const float* ln1_b   = (const float*)d_in[30];
    const float* ln2_g   = (const float*)d_in[31];
    const float* ln2_b   = (const float*)d_in[32];
    const float* W_out   = (const float*)d_in[33];
    const float* b_out   = (const float*)d_in[34];

    float* out = (float*)d_out;

    // workspace layout
    float* ws = (float*)d_ws;
    float* x  = ws;                                 // 131072 f32
    float* pm = x  + S_LEN * D_DIM;                 // 65536
    float* pl = pm + ATT_KS * H_HEADS * S_LEN;      // 65536
    float* po = pl + ATT_KS * H_HEADS * S_LEN;      // 1048576
    float* P  = po + ATT_KS * H_HEADS * S_LEN * 16; // 4*131072 (FF2 partials)
    __hip_bfloat16* bfb = (__hip_bfloat16*)(P + FF2_KS * S_LEN * D_DIM);
    __hip_bfloat16* wqkv_bf = bfb;                  // [4][384][128]
    __hip_bfloat16* wo_bf   = wqkv_bf + 196608;     // [4][128][128]
    __hip_bfloat16* w1_bf   = wo_bf   + 65536;      // [4][2048][128]
    __hip_bfloat16* w2_bf   = w1_bf   + 1048576;    // [4][128][2048]
    __hip_bfloat16* wout_bf = w2_bf   + 1048576;    // [768][128]
    __hip_bfloat16* x_bf    = wout_bf + 98304;      // [1024][128]
    __hip_bfloat16* qkv_bf  = x_bf    + 131072;     // [1024][384]

    // 1) weights -> bf16
    wconv_kernel<<<2400, 256, 0, stream>>>(Wqkv, Wo, W1, W2, W_out, bfb);

    // 2) embed + layer-0 qkv
    embed_qkv_kernel<<<64, 1024, 0, stream>>>(
        shot, cam, light, tone, rhythm, trans, motion, focus,
        E_shot, E_cam, E_light, E_tone, E_rhyth, E_trans,
        W_m1, b_m1, W_m2, b_m2, W_f, b_f, pos,
        wqkv_bf, bqkv, x, x_bf, qkv_bf);

    // 3) layers: 4 dispatches each
    for (int li = 0; li < L_LAYERS; ++li) {
        const __hip_bfloat16* Wo_i = wo_bf + (size_t)li * D_DIM * D_DIM;
        const __hip_bfloat16* W1_i = w1_bf + (size_t)li * FF_DIM * D_DIM;
        const __hip_bfloat16* W2_i = w2_bf + (size_t)li * D_DIM * FF_DIM;
        const float* bo_i = bo + (size_t)li * D_DIM;
        const float* b1_i = b1 + (size_t)li * FF_DIM;
        const float* b2_i = b2 + (size_t)li * D_DIM;
        const float* l1g = ln1_g + (size_t)li * D_DIM;
        const float* l1b = ln1_b + (size_t)li * D_DIM;
        const float* l2g = ln2_g + (size_t)li * D_DIM;
        const float* l2b = ln2_b + (size_t)li * D_DIM;

        attn_part_kernel<<<dim3(ATT_KS, 4, H_HEADS), 256, 0, stream>>>(
            qkv_bf, pm, pl, po);

        comb_wo_ln1_kernel<<<64, 1024, 0, stream>>>(
            pm, pl, po, Wo_i, bo_i, x, x_bf, l1g, l1b);

        ff_fused_kernel<<<dim3(64, FF2_KS), 256, 0, stream>>>(
            x_bf, W1_i, b1_i, W2_i, P);

        if (li < L_LAYERS - 1) {
            const __hip_bfloat16* Wn = wqkv_bf + (size_t)(li + 1) * 3 * D_DIM * D_DIM;
            const float* bn = bqkv + (size_t)(li + 1) * 3 * D_DIM;
            ln2_qkv_kernel<0><<<64, 1024, 0, stream>>>(
                P, b2_i, x, x_bf, l2g, l2b, Wn, bn, qkv_bf, nullptr);
        } else {
            ln2_qkv_kernel<1><<<64, 1024, 0, stream>>>(
                P, b2_i, x, x_bf, l2g, l2b, wout_bf, b_out, nullptr, out);
        }
    }
}

// Round 12
// 208.296 us; speedup vs baseline: 1.3323x; 1.0400x over previous
//
#include <hip/hip_runtime.h>
#include <hip/hip_bf16.h>
#include <cstddef>
#include <math.h>

// ---------------------------------------------------------------------------
// Model constants
// ---------------------------------------------------------------------------
#define S_LEN 1024
#define D_DIM 128
#define H_HEADS 8
#define FF_DIM 2048
#define L_LAYERS 4
#define HID_DIM 768
#define LN_EPS 1e-5f

#define ATT_KS 8                  // attention K-split chunks
#define ATT_KCH (S_LEN / ATT_KS)  // 128 keys per chunk
#define FF2_KS 4                  // FF2 split-K chunks (fused kernel z-dim)
#define FF_KC (FF_DIM / FF2_KS)   // 512 h-cols per fused block

typedef __attribute__((ext_vector_type(8))) short bf16x8;
typedef __attribute__((ext_vector_type(4))) float f32x4;

// bf16 (as short bits) -> f32 : 16-bit left shift
__device__ __forceinline__ float bf16s_to_f(short s)
{
    return __uint_as_float(((unsigned int)(unsigned short)s) << 16);
}

// ---------------------------------------------------------------------------
// Wave-level MFMA tile: 16 rows x (NT*16) cols (proven fragment layout:
// A row = l&15, k-offset = (l>>4)*8; C/D row = (l>>4)*4+j, col = l&15).
// ---------------------------------------------------------------------------
template<int NT>
__device__ __forceinline__ void mfma_tile(
    const __hip_bfloat16* __restrict__ A, const __hip_bfloat16* __restrict__ W,
    int K, int m0, int n0, int kbeg, int kend, int lane, f32x4* acc)
{
    const int lr = lane & 15;
    const int lk = (lane >> 4) * 8;
    const __hip_bfloat16* Ap = A + (size_t)(m0 + lr) * K + lk;
    const __hip_bfloat16* Wp = W + (size_t)(n0 + lr) * K + lk;
    #pragma unroll 4
    for (int k = kbeg; k < kend; k += 32) {
        const bf16x8 a = *reinterpret_cast<const bf16x8*>(Ap + k);
        #pragma unroll
        for (int nt = 0; nt < NT; ++nt) {
            const bf16x8 b = *reinterpret_cast<const bf16x8*>(Wp + (size_t)nt * 16 * K + k);
            acc[nt] = __builtin_amdgcn_mfma_f32_16x16x32_bf16(a, b, acc[nt], 0, 0, 0);
        }
    }
}

// ---------------------------------------------------------------------------
// One-shot weight conversion fp32 -> bf16 (concatenated, proven).
// ---------------------------------------------------------------------------
__global__ __launch_bounds__(256) void wconv_kernel(
    const float* __restrict__ Wqkv, const float* __restrict__ Wo,
    const float* __restrict__ W1, const float* __restrict__ W2,
    const float* __restrict__ Wout, __hip_bfloat16* __restrict__ dst)
{
    const int i = blockIdx.x * 256 + threadIdx.x;   // float4 index, 0..614399
    const float* src;
    int off4;
    if (i < 49152)       { src = Wqkv; off4 = i; }
    else if (i < 65536)  { src = Wo;   off4 = i - 49152; }
    else if (i < 327680) { src = W1;   off4 = i - 65536; }
    else if (i < 589824) { src = W2;   off4 = i - 327680; }
    else                 { src = Wout; off4 = i - 589824; }
    const float4 v = reinterpret_cast<const float4*>(src)[off4];
    __hip_bfloat16* o = dst + (size_t)i * 4;
    o[0] = __float2bfloat16(v.x);
    o[1] = __float2bfloat16(v.y);
    o[2] = __float2bfloat16(v.z);
    o[3] = __float2bfloat16(v.w);
}

// ---------------------------------------------------------------------------
// embed + layer-0 QKV, fused (proven). 64 blocks x 1024 thr.
// ---------------------------------------------------------------------------
__global__ __launch_bounds__(1024, 1) void embed_qkv_kernel(
    const int* __restrict__ shot, const int* __restrict__ cam,
    const int* __restrict__ light, const int* __restrict__ tone,
    const int* __restrict__ rhythm, const int* __restrict__ trans,
    const float* __restrict__ motion, const float* __restrict__ focus,
    const float* __restrict__ E_shot, const float* __restrict__ E_cam,
    const float* __restrict__ E_light, const float* __restrict__ E_tone,
    const float* __restrict__ E_rhythm, const float* __restrict__ E_trans,
    const float* __restrict__ W_m1, const float* __restrict__ b_m1,
    const float* __restrict__ W_m2, const float* __restrict__ b_m2,
    const float* __restrict__ W_f, const float* __restrict__ b_f,
    const float* __restrict__ pos,
    const __hip_bfloat16* __restrict__ Wqkv0, const float* __restrict__ bqkv0,
    float* __restrict__ x, __hip_bfloat16* __restrict__ x_bf,
    __hip_bfloat16* __restrict__ qkv_bf)
{
    const int blk = blockIdx.x;
    const int tid = threadIdx.x;
    const int m0  = blk * 16;

    for (int e = tid; e < 16 * D_DIM; e += 1024) {
        const int s = m0 + (e >> 7);
        const int d = e & 127;
        const float4 mp = *reinterpret_cast<const float4*>(motion + s * 4);
        const float f0 = focus[s * 2 + 0], f1 = focus[s * 2 + 1];
        float acc = b_m2[d];
        const float* w2row = W_m2 + (size_t)d * 64;
        #pragma unroll 8
        for (int k2 = 0; k2 < 64; ++k2) {
            const float hk = b_m1[k2]
                + W_m1[k2 * 4 + 0] * mp.x + W_m1[k2 * 4 + 1] * mp.y
                + W_m1[k2 * 4 + 2] * mp.z + W_m1[k2 * 4 + 3] * mp.w;
            acc += w2row[k2] * fmaxf(hk, 0.0f);
        }
        acc += b_f[d] + W_f[d * 2 + 0] * f0 + W_f[d * 2 + 1] * f1;
        acc += E_shot  [(size_t)shot[s]   * D_DIM + d];
        acc += E_cam   [(size_t)cam[s]    * D_DIM + d];
        acc += E_light [(size_t)light[s]  * D_DIM + d];
        acc += E_tone  [(size_t)tone[s]   * D_DIM + d];
        acc += E_rhythm[(size_t)rhythm[s] * D_DIM + d];
        acc += E_trans [(size_t)trans[s]  * D_DIM + d];
        acc += pos[(size_t)s * D_DIM + d];
        const size_t gi = (size_t)s * D_DIM + d;
        x[gi] = acc;
        x_bf[gi] = __float2bfloat16(acc);
    }
    __syncthreads();

    const int wave = tid >> 6, lane = tid & 63;
    for (int u = wave; u < 12; u += 16) {
        const int n0 = u * 32;
        f32x4 acc[2] = {};
        mfma_tile<2>(x_bf, Wqkv0, 128, m0, n0, 0, 128, lane, acc);
        const int orow = m0 + (lane >> 4) * 4;
        #pragma unroll
        for (int h = 0; h < 2; ++h) {
            const int col = n0 + h * 16 + (lane & 15);
            const float bv = bqkv0[col];
            #pragma unroll
            for (int j = 0; j < 4; ++j)
                qkv_bf[(size_t)(orow + j) * 384 + col] =
                    __float2bfloat16(acc[h][j] + bv);
        }
    }
}

// ---------------------------------------------------------------------------
// Attention split-K partials, vectorized loads (G13). grid (8, 4, 8), 256 thr.
// Staging: bf16x8 (16B) global loads + shift-convert + float4 LDS stores.
// q: 2x bf16x8. PV: 4x float4 LDS reads (wave-uniform -> broadcast).
// ---------------------------------------------------------------------------
__global__ __launch_bounds__(256) void attn_part_kernel(
    const __hip_bfloat16* __restrict__ qkv,
    float* __restrict__ pm, float* __restrict__ pl, float* __restrict__ po)
{
    __shared__ float Ks[ATT_KCH * 16];
    __shared__ float Vs[ATT_KCH * 16];

    const int t     = threadIdx.x;
    const int chunk = blockIdx.x;
    const int qb    = blockIdx.y;
    const int head  = blockIdx.z;
    const int kbase = chunk * ATT_KCH;

    {
        const int row  = t >> 1;
        const int half = (t & 1) * 8;
        const __hip_bfloat16* src = qkv + (size_t)(kbase + row) * 384 + head * 16 + half;
        const bf16x8 k8 = *reinterpret_cast<const bf16x8*>(src + 128);
        const bf16x8 v8 = *reinterpret_cast<const bf16x8*>(src + 256);
        float* kd = &Ks[row * 16 + half];
        float* vd = &Vs[row * 16 + half];
        *reinterpret_cast<float4*>(kd) = make_float4(
            bf16s_to_f(k8[0]), bf16s_to_f(k8[1]), bf16s_to_f(k8[2]), bf16s_to_f(k8[3]));
        *reinterpret_cast<float4*>(kd + 4) = make_float4(
            bf16s_to_f(k8[4]), bf16s_to_f(k8[5]), bf16s_to_f(k8[6]), bf16s_to_f(k8[7]));
        *reinterpret_cast<float4*>(vd) = make_float4(
            bf16s_to_f(v8[0]), bf16s_to_f(v8[1]), bf16s_to_f(v8[2]), bf16s_to_f(v8[3]));
        *reinterpret_cast<float4*>(vd + 4) = make_float4(
            bf16s_to_f(v8[4]), bf16s_to_f(v8[5]), bf16s_to_f(v8[6]), bf16s_to_f(v8[7]));
    }

    const int qrow = qb * 256 + t;
    float q[16];
    {
        const __hip_bfloat16* qp = qkv + (size_t)qrow * 384 + head * 16;
        const bf16x8 q0 = *reinterpret_cast<const bf16x8*>(qp);
        const bf16x8 q1 = *reinterpret_cast<const bf16x8*>(qp + 8);
        #pragma unroll
        for (int d = 0; d < 8; ++d) {
            q[d]     = bf16s_to_f(q0[d]) * 0.25f;
            q[d + 8] = bf16s_to_f(q1[d]) * 0.25f;
        }
    }
    __syncthreads();

    float m = -INFINITY, l = 0.f;
    float O[16];
    #pragma unroll
    for (int d = 0; d < 16; ++d) O[d] = 0.f;

    for (int j0 = 0; j0 < ATT_KCH; j0 += 8) {
        float sv[8];
        #pragma unroll
        for (int jj = 0; jj < 8; ++jj) {
            const float* kr = &Ks[(j0 + jj) * 16];
            const float4 k0 = *reinterpret_cast<const float4*>(kr);
            const float4 k1 = *reinterpret_cast<const float4*>(kr + 4);
            const float4 k2 = *reinterpret_cast<const float4*>(kr + 8);
            const float4 k3 = *reinterpret_cast<const float4*>(kr + 12);
            sv[jj] = q[0] * k0.x + q[1] * k0.y + q[2] * k0.z + q[3] * k0.w
                   + q[4] * k1.x + q[5] * k1.y + q[6] * k1.z + q[7] * k1.w
                   + q[8] * k2.x + q[9] * k2.y + q[10] * k2.z + q[11] * k2.w
                   + q[12] * k3.x + q[13] * k3.y + q[14] * k3.z + q[15] * k3.w;
        }
        float bm = sv[0];
        #pragma unroll
        for (int jj = 1; jj < 8; ++jj) bm = fmaxf(bm, sv[jj]);
        const float mn = fmaxf(m, bm);
        const float corr = __expf(m - mn);
        m = mn;
        l *= corr;
        #pragma unroll
        for (int d = 0; d < 16; ++d) O[d] *= corr;
        #pragma unroll
        for (int jj = 0; jj < 8; ++jj) {
            const float p = __expf(sv[jj] - m);
            l += p;
            const float* vr = &Vs[(j0 + jj) * 16];
            const float4 v0 = *reinterpret_cast<const float4*>(vr);
            const float4 v1 = *reinterpret_cast<const float4*>(vr + 4);
            const float4 v2 = *reinterpret_cast<const float4*>(vr + 8);
            const float4 v3 = *reinterpret_cast<const float4*>(vr + 12);
            O[0]  += p * v0.x; O[1]  += p * v0.y; O[2]  += p * v0.z; O[3]  += p * v0.w;
            O[4]  += p * v1.x; O[5]  += p * v1.y; O[6]  += p * v1.z; O[7]  += p * v1.w;
            O[8]  += p * v2.x; O[9]  += p * v2.y; O[10] += p * v2.z; O[11] += p * v2.w;
            O[12] += p * v3.x; O[13] += p * v3.y; O[14] += p * v3.z; O[15] += p * v3.w;
        }
    }

    const int pidx = ((chunk * H_HEADS + head) << 10) + qrow;
    pm[pidx] = m;
    pl[pidx] = l;
    #pragma unroll
    for (int d = 0; d < 16; d += 4)
        *reinterpret_cast<float4*>(&po[(size_t)pidx * 16 + d]) =
            make_float4(O[d], O[d + 1], O[d + 2], O[d + 3]);
}

// ---------------------------------------------------------------------------
// comb + Wo + residual + LN1 fused (proven R10). 64 blocks x 1024 thr.
// ---------------------------------------------------------------------------
__global__ __launch_bounds__(1024, 1) void comb_wo_ln1_kernel(
    const float* __restrict__ pm, const float* __restrict__ pl,
    const float* __restrict__ po,
    const __hip_bfloat16* __restrict__ Wo_i, const float* __restrict__ bo_i,
    float* __restrict__ x, __hip_bfloat16* __restrict__ x_bf,
    const float* __restrict__ g, const float* __restrict__ b)
{
    __shared__ __hip_bfloat16 att[16][136];   // attn rows (pad 136: 272B rows)
    __shared__ float lds_wo[16][132];         // Wo output

    const int tid  = threadIdx.x;
    const int wave = tid >> 6;
    const int lane = tid & 63;
    const int m0   = blockIdx.x * 16;

    // ---- combine partials for this block's 16 rows (1024 = 128 units x 8) ----
    {
        const int unit = tid >> 3;            // (rloc, head)
        const int rloc = unit >> 3;
        const int head = unit & 7;
        const int row  = m0 + rloc;
        const int d0   = (tid & 7) * 2;

        float mg = -INFINITY;
        #pragma unroll
        for (int c = 0; c < ATT_KS; ++c)
            mg = fmaxf(mg, pm[((c * H_HEADS + head) << 10) + row]);
        float lg = 0.f, O0 = 0.f, O1 = 0.f;
        #pragma unroll
        for (int c = 0; c < ATT_KS; ++c) {
            const int pidx = ((c * H_HEADS + head) << 10) + row;
            const float w = __expf(pm[pidx] - mg);
            lg += pl[pidx] * w;
            O0 += w * po[(size_t)pidx * 16 + d0];
            O1 += w * po[(size_t)pidx * 16 + d0 + 1];
        }
        const float inv = 1.f / lg;
        att[rloc][head * 16 + d0]     = __float2bfloat16(O0 * inv);
        att[rloc][head * 16 + d0 + 1] = __float2bfloat16(O1 * inv);
    }
    __syncthreads();

    // ---- Wo: waves 0-7, each a 16x16 col-unit, A-frags from LDS ----
    if (wave < 8) {
        const int lr = lane & 15;
        const int lk = (lane >> 4) * 8;
        const int n0 = wave * 16;
        f32x4 acc = {};
        const __hip_bfloat16* Wp = Wo_i + (size_t)(n0 + lr) * 128 + lk;
        #pragma unroll
        for (int k = 0; k < 128; k += 32) {
            const bf16x8 a = *reinterpret_cast<const bf16x8*>(&att[lr][lk + k]);
            const bf16x8 bb = *reinterpret_cast<const bf16x8*>(Wp + k);
            acc = __builtin_amdgcn_mfma_f32_16x16x32_bf16(a, bb, acc, 0, 0, 0);
        }
        const int orow = (lane >> 4) * 4;
        const int col  = n0 + lr;
        #pragma unroll
        for (int j = 0; j < 4; ++j)
            lds_wo[orow + j][col] = acc[j];
    }
    __syncthreads();

    // ---- LN1: 16 waves, one row each ----
    {
        const int rloc = wave;
        const int d0 = lane * 2;
        const size_t i0 = (size_t)(m0 + rloc) * D_DIM + d0;
        float v0 = x[i0]     + lds_wo[rloc][d0]     + bo_i[d0];
        float v1 = x[i0 + 1] + lds_wo[rloc][d0 + 1] + bo_i[d0 + 1];
        float s = v0 + v1;
        #pragma unroll
        for (int off = 32; off >= 1; off >>= 1) s += __shfl_xor(s, off);
        const float mu = s * (1.0f / 128.0f);
        const float q0 = v0 - mu, q1 = v1 - mu;
        float qs = q0 * q0 + q1 * q1;
        #pragma unroll
        for (int off = 32; off >= 1; off >>= 1) qs += __shfl_xor(qs, off);
        const float rs = rsqrtf(qs * (1.0f / 128.0f) + LN_EPS);
        const float r0 = q0 * rs * g[d0] + b[d0];
        const float r1 = q1 * rs * g[d0 + 1] + b[d0 + 1];
        x[i0] = r0;     x[i0 + 1] = r1;
        x_bf[i0] = __float2bfloat16(r0);
        x_bf[i0 + 1] = __float2bfloat16(r1);
    }
}

// ---------------------------------------------------------------------------
// FF1 -> LDS -> FF2-partial fused (proven R11). grid (64, FF2_KS), 256 thr.
// ---------------------------------------------------------------------------
__global__ __launch_bounds__(256) void ff_fused_kernel(
    const __hip_bfloat16* __restrict__ x_bf,
    const __hip_bfloat16* __restrict__ W1_i, const float* __restrict__ b1_i,
    const __hip_bfloat16* __restrict__ W2_i, float* __restrict__ P)
{
    __shared__ __hip_bfloat16 h[16][FF_KC + 8];   // 16 x 520 bf16 = 16.6 KB

    const int t    = threadIdx.x;
    const int wave = t >> 6;
    const int lane = t & 63;
    const int lr   = lane & 15;
    const int lk   = (lane >> 4) * 8;
    const int m0   = blockIdx.x * 16;
    const int kb   = blockIdx.y * FF_KC;   // h-col base == FF2 k base

    // ---- phase 1: FF1 (+bias+ReLU) -> LDS. 16 units of 16x32 over 4 waves.
    #pragma unroll
    for (int r = 0; r < FF_KC / 32 / 4; ++r) {
        const int u  = wave + r * 4;
        const int n0 = kb + u * 32;
        f32x4 acc[2] = {};
        mfma_tile<2>(x_bf, W1_i, 128, m0, n0, 0, 128, lane, acc);
        const int orow = (lane >> 4) * 4;
        #pragma unroll
        for (int hh = 0; hh < 2; ++hh) {
            const int colg = n0 + hh * 16 + lr;      // global col (bias)
            const int coll = colg - kb;              // local LDS col
            const float bv = b1_i[colg];
            #pragma unroll
            for (int j = 0; j < 4; ++j)
                h[orow + j][coll] =
                    __float2bfloat16(fmaxf(acc[hh][j] + bv, 0.f));
        }
    }
    __syncthreads();

    // ---- phase 2: FF2 partial [16 x 128], K = FF_KC from LDS ----
    {
        const int n0 = wave * 32;
        f32x4 acc[2] = {};
        const __hip_bfloat16* Wp = W2_i + (size_t)(n0 + lr) * FF_DIM + kb + lk;
        #pragma unroll 4
        for (int k = 0; k < FF_KC; k += 32) {
            const bf16x8 a = *reinterpret_cast<const bf16x8*>(&h[lr][lk + k]);
            #pragma unroll
            for (int nt = 0; nt < 2; ++nt) {
                const bf16x8 bb =
                    *reinterpret_cast<const bf16x8*>(Wp + (size_t)nt * 16 * FF_DIM + k);
                acc[nt] = __builtin_amdgcn_mfma_f32_16x16x32_bf16(a, bb, acc[nt], 0, 0, 0);
            }
        }
        float* Pz = P + (size_t)blockIdx.y * (S_LEN * D_DIM);
        const int orow = m0 + (lane >> 4) * 4;
        #pragma unroll
        for (int nt = 0; nt < 2; ++nt) {
            const int col = n0 + nt * 16 + lr;
            #pragma unroll
            for (int j = 0; j < 4; ++j)
                Pz[(size_t)(orow + j) * D_DIM + col] = acc[nt][j];
        }
    }
}

// ---------------------------------------------------------------------------
// LN2 (+FF2_KS partials + bias) then next-layer QKV (or out-proj if LAST).
// 64 blocks x 1024 thr (proven R10).
// ---------------------------------------------------------------------------
template<int LAST>
__global__ __launch_bounds__(1024, 1) void ln2_qkv_kernel(
    const float* __restrict__ P, const float* __restrict__ b2_i,
    float* __restrict__ x, __hip_bfloat16* __restrict__ x_bf,
    const float* __restrict__ g, const float* __restrict__ b,
    const __hip_bfloat16* __restrict__ Wn, const float* __restrict__ bn,
    __hip_bfloat16* __restrict__ qkv_bf, float* __restrict__ out)
{
    const int tid  = threadIdx.x;
    const int wave = tid >> 6;
    const int lane = tid & 63;
    const int m0   = blockIdx.x * 16;

    // ---- LN2: 16 waves, one row each ----
    {
        const int rloc = wave;
        const int d0 = lane * 2;
        const size_t i0 = (size_t)(m0 + rloc) * D_DIM + d0;
        float v0 = x[i0]     + b2_i[d0];
        float v1 = x[i0 + 1] + b2_i[d0 + 1];
        #pragma unroll
        for (int p = 0; p < FF2_KS; ++p) {
            v0 += P[(size_t)p * (S_LEN * D_DIM) + i0];
            v1 += P[(size_t)p * (S_LEN * D_DIM) + i0 + 1];
        }
        float s = v0 + v1;
        #pragma unroll
        for (int off = 32; off >= 1; off >>= 1) s += __shfl_xor(s, off);
        const float mu = s * (1.0f / 128.0f);
        const float q0 = v0 - mu, q1 = v1 - mu;
        float qs = q0 * q0 + q1 * q1;
        #pragma unroll
        for (int off = 32; off >= 1; off >>= 1) qs += __shfl_xor(qs, off);
        const float rs = rsqrtf(qs * (1.0f / 128.0f) + LN_EPS);
        const float r0 = q0 * rs * g[d0] + b[d0];
        const float r1 = q1 * rs * g[d0 + 1] + b[d0 + 1];
        x[i0] = r0;     x[i0 + 1] = r1;
        x_bf[i0] = __float2bfloat16(r0);
        x_bf[i0 + 1] = __float2bfloat16(r1);
    }
    __syncthreads();

    if (!LAST) {
        // next-layer QKV: 12 units, 16 waves -> single round
        if (wave < 12) {
            const int n0 = wave * 32;
            f32x4 acc[2] = {};
            mfma_tile<2>(x_bf, Wn, 128, m0, n0, 0, 128, lane, acc);
            const int orow = m0 + (lane >> 4) * 4;
            #pragma unroll
            for (int h = 0; h < 2; ++h) {
                const int col = n0 + h * 16 + (lane & 15);
                const float bv = bn[col];
                #pragma unroll
                for (int j = 0; j < 4; ++j)
                    qkv_bf[(size_t)(orow + j) * 384 + col] =
                        __float2bfloat16(acc[h][j] + bv);
            }
        }
    } else {
        // out-proj: 24 units over 16 waves -> <=2 rounds
        #pragma unroll
        for (int r = 0; r < 2; ++r) {
            const int u = wave + r * 16;
            if (u < 24) {
                const int n0 = u * 32;
                f32x4 acc[2] = {};
                mfma_tile<2>(x_bf, Wn, 128, m0, n0, 0, 128, lane, acc);
                const int orow = m0 + (lane >> 4) * 4;
                #pragma unroll
                for (int h = 0; h < 2; ++h) {
                    const int col = n0 + h * 16 + (lane & 15);
                    const float bv = bn[col];
                    #pragma unroll
                    for (int j = 0; j < 4; ++j)
                        out[(size_t)(orow + j) * HID_DIM + col] = acc[h][j] + bv;
                }
            }
        }
        if (tid < 16)
            out[(size_t)S_LEN * HID_DIM + m0 + tid] = 0.0f;
    }
}

// ---------------------------------------------------------------------------
// Host launch: 18 dispatches.
// ---------------------------------------------------------------------------
extern "C" void kernel_launch(void* const* d_in, const int* in_sizes, int n_in,
                              void* d_out, int out_size, void* d_ws, size_t ws_size,
                              hipStream_t stream)
{
    const int*   shot    = (const int*)  d_in[0];
    const int*   cam     = (const int*)  d_in[1];
    const int*   light   = (const int*)  d_in[2];
    const int*   tone    = (const int*)  d_in[3];
    const int*   rhythm  = (const int*)  d_in[4];
    const int*   trans   = (const int*)  d_in[5];
    const float* motion  = (const float*)d_in[6];
    const float* focus   = (const float*)d_in[7];
    const float* E_shot  = (const float*)d_in[8];
    const float* E_cam   = (const float*)d_in[9];
    const float* E_light = (const float*)d_in[10];
    const float* E_tone  = (const float*)d_in[11];
    const float* E_rhyth = (const float*)d_in[12];
    const float* E_trans = (const float*)d_in[13];
    const float* W_m1    = (const float*)d_in[14];
    const float* b_m1    = (const float*)d_in[15];
    const float* W_m2    = (const float*)d_in[16];
    const float* b_m2    = (const float*)d_in[17];
    const float* W_f     = (const float*)d_in[18];
    const float* b_f     = (const float*)d_in[19];
    const float* pos     = (const float*)d_in[20];
    const float* Wqkv    = (const float*)d_in[21];
    const float* bqkv    = (const float*)d_in[22];
    const float* Wo      = (const float*)d_in[23];
    const float* bo      = (const float*)d_in[24];
    const float* W1      = (const float*)d_in[25];
    const float* b1      = (const float*)d_in[26];
    const float* W2      = (const float*)d_in[27];
    const float* b2      = (const float*)d_in[28];
    const float* ln1_g   = (const float*)d_in[29];
    const float* ln1_b   = (const float*)d_in[30];
    const float* ln2_g   = (const float*)d_in[31];
    const float* ln2_b   = (const float*)d_in[32];
    const float* W_out   = (const float*)d_in[33];
    const float* b_out   = (const float*)d_in[34];

    float* out = (float*)d_out;

    // workspace layout
    float* ws = (float*)d_ws;
    float* x  = ws;                                 // 131072 f32
    float* pm = x  + S_LEN * D_DIM;                 // 65536
    float* pl = pm + ATT_KS * H_HEADS * S_LEN;      // 65536
    float* po = pl + ATT_KS * H_HEADS * S_LEN;      // 1048576
    float* P  = po + ATT_KS * H_HEADS * S_LEN * 16; // 4*131072 (FF2 partials)
    __hip_bfloat16* bfb = (__hip_bfloat16*)(P + FF2_KS * S_LEN * D_DIM);
    __hip_bfloat16* wqkv_bf = bfb;                  // [4][384][128]
    __hip_bfloat16* wo_bf   = wqkv_bf + 196608;     // [4][128][128]
    __hip_bfloat16* w1_bf   = wo_bf   + 65536;      // [4][2048][128]
    __hip_bfloat16* w2_bf   = w1_bf   + 1048576;    // [4][128][2048]
    __hip_bfloat16* wout_bf = w2_bf   + 1048576;    // [768][128]
    __hip_bfloat16* x_bf    = wout_bf + 98304;      // [1024][128]
    __hip_bfloat16* qkv_bf  = x_bf    + 131072;     // [1024][384]

    // 1) weights -> bf16
    wconv_kernel<<<2400, 256, 0, stream>>>(Wqkv, Wo, W1, W2, W_out, bfb);

    // 2) embed + layer-0 qkv
    embed_qkv_kernel<<<64, 1024, 0, stream>>>(
        shot, cam, light, tone, rhythm, trans, motion, focus,
        E_shot, E_cam, E_light, E_tone, E_rhyth, E_trans,
        W_m1, b_m1, W_m2, b_m2, W_f, b_f, pos,
        wqkv_bf, bqkv, x, x_bf, qkv_bf);

    // 3) layers: 4 dispatches each
    for (int li = 0; li < L_LAYERS; ++li) {
        const __hip_bfloat16* Wo_i = wo_bf + (size_t)li * D_DIM * D_DIM;
        const __hip_bfloat16* W1_i = w1_bf + (size_t)li * FF_DIM * D_DIM;
        const __hip_bfloat16* W2_i = w2_bf + (size_t)li * D_DIM * FF_DIM;
        const float* bo_i = bo + (size_t)li * D_DIM;
        const float* b1_i = b1 + (size_t)li * FF_DIM;
        const float* b2_i = b2 + (size_t)li * D_DIM;
        const float* l1g = ln1_g + (size_t)li * D_DIM;
        const float* l1b = ln1_b + (size_t)li * D_DIM;
        const float* l2g = ln2_g + (size_t)li * D_DIM;
        const float* l2b = ln2_b + (size_t)li * D_DIM;

        attn_part_kernel<<<dim3(ATT_KS, 4, H_HEADS), 256, 0, stream>>>(
            qkv_bf, pm, pl, po);

        comb_wo_ln1_kernel<<<64, 1024, 0, stream>>>(
            pm, pl, po, Wo_i, bo_i, x, x_bf, l1g, l1b);

        ff_fused_kernel<<<dim3(64, FF2_KS), 256, 0, stream>>>(
            x_bf, W1_i, b1_i, W2_i, P);

        if (li < L_LAYERS - 1) {
            const __hip_bfloat16* Wn = wqkv_bf + (size_t)(li + 1) * 3 * D_DIM * D_DIM;
            const float* bn = bqkv + (size_t)(li + 1) * 3 * D_DIM;
            ln2_qkv_kernel<0><<<64, 1024, 0, stream>>>(
                P, b2_i, x, x_bf, l2g, l2b, Wn, bn, qkv_bf, nullptr);
        } else {
            ln2_qkv_kernel<1><<<64, 1024, 0, stream>>>(
                P, b2_i, x, x_bf, l2g, l2b, wout_bf, b_out, nullptr, out);
        }
    }
}

// Round 13
// 203.666 us; speedup vs baseline: 1.3626x; 1.0227x over previous
//
#include <hip/hip_runtime.h>
#include <hip/hip_bf16.h>
#include <cstddef>
#include <math.h>

// ---------------------------------------------------------------------------
// Model constants
// ---------------------------------------------------------------------------
#define S_LEN 1024
#define D_DIM 128
#define H_HEADS 8
#define FF_DIM 2048
#define L_LAYERS 4
#define HID_DIM 768
#define LN_EPS 1e-5f

#define ATT_KS 8                  // attention K-split chunks
#define ATT_KCH (S_LEN / ATT_KS)  // 128 keys per chunk
#define FF2_KS 4                  // FF2 split-K chunks (fused kernel z-dim)
#define FF_KC (FF_DIM / FF2_KS)   // 512 h-cols per fused block

typedef __attribute__((ext_vector_type(8))) short bf16x8;
typedef __attribute__((ext_vector_type(4))) float f32x4;

// bf16 (as short bits) -> f32 : 16-bit left shift
__device__ __forceinline__ float bf16s_to_f(short s)
{
    return __uint_as_float(((unsigned int)(unsigned short)s) << 16);
}

// ---------------------------------------------------------------------------
// Wave-level MFMA tile: 16 rows x (NT*16) cols (proven fragment layout:
// A row = l&15, k-offset = (l>>4)*8; C/D row = (l>>4)*4+j, col = l&15).
// ---------------------------------------------------------------------------
template<int NT>
__device__ __forceinline__ void mfma_tile(
    const __hip_bfloat16* __restrict__ A, const __hip_bfloat16* __restrict__ W,
    int K, int m0, int n0, int kbeg, int kend, int lane, f32x4* acc)
{
    const int lr = lane & 15;
    const int lk = (lane >> 4) * 8;
    const __hip_bfloat16* Ap = A + (size_t)(m0 + lr) * K + lk;
    const __hip_bfloat16* Wp = W + (size_t)(n0 + lr) * K + lk;
    #pragma unroll 4
    for (int k = kbeg; k < kend; k += 32) {
        const bf16x8 a = *reinterpret_cast<const bf16x8*>(Ap + k);
        #pragma unroll
        for (int nt = 0; nt < NT; ++nt) {
            const bf16x8 b = *reinterpret_cast<const bf16x8*>(Wp + (size_t)nt * 16 * K + k);
            acc[nt] = __builtin_amdgcn_mfma_f32_16x16x32_bf16(a, b, acc[nt], 0, 0, 0);
        }
    }
}

// ---------------------------------------------------------------------------
// One-shot weight conversion fp32 -> bf16 (concatenated, proven).
// ---------------------------------------------------------------------------
__global__ __launch_bounds__(256) void wconv_kernel(
    const float* __restrict__ Wqkv, const float* __restrict__ Wo,
    const float* __restrict__ W1, const float* __restrict__ W2,
    const float* __restrict__ Wout, __hip_bfloat16* __restrict__ dst)
{
    const int i = blockIdx.x * 256 + threadIdx.x;   // float4 index, 0..614399
    const float* src;
    int off4;
    if (i < 49152)       { src = Wqkv; off4 = i; }
    else if (i < 65536)  { src = Wo;   off4 = i - 49152; }
    else if (i < 327680) { src = W1;   off4 = i - 65536; }
    else if (i < 589824) { src = W2;   off4 = i - 327680; }
    else                 { src = Wout; off4 = i - 589824; }
    const float4 v = reinterpret_cast<const float4*>(src)[off4];
    __hip_bfloat16* o = dst + (size_t)i * 4;
    o[0] = __float2bfloat16(v.x);
    o[1] = __float2bfloat16(v.y);
    o[2] = __float2bfloat16(v.z);
    o[3] = __float2bfloat16(v.w);
}

// ---------------------------------------------------------------------------
// embed + layer-0 QKV, fused (proven). 64 blocks x 1024 thr.
// ---------------------------------------------------------------------------
__global__ __launch_bounds__(1024, 1) void embed_qkv_kernel(
    const int* __restrict__ shot, const int* __restrict__ cam,
    const int* __restrict__ light, const int* __restrict__ tone,
    const int* __restrict__ rhythm, const int* __restrict__ trans,
    const float* __restrict__ motion, const float* __restrict__ focus,
    const float* __restrict__ E_shot, const float* __restrict__ E_cam,
    const float* __restrict__ E_light, const float* __restrict__ E_tone,
    const float* __restrict__ E_rhythm, const float* __restrict__ E_trans,
    const float* __restrict__ W_m1, const float* __restrict__ b_m1,
    const float* __restrict__ W_m2, const float* __restrict__ b_m2,
    const float* __restrict__ W_f, const float* __restrict__ b_f,
    const float* __restrict__ pos,
    const __hip_bfloat16* __restrict__ Wqkv0, const float* __restrict__ bqkv0,
    float* __restrict__ x, __hip_bfloat16* __restrict__ x_bf,
    __hip_bfloat16* __restrict__ qkv_bf)
{
    const int blk = blockIdx.x;
    const int tid = threadIdx.x;
    const int m0  = blk * 16;

    for (int e = tid; e < 16 * D_DIM; e += 1024) {
        const int s = m0 + (e >> 7);
        const int d = e & 127;
        const float4 mp = *reinterpret_cast<const float4*>(motion + s * 4);
        const float f0 = focus[s * 2 + 0], f1 = focus[s * 2 + 1];
        float acc = b_m2[d];
        const float* w2row = W_m2 + (size_t)d * 64;
        #pragma unroll 8
        for (int k2 = 0; k2 < 64; ++k2) {
            const float hk = b_m1[k2]
                + W_m1[k2 * 4 + 0] * mp.x + W_m1[k2 * 4 + 1] * mp.y
                + W_m1[k2 * 4 + 2] * mp.z + W_m1[k2 * 4 + 3] * mp.w;
            acc += w2row[k2] * fmaxf(hk, 0.0f);
        }
        acc += b_f[d] + W_f[d * 2 + 0] * f0 + W_f[d * 2 + 1] * f1;
        acc += E_shot  [(size_t)shot[s]   * D_DIM + d];
        acc += E_cam   [(size_t)cam[s]    * D_DIM + d];
        acc += E_light [(size_t)light[s]  * D_DIM + d];
        acc += E_tone  [(size_t)tone[s]   * D_DIM + d];
        acc += E_rhythm[(size_t)rhythm[s] * D_DIM + d];
        acc += E_trans [(size_t)trans[s]  * D_DIM + d];
        acc += pos[(size_t)s * D_DIM + d];
        const size_t gi = (size_t)s * D_DIM + d;
        x[gi] = acc;
        x_bf[gi] = __float2bfloat16(acc);
    }
    __syncthreads();

    const int wave = tid >> 6, lane = tid & 63;
    for (int u = wave; u < 12; u += 16) {
        const int n0 = u * 32;
        f32x4 acc[2] = {};
        mfma_tile<2>(x_bf, Wqkv0, 128, m0, n0, 0, 128, lane, acc);
        const int orow = m0 + (lane >> 4) * 4;
        #pragma unroll
        for (int h = 0; h < 2; ++h) {
            const int col = n0 + h * 16 + (lane & 15);
            const float bv = bqkv0[col];
            #pragma unroll
            for (int j = 0; j < 4; ++j)
                qkv_bf[(size_t)(orow + j) * 384 + col] =
                    __float2bfloat16(acc[h][j] + bv);
        }
    }
}

// ---------------------------------------------------------------------------
// Attention split-K partials, vectorized loads (proven R12). grid (8, 4, 8).
// ---------------------------------------------------------------------------
__global__ __launch_bounds__(256) void attn_part_kernel(
    const __hip_bfloat16* __restrict__ qkv,
    float* __restrict__ pm, float* __restrict__ pl, float* __restrict__ po)
{
    __shared__ float Ks[ATT_KCH * 16];
    __shared__ float Vs[ATT_KCH * 16];

    const int t     = threadIdx.x;
    const int chunk = blockIdx.x;
    const int qb    = blockIdx.y;
    const int head  = blockIdx.z;
    const int kbase = chunk * ATT_KCH;

    {
        const int row  = t >> 1;
        const int half = (t & 1) * 8;
        const __hip_bfloat16* src = qkv + (size_t)(kbase + row) * 384 + head * 16 + half;
        const bf16x8 k8 = *reinterpret_cast<const bf16x8*>(src + 128);
        const bf16x8 v8 = *reinterpret_cast<const bf16x8*>(src + 256);
        float* kd = &Ks[row * 16 + half];
        float* vd = &Vs[row * 16 + half];
        *reinterpret_cast<float4*>(kd) = make_float4(
            bf16s_to_f(k8[0]), bf16s_to_f(k8[1]), bf16s_to_f(k8[2]), bf16s_to_f(k8[3]));
        *reinterpret_cast<float4*>(kd + 4) = make_float4(
            bf16s_to_f(k8[4]), bf16s_to_f(k8[5]), bf16s_to_f(k8[6]), bf16s_to_f(k8[7]));
        *reinterpret_cast<float4*>(vd) = make_float4(
            bf16s_to_f(v8[0]), bf16s_to_f(v8[1]), bf16s_to_f(v8[2]), bf16s_to_f(v8[3]));
        *reinterpret_cast<float4*>(vd + 4) = make_float4(
            bf16s_to_f(v8[4]), bf16s_to_f(v8[5]), bf16s_to_f(v8[6]), bf16s_to_f(v8[7]));
    }

    const int qrow = qb * 256 + t;
    float q[16];
    {
        const __hip_bfloat16* qp = qkv + (size_t)qrow * 384 + head * 16;
        const bf16x8 q0 = *reinterpret_cast<const bf16x8*>(qp);
        const bf16x8 q1 = *reinterpret_cast<const bf16x8*>(qp + 8);
        #pragma unroll
        for (int d = 0; d < 8; ++d) {
            q[d]     = bf16s_to_f(q0[d]) * 0.25f;
            q[d + 8] = bf16s_to_f(q1[d]) * 0.25f;
        }
    }
    __syncthreads();

    float m = -INFINITY, l = 0.f;
    float O[16];
    #pragma unroll
    for (int d = 0; d < 16; ++d) O[d] = 0.f;

    for (int j0 = 0; j0 < ATT_KCH; j0 += 8) {
        float sv[8];
        #pragma unroll
        for (int jj = 0; jj < 8; ++jj) {
            const float* kr = &Ks[(j0 + jj) * 16];
            const float4 k0 = *reinterpret_cast<const float4*>(kr);
            const float4 k1 = *reinterpret_cast<const float4*>(kr + 4);
            const float4 k2 = *reinterpret_cast<const float4*>(kr + 8);
            const float4 k3 = *reinterpret_cast<const float4*>(kr + 12);
            sv[jj] = q[0] * k0.x + q[1] * k0.y + q[2] * k0.z + q[3] * k0.w
                   + q[4] * k1.x + q[5] * k1.y + q[6] * k1.z + q[7] * k1.w
                   + q[8] * k2.x + q[9] * k2.y + q[10] * k2.z + q[11] * k2.w
                   + q[12] * k3.x + q[13] * k3.y + q[14] * k3.z + q[15] * k3.w;
        }
        float bm = sv[0];
        #pragma unroll
        for (int jj = 1; jj < 8; ++jj) bm = fmaxf(bm, sv[jj]);
        const float mn = fmaxf(m, bm);
        const float corr = __expf(m - mn);
        m = mn;
        l *= corr;
        #pragma unroll
        for (int d = 0; d < 16; ++d) O[d] *= corr;
        #pragma unroll
        for (int jj = 0; jj < 8; ++jj) {
            const float p = __expf(sv[jj] - m);
            l += p;
            const float* vr = &Vs[(j0 + jj) * 16];
            const float4 v0 = *reinterpret_cast<const float4*>(vr);
            const float4 v1 = *reinterpret_cast<const float4*>(vr + 4);
            const float4 v2 = *reinterpret_cast<const float4*>(vr + 8);
            const float4 v3 = *reinterpret_cast<const float4*>(vr + 12);
            O[0]  += p * v0.x; O[1]  += p * v0.y; O[2]  += p * v0.z; O[3]  += p * v0.w;
            O[4]  += p * v1.x; O[5]  += p * v1.y; O[6]  += p * v1.z; O[7]  += p * v1.w;
            O[8]  += p * v2.x; O[9]  += p * v2.y; O[10] += p * v2.z; O[11] += p * v2.w;
            O[12] += p * v3.x; O[13] += p * v3.y; O[14] += p * v3.z; O[15] += p * v3.w;
        }
    }

    const int pidx = ((chunk * H_HEADS + head) << 10) + qrow;
    pm[pidx] = m;
    pl[pidx] = l;
    #pragma unroll
    for (int d = 0; d < 16; d += 4)
        *reinterpret_cast<float4*>(&po[(size_t)pidx * 16 + d]) =
            make_float4(O[d], O[d + 1], O[d + 2], O[d + 3]);
}

// ---------------------------------------------------------------------------
// tail1: comb + Wo + residual + LN1 + FF1 + FF2-partial, all in one kernel.
// grid (64 m-tiles, FF2_KS z) = 256 blocks x 256 thr (4 waves).
// The comb/Wo/LN1 front is replicated across the 4 z-blocks of an m-tile
// (cheap); post-LN1 activations stay in LDS (xb) and feed FF1 directly.
// Residual ping-pong: reads x_in (pre-LN1 stream), writes x2 (post-LN1
// residual for LN2). All z-blocks write identical x2 values (benign).
// ---------------------------------------------------------------------------
__global__ __launch_bounds__(256) void tail1_kernel(
    const float* __restrict__ pm, const float* __restrict__ pl,
    const float* __restrict__ po,
    const __hip_bfloat16* __restrict__ Wo_i, const float* __restrict__ bo_i,
    const float* __restrict__ x_in, float* __restrict__ x2,
    const float* __restrict__ g, const float* __restrict__ b,
    const __hip_bfloat16* __restrict__ W1_i, const float* __restrict__ b1_i,
    const __hip_bfloat16* __restrict__ W2_i, float* __restrict__ P)
{
    __shared__ __hip_bfloat16 att[16][136];     // combined attn rows (bf16)
    __shared__ float lds_wo[16][132];           // Wo output (f32)
    __shared__ __hip_bfloat16 xb[16][136];      // post-LN1 rows (bf16)
    __shared__ __hip_bfloat16 h[16][FF_KC + 8]; // FF1 output (bf16)

    const int t    = threadIdx.x;
    const int wave = t >> 6;
    const int lane = t & 63;
    const int lr   = lane & 15;
    const int lk   = (lane >> 4) * 8;
    const int m0   = blockIdx.x * 16;
    const int kb   = blockIdx.y * FF_KC;

    // ---- A: combine attention partials (128 units x 2 thr, 8 elems each) ----
    {
        const int unit = t >> 1;              // 0..127 = (rloc, head)
        const int rloc = unit >> 3;
        const int head = unit & 7;
        const int row  = m0 + rloc;
        const int d0   = (t & 1) * 8;

        float mg = -INFINITY;
        #pragma unroll
        for (int c = 0; c < ATT_KS; ++c)
            mg = fmaxf(mg, pm[((c * H_HEADS + head) << 10) + row]);
        float lg = 0.f;
        float O[8];
        #pragma unroll
        for (int d = 0; d < 8; ++d) O[d] = 0.f;
        #pragma unroll
        for (int c = 0; c < ATT_KS; ++c) {
            const int pidx = ((c * H_HEADS + head) << 10) + row;
            const float w = __expf(pm[pidx] - mg);
            lg += pl[pidx] * w;
            const float4 a0 = *reinterpret_cast<const float4*>(&po[(size_t)pidx * 16 + d0]);
            const float4 a1 = *reinterpret_cast<const float4*>(&po[(size_t)pidx * 16 + d0 + 4]);
            O[0] += w * a0.x; O[1] += w * a0.y; O[2] += w * a0.z; O[3] += w * a0.w;
            O[4] += w * a1.x; O[5] += w * a1.y; O[6] += w * a1.z; O[7] += w * a1.w;
        }
        const float inv = 1.f / lg;
        #pragma unroll
        for (int d = 0; d < 8; ++d)
            att[rloc][head * 16 + d0 + d] = __float2bfloat16(O[d] * inv);
    }
    __syncthreads();

    // ---- B: Wo (8 col-units of 16 over 4 waves = 2 rounds) ----
    #pragma unroll
    for (int r = 0; r < 2; ++r) {
        const int n0 = (wave + r * 4) * 16;
        f32x4 acc = {};
        const __hip_bfloat16* Wp = Wo_i + (size_t)(n0 + lr) * 128 + lk;
        #pragma unroll
        for (int k = 0; k < 128; k += 32) {
            const bf16x8 a = *reinterpret_cast<const bf16x8*>(&att[lr][lk + k]);
            const bf16x8 bb = *reinterpret_cast<const bf16x8*>(Wp + k);
            acc = __builtin_amdgcn_mfma_f32_16x16x32_bf16(a, bb, acc, 0, 0, 0);
        }
        const int orow = (lane >> 4) * 4;
        const int col  = n0 + lr;
        #pragma unroll
        for (int j = 0; j < 4; ++j)
            lds_wo[orow + j][col] = acc[j];
    }
    __syncthreads();

    // ---- C: residual + LN1 (16 rows over 4 waves = 4 rounds) ----
    #pragma unroll
    for (int rr = 0; rr < 4; ++rr) {
        const int rloc = wave + rr * 4;
        const int d0 = lane * 2;
        const size_t i0 = (size_t)(m0 + rloc) * D_DIM + d0;
        float v0 = x_in[i0]     + lds_wo[rloc][d0]     + bo_i[d0];
        float v1 = x_in[i0 + 1] + lds_wo[rloc][d0 + 1] + bo_i[d0 + 1];
        float s = v0 + v1;
        #pragma unroll
        for (int off = 32; off >= 1; off >>= 1) s += __shfl_xor(s, off);
        const float mu = s * (1.0f / 128.0f);
        const float q0 = v0 - mu, q1 = v1 - mu;
        float qs = q0 * q0 + q1 * q1;
        #pragma unroll
        for (int off = 32; off >= 1; off >>= 1) qs += __shfl_xor(qs, off);
        const float rs = rsqrtf(qs * (1.0f / 128.0f) + LN_EPS);
        const float r0 = q0 * rs * g[d0] + b[d0];
        const float r1 = q1 * rs * g[d0 + 1] + b[d0 + 1];
        x2[i0] = r0;     x2[i0 + 1] = r1;
        xb[rloc][d0] = __float2bfloat16(r0);
        xb[rloc][d0 + 1] = __float2bfloat16(r1);
    }
    __syncthreads();

    // ---- D: FF1 (+bias+ReLU) from LDS xb -> LDS h (16 units / 4 waves) ----
    #pragma unroll
    for (int r = 0; r < 4; ++r) {
        const int n0 = kb + (wave + r * 4) * 32;
        f32x4 acc[2] = {};
        const __hip_bfloat16* Wp = W1_i + (size_t)(n0 + lr) * 128 + lk;
        #pragma unroll
        for (int k = 0; k < 128; k += 32) {
            const bf16x8 a = *reinterpret_cast<const bf16x8*>(&xb[lr][lk + k]);
            #pragma unroll
            for (int nt = 0; nt < 2; ++nt) {
                const bf16x8 bb = *reinterpret_cast<const bf16x8*>(Wp + (size_t)nt * 16 * 128 + k);
                acc[nt] = __builtin_amdgcn_mfma_f32_16x16x32_bf16(a, bb, acc[nt], 0, 0, 0);
            }
        }
        const int orow = (lane >> 4) * 4;
        #pragma unroll
        for (int hh = 0; hh < 2; ++hh) {
            const int colg = n0 + hh * 16 + lr;      // global col (bias)
            const int coll = colg - kb;              // local LDS col
            const float bv = b1_i[colg];
            #pragma unroll
            for (int j = 0; j < 4; ++j)
                h[orow + j][coll] =
                    __float2bfloat16(fmaxf(acc[hh][j] + bv, 0.f));
        }
    }
    __syncthreads();

    // ---- E: FF2 partial [16 x 128], K = FF_KC from LDS -> P[z] ----
    {
        const int n0 = wave * 32;
        f32x4 acc[2] = {};
        const __hip_bfloat16* Wp = W2_i + (size_t)(n0 + lr) * FF_DIM + kb + lk;
        #pragma unroll 4
        for (int k = 0; k < FF_KC; k += 32) {
            const bf16x8 a = *reinterpret_cast<const bf16x8*>(&h[lr][lk + k]);
            #pragma unroll
            for (int nt = 0; nt < 2; ++nt) {
                const bf16x8 bb =
                    *reinterpret_cast<const bf16x8*>(Wp + (size_t)nt * 16 * FF_DIM + k);
                acc[nt] = __builtin_amdgcn_mfma_f32_16x16x32_bf16(a, bb, acc[nt], 0, 0, 0);
            }
        }
        float* Pz = P + (size_t)blockIdx.y * (S_LEN * D_DIM);
        const int orow = m0 + (lane >> 4) * 4;
        #pragma unroll
        for (int nt = 0; nt < 2; ++nt) {
            const int col = n0 + nt * 16 + lr;
            #pragma unroll
            for (int j = 0; j < 4; ++j)
                Pz[(size_t)(orow + j) * D_DIM + col] = acc[nt][j];
        }
    }
}

// ---------------------------------------------------------------------------
// LN2 (+FF2_KS partials + bias) then next-layer QKV (or out-proj if LAST).
// 64 blocks x 1024 thr. Residual ping-pong: reads xr (=x2), writes xw (=x).
// ---------------------------------------------------------------------------
template<int LAST>
__global__ __launch_bounds__(1024, 1) void ln2_qkv_kernel(
    const float* __restrict__ P, const float* __restrict__ b2_i,
    const float* __restrict__ xr, float* __restrict__ xw,
    __hip_bfloat16* __restrict__ x_bf,
    const float* __restrict__ g, const float* __restrict__ b,
    const __hip_bfloat16* __restrict__ Wn, const float* __restrict__ bn,
    __hip_bfloat16* __restrict__ qkv_bf, float* __restrict__ out)
{
    const int tid  = threadIdx.x;
    const int wave = tid >> 6;
    const int lane = tid & 63;
    const int m0   = blockIdx.x * 16;

    // ---- LN2: 16 waves, one row each ----
    {
        const int rloc = wave;
        const int d0 = lane * 2;
        const size_t i0 = (size_t)(m0 + rloc) * D_DIM + d0;
        float v0 = xr[i0]     + b2_i[d0];
        float v1 = xr[i0 + 1] + b2_i[d0 + 1];
        #pragma unroll
        for (int p = 0; p < FF2_KS; ++p) {
            v0 += P[(size_t)p * (S_LEN * D_DIM) + i0];
            v1 += P[(size_t)p * (S_LEN * D_DIM) + i0 + 1];
        }
        float s = v0 + v1;
        #pragma unroll
        for (int off = 32; off >= 1; off >>= 1) s += __shfl_xor(s, off);
        const float mu = s * (1.0f / 128.0f);
        const float q0 = v0 - mu, q1 = v1 - mu;
        float qs = q0 * q0 + q1 * q1;
        #pragma unroll
        for (int off = 32; off >= 1; off >>= 1) qs += __shfl_xor(qs, off);
        const float rs = rsqrtf(qs * (1.0f / 128.0f) + LN_EPS);
        const float r0 = q0 * rs * g[d0] + b[d0];
        const float r1 = q1 * rs * g[d0 + 1] + b[d0 + 1];
        xw[i0] = r0;     xw[i0 + 1] = r1;
        x_bf[i0] = __float2bfloat16(r0);
        x_bf[i0 + 1] = __float2bfloat16(r1);
    }
    __syncthreads();

    if (!LAST) {
        // next-layer QKV: 12 units, 16 waves -> single round
        if (wave < 12) {
            const int n0 = wave * 32;
            f32x4 acc[2] = {};
            mfma_tile<2>(x_bf, Wn, 128, m0, n0, 0, 128, lane, acc);
            const int orow = m0 + (lane >> 4) * 4;
            #pragma unroll
            for (int h = 0; h < 2; ++h) {
                const int col = n0 + h * 16 + (lane & 15);
                const float bv = bn[col];
                #pragma unroll
                for (int j = 0; j < 4; ++j)
                    qkv_bf[(size_t)(orow + j) * 384 + col] =
                        __float2bfloat16(acc[h][j] + bv);
            }
        }
    } else {
        // out-proj: 24 units over 16 waves -> <=2 rounds
        #pragma unroll
        for (int r = 0; r < 2; ++r) {
            const int u = wave + r * 16;
            if (u < 24) {
                const int n0 = u * 32;
                f32x4 acc[2] = {};
                mfma_tile<2>(x_bf, Wn, 128, m0, n0, 0, 128, lane, acc);
                const int orow = m0 + (lane >> 4) * 4;
                #pragma unroll
                for (int h = 0; h < 2; ++h) {
                    const int col = n0 + h * 16 + (lane & 15);
                    const float bv = bn[col];
                    #pragma unroll
                    for (int j = 0; j < 4; ++j)
                        out[(size_t)(orow + j) * HID_DIM + col] = acc[h][j] + bv;
                }
            }
        }
        if (tid < 16)
            out[(size_t)S_LEN * HID_DIM + m0 + tid] = 0.0f;
    }
}

// ---------------------------------------------------------------------------
// Host launch: 14 dispatches.
// ---------------------------------------------------------------------------
extern "C" void kernel_launch(void* const* d_in, const int* in_sizes, int n_in,
                              void* d_out, int out_size, void* d_ws, size_t ws_size,
                              hipStream_t stream)
{
    const int*   shot    = (const int*)  d_in[0];
    const int*   cam     = (const int*)  d_in[1];
    const int*   light   = (const int*)  d_in[2];
    const int*   tone    = (const int*)  d_in[3];
    const int*   rhythm  = (const int*)  d_in[4];
    const int*   trans   = (const int*)  d_in[5];
    const float* motion  = (const float*)d_in[6];
    const float* focus   = (const float*)d_in[7];
    const float* E_shot  = (const float*)d_in[8];
    const float* E_cam   = (const float*)d_in[9];
    const float* E_light = (const float*)d_in[10];
    const float* E_tone  = (const float*)d_in[11];
    const float* E_rhyth = (const float*)d_in[12];
    const float* E_trans = (const float*)d_in[13];
    const float* W_m1    = (const float*)d_in[14];
    const float* b_m1    = (const float*)d_in[15];
    const float* W_m2    = (const float*)d_in[16];
    const float* b_m2    = (const float*)d_in[17];
    const float* W_f     = (const float*)d_in[18];
    const float* b_f     = (const float*)d_in[19];
    const float* pos     = (const float*)d_in[20];
    const float* Wqkv    = (const float*)d_in[21];
    const float* bqkv    = (const float*)d_in[22];
    const float* Wo      = (const float*)d_in[23];
    const float* bo      = (const float*)d_in[24];
    const float* W1      = (const float*)d_in[25];
    const float* b1      = (const float*)d_in[26];
    const float* W2      = (const float*)d_in[27];
    const float* b2      = (const float*)d_in[28];
    const float* ln1_g   = (const float*)d_in[29];
    const float* ln1_b   = (const float*)d_in[30];
    const float* ln2_g   = (const float*)d_in[31];
    const float* ln2_b   = (const float*)d_in[32];
    const float* W_out   = (const float*)d_in[33];
    const float* b_out   = (const float*)d_in[34];

    float* out = (float*)d_out;

    // workspace layout
    float* ws = (float*)d_ws;
    float* x  = ws;                                 // 131072 f32 (pre-LN1 residual)
    float* x2 = x + S_LEN * D_DIM;                  // 131072 f32 (post-LN1 residual)
    float* pm = x2 + S_LEN * D_DIM;                 // 65536
    float* pl = pm + ATT_KS * H_HEADS * S_LEN;      // 65536
    float* po = pl + ATT_KS * H_HEADS * S_LEN;      // 1048576
    float* P  = po + ATT_KS * H_HEADS * S_LEN * 16; // 4*131072 (FF2 partials)
    __hip_bfloat16* bfb = (__hip_bfloat16*)(P + FF2_KS * S_LEN * D_DIM);
    __hip_bfloat16* wqkv_bf = bfb;                  // [4][384][128]
    __hip_bfloat16* wo_bf   = wqkv_bf + 196608;     // [4][128][128]
    __hip_bfloat16* w1_bf   = wo_bf   + 65536;      // [4][2048][128]
    __hip_bfloat16* w2_bf   = w1_bf   + 1048576;    // [4][128][2048]
    __hip_bfloat16* wout_bf = w2_bf   + 1048576;    // [768][128]
    __hip_bfloat16* x_bf    = wout_bf + 98304;      // [1024][128]
    __hip_bfloat16* qkv_bf  = x_bf    + 131072;     // [1024][384]

    // 1) weights -> bf16
    wconv_kernel<<<2400, 256, 0, stream>>>(Wqkv, Wo, W1, W2, W_out, bfb);

    // 2) embed + layer-0 qkv
    embed_qkv_kernel<<<64, 1024, 0, stream>>>(
        shot, cam, light, tone, rhythm, trans, motion, focus,
        E_shot, E_cam, E_light, E_tone, E_rhyth, E_trans,
        W_m1, b_m1, W_m2, b_m2, W_f, b_f, pos,
        wqkv_bf, bqkv, x, x_bf, qkv_bf);

    // 3) layers: 3 dispatches each
    for (int li = 0; li < L_LAYERS; ++li) {
        const __hip_bfloat16* Wo_i = wo_bf + (size_t)li * D_DIM * D_DIM;
        const __hip_bfloat16* W1_i = w1_bf + (size_t)li * FF_DIM * D_DIM;
        const __hip_bfloat16* W2_i = w2_bf + (size_t)li * D_DIM * FF_DIM;
        const float* bo_i = bo + (size_t)li * D_DIM;
        const float* b1_i = b1 + (size_t)li * FF_DIM;
        const float* b2_i = b2 + (size_t)li * D_DIM;
        const float* l1g = ln1_g + (size_t)li * D_DIM;
        const float* l1b = ln1_b + (size_t)li * D_DIM;
        const float* l2g = ln2_g + (size_t)li * D_DIM;
        const float* l2b = ln2_b + (size_t)li * D_DIM;

        attn_part_kernel<<<dim3(ATT_KS, 4, H_HEADS), 256, 0, stream>>>(
            qkv_bf, pm, pl, po);

        tail1_kernel<<<dim3(64, FF2_KS), 256, 0, stream>>>(
            pm, pl, po, Wo_i, bo_i, x, x2, l1g, l1b, W1_i, b1_i, W2_i, P);

        if (li < L_LAYERS - 1) {
            const __hip_bfloat16* Wn = wqkv_bf + (size_t)(li + 1) * 3 * D_DIM * D_DIM;
            const float* bn = bqkv + (size_t)(li + 1) * 3 * D_DIM;
            ln2_qkv_kernel<0><<<64, 1024, 0, stream>>>(
                P, b2_i, x2, x, x_bf, l2g, l2b, Wn, bn, qkv_bf, nullptr);
        } else {
            ln2_qkv_kernel<1><<<64, 1024, 0, stream>>>(
                P, b2_i, x2, x, x_bf, l2g, l2b, wout_bf, b_out, nullptr, out);
        }
    }
}

// Round 14
// 193.286 us; speedup vs baseline: 1.4357x; 1.0537x over previous
//
#include <hip/hip_runtime.h>
#include <hip/hip_bf16.h>
#include <cstddef>
#include <math.h>

// ---------------------------------------------------------------------------
// Model constants
// ---------------------------------------------------------------------------
#define S_LEN 1024
#define D_DIM 128
#define H_HEADS 8
#define FF_DIM 2048
#define L_LAYERS 4
#define HID_DIM 768
#define LN_EPS 1e-5f

#define ATT_KS 16                 // attention K-split chunks (2 waves/SIMD)
#define ATT_KCH (S_LEN / ATT_KS)  // 64 keys per chunk
#define FF2_KS 4                  // FF2 split-K chunks (fused kernel z-dim)
#define FF_KC (FF_DIM / FF2_KS)   // 512 h-cols per fused block

typedef __attribute__((ext_vector_type(8))) short bf16x8;
typedef __attribute__((ext_vector_type(4))) float f32x4;

// bf16 (as short bits) -> f32 : 16-bit left shift
__device__ __forceinline__ float bf16s_to_f(short s)
{
    return __uint_as_float(((unsigned int)(unsigned short)s) << 16);
}

// ---------------------------------------------------------------------------
// Wave-level MFMA tile: 16 rows x (NT*16) cols (proven fragment layout:
// A row = l&15, k-offset = (l>>4)*8; C/D row = (l>>4)*4+j, col = l&15).
// ---------------------------------------------------------------------------
template<int NT>
__device__ __forceinline__ void mfma_tile(
    const __hip_bfloat16* __restrict__ A, const __hip_bfloat16* __restrict__ W,
    int K, int m0, int n0, int kbeg, int kend, int lane, f32x4* acc)
{
    const int lr = lane & 15;
    const int lk = (lane >> 4) * 8;
    const __hip_bfloat16* Ap = A + (size_t)(m0 + lr) * K + lk;
    const __hip_bfloat16* Wp = W + (size_t)(n0 + lr) * K + lk;
    #pragma unroll 4
    for (int k = kbeg; k < kend; k += 32) {
        const bf16x8 a = *reinterpret_cast<const bf16x8*>(Ap + k);
        #pragma unroll
        for (int nt = 0; nt < NT; ++nt) {
            const bf16x8 b = *reinterpret_cast<const bf16x8*>(Wp + (size_t)nt * 16 * K + k);
            acc[nt] = __builtin_amdgcn_mfma_f32_16x16x32_bf16(a, b, acc[nt], 0, 0, 0);
        }
    }
}

// ---------------------------------------------------------------------------
// One-shot weight conversion fp32 -> bf16 (concatenated, proven).
// ---------------------------------------------------------------------------
__global__ __launch_bounds__(256) void wconv_kernel(
    const float* __restrict__ Wqkv, const float* __restrict__ Wo,
    const float* __restrict__ W1, const float* __restrict__ W2,
    const float* __restrict__ Wout, __hip_bfloat16* __restrict__ dst)
{
    const int i = blockIdx.x * 256 + threadIdx.x;   // float4 index, 0..614399
    const float* src;
    int off4;
    if (i < 49152)       { src = Wqkv; off4 = i; }
    else if (i < 65536)  { src = Wo;   off4 = i - 49152; }
    else if (i < 327680) { src = W1;   off4 = i - 65536; }
    else if (i < 589824) { src = W2;   off4 = i - 327680; }
    else                 { src = Wout; off4 = i - 589824; }
    const float4 v = reinterpret_cast<const float4*>(src)[off4];
    __hip_bfloat16* o = dst + (size_t)i * 4;
    o[0] = __float2bfloat16(v.x);
    o[1] = __float2bfloat16(v.y);
    o[2] = __float2bfloat16(v.z);
    o[3] = __float2bfloat16(v.w);
}

// ---------------------------------------------------------------------------
// embed + layer-0 QKV, fused (proven). 64 blocks x 1024 thr.
// ---------------------------------------------------------------------------
__global__ __launch_bounds__(1024, 1) void embed_qkv_kernel(
    const int* __restrict__ shot, const int* __restrict__ cam,
    const int* __restrict__ light, const int* __restrict__ tone,
    const int* __restrict__ rhythm, const int* __restrict__ trans,
    const float* __restrict__ motion, const float* __restrict__ focus,
    const float* __restrict__ E_shot, const float* __restrict__ E_cam,
    const float* __restrict__ E_light, const float* __restrict__ E_tone,
    const float* __restrict__ E_rhythm, const float* __restrict__ E_trans,
    const float* __restrict__ W_m1, const float* __restrict__ b_m1,
    const float* __restrict__ W_m2, const float* __restrict__ b_m2,
    const float* __restrict__ W_f, const float* __restrict__ b_f,
    const float* __restrict__ pos,
    const __hip_bfloat16* __restrict__ Wqkv0, const float* __restrict__ bqkv0,
    float* __restrict__ x, __hip_bfloat16* __restrict__ x_bf,
    __hip_bfloat16* __restrict__ qkv_bf)
{
    const int blk = blockIdx.x;
    const int tid = threadIdx.x;
    const int m0  = blk * 16;

    for (int e = tid; e < 16 * D_DIM; e += 1024) {
        const int s = m0 + (e >> 7);
        const int d = e & 127;
        const float4 mp = *reinterpret_cast<const float4*>(motion + s * 4);
        const float f0 = focus[s * 2 + 0], f1 = focus[s * 2 + 1];
        float acc = b_m2[d];
        const float* w2row = W_m2 + (size_t)d * 64;
        #pragma unroll 8
        for (int k2 = 0; k2 < 64; ++k2) {
            const float hk = b_m1[k2]
                + W_m1[k2 * 4 + 0] * mp.x + W_m1[k2 * 4 + 1] * mp.y
                + W_m1[k2 * 4 + 2] * mp.z + W_m1[k2 * 4 + 3] * mp.w;
            acc += w2row[k2] * fmaxf(hk, 0.0f);
        }
        acc += b_f[d] + W_f[d * 2 + 0] * f0 + W_f[d * 2 + 1] * f1;
        acc += E_shot  [(size_t)shot[s]   * D_DIM + d];
        acc += E_cam   [(size_t)cam[s]    * D_DIM + d];
        acc += E_light [(size_t)light[s]  * D_DIM + d];
        acc += E_tone  [(size_t)tone[s]   * D_DIM + d];
        acc += E_rhythm[(size_t)rhythm[s] * D_DIM + d];
        acc += E_trans [(size_t)trans[s]  * D_DIM + d];
        acc += pos[(size_t)s * D_DIM + d];
        const size_t gi = (size_t)s * D_DIM + d;
        x[gi] = acc;
        x_bf[gi] = __float2bfloat16(acc);
    }
    __syncthreads();

    const int wave = tid >> 6, lane = tid & 63;
    for (int u = wave; u < 12; u += 16) {
        const int n0 = u * 32;
        f32x4 acc[2] = {};
        mfma_tile<2>(x_bf, Wqkv0, 128, m0, n0, 0, 128, lane, acc);
        const int orow = m0 + (lane >> 4) * 4;
        #pragma unroll
        for (int h = 0; h < 2; ++h) {
            const int col = n0 + h * 16 + (lane & 15);
            const float bv = bqkv0[col];
            #pragma unroll
            for (int j = 0; j < 4; ++j)
                qkv_bf[(size_t)(orow + j) * 384 + col] =
                    __float2bfloat16(acc[h][j] + bv);
        }
    }
}

// ---------------------------------------------------------------------------
// Attention split-K partials. ATT_KS=16 -> grid (16, 4, 8) = 512 blocks
// (2 blocks/CU, 2 waves/SIMD). Vectorized staging (proven R12 pattern).
// ---------------------------------------------------------------------------
__global__ __launch_bounds__(256) void attn_part_kernel(
    const __hip_bfloat16* __restrict__ qkv,
    float* __restrict__ pm, float* __restrict__ pl, float* __restrict__ po)
{
    __shared__ float Ks[ATT_KCH * 16];
    __shared__ float Vs[ATT_KCH * 16];

    const int t     = threadIdx.x;
    const int chunk = blockIdx.x;
    const int qb    = blockIdx.y;
    const int head  = blockIdx.z;
    const int kbase = chunk * ATT_KCH;

    {
        // 64 rows x 4 parts (K-lo, K-hi, V-lo, V-hi), one bf16x8 per thread
        const int row  = t >> 2;
        const int part = t & 3;
        const int half = (part & 1) * 8;
        const int koff = (part < 2) ? 128 : 256;
        const __hip_bfloat16* src =
            qkv + (size_t)(kbase + row) * 384 + head * 16 + half + koff;
        const bf16x8 v8 = *reinterpret_cast<const bf16x8*>(src);
        float* dst = (part < 2) ? &Ks[row * 16 + half] : &Vs[row * 16 + half];
        *reinterpret_cast<float4*>(dst) = make_float4(
            bf16s_to_f(v8[0]), bf16s_to_f(v8[1]), bf16s_to_f(v8[2]), bf16s_to_f(v8[3]));
        *reinterpret_cast<float4*>(dst + 4) = make_float4(
            bf16s_to_f(v8[4]), bf16s_to_f(v8[5]), bf16s_to_f(v8[6]), bf16s_to_f(v8[7]));
    }

    const int qrow = qb * 256 + t;
    float q[16];
    {
        const __hip_bfloat16* qp = qkv + (size_t)qrow * 384 + head * 16;
        const bf16x8 q0 = *reinterpret_cast<const bf16x8*>(qp);
        const bf16x8 q1 = *reinterpret_cast<const bf16x8*>(qp + 8);
        #pragma unroll
        for (int d = 0; d < 8; ++d) {
            q[d]     = bf16s_to_f(q0[d]) * 0.25f;
            q[d + 8] = bf16s_to_f(q1[d]) * 0.25f;
        }
    }
    __syncthreads();

    float m = -INFINITY, l = 0.f;
    float O[16];
    #pragma unroll
    for (int d = 0; d < 16; ++d) O[d] = 0.f;

    for (int j0 = 0; j0 < ATT_KCH; j0 += 8) {
        float sv[8];
        #pragma unroll
        for (int jj = 0; jj < 8; ++jj) {
            const float* kr = &Ks[(j0 + jj) * 16];
            const float4 k0 = *reinterpret_cast<const float4*>(kr);
            const float4 k1 = *reinterpret_cast<const float4*>(kr + 4);
            const float4 k2 = *reinterpret_cast<const float4*>(kr + 8);
            const float4 k3 = *reinterpret_cast<const float4*>(kr + 12);
            sv[jj] = q[0] * k0.x + q[1] * k0.y + q[2] * k0.z + q[3] * k0.w
                   + q[4] * k1.x + q[5] * k1.y + q[6] * k1.z + q[7] * k1.w
                   + q[8] * k2.x + q[9] * k2.y + q[10] * k2.z + q[11] * k2.w
                   + q[12] * k3.x + q[13] * k3.y + q[14] * k3.z + q[15] * k3.w;
        }
        float bm = sv[0];
        #pragma unroll
        for (int jj = 1; jj < 8; ++jj) bm = fmaxf(bm, sv[jj]);
        const float mn = fmaxf(m, bm);
        const float corr = __expf(m - mn);
        m = mn;
        l *= corr;
        #pragma unroll
        for (int d = 0; d < 16; ++d) O[d] *= corr;
        #pragma unroll
        for (int jj = 0; jj < 8; ++jj) {
            const float p = __expf(sv[jj] - m);
            l += p;
            const float* vr = &Vs[(j0 + jj) * 16];
            const float4 v0 = *reinterpret_cast<const float4*>(vr);
            const float4 v1 = *reinterpret_cast<const float4*>(vr + 4);
            const float4 v2 = *reinterpret_cast<const float4*>(vr + 8);
            const float4 v3 = *reinterpret_cast<const float4*>(vr + 12);
            O[0]  += p * v0.x; O[1]  += p * v0.y; O[2]  += p * v0.z; O[3]  += p * v0.w;
            O[4]  += p * v1.x; O[5]  += p * v1.y; O[6]  += p * v1.z; O[7]  += p * v1.w;
            O[8]  += p * v2.x; O[9]  += p * v2.y; O[10] += p * v2.z; O[11] += p * v2.w;
            O[12] += p * v3.x; O[13] += p * v3.y; O[14] += p * v3.z; O[15] += p * v3.w;
        }
    }

    const int pidx = ((chunk * H_HEADS + head) << 10) + qrow;
    pm[pidx] = m;
    pl[pidx] = l;
    #pragma unroll
    for (int d = 0; d < 16; d += 4)
        *reinterpret_cast<float4*>(&po[(size_t)pidx * 16 + d]) =
            make_float4(O[d], O[d + 1], O[d + 2], O[d + 3]);
}

// ---------------------------------------------------------------------------
// tail1: comb + Wo + residual + LN1 + FF1 + FF2-partial. grid (64, FF2_KS)
// = 256 blocks x 512 thr (8 waves -> 2 waves/SIMD). LDS ~34 KB.
// ---------------------------------------------------------------------------
__global__ __launch_bounds__(512) void tail1_kernel(
    const float* __restrict__ pm, const float* __restrict__ pl,
    const float* __restrict__ po,
    const __hip_bfloat16* __restrict__ Wo_i, const float* __restrict__ bo_i,
    const float* __restrict__ x_in, float* __restrict__ x2,
    const float* __restrict__ g, const float* __restrict__ b,
    const __hip_bfloat16* __restrict__ W1_i, const float* __restrict__ b1_i,
    const __hip_bfloat16* __restrict__ W2_i, float* __restrict__ P)
{
    __shared__ __hip_bfloat16 att[16][136];     // combined attn rows (bf16)
    __shared__ float lds_wo[16][132];           // Wo output (f32)
    __shared__ __hip_bfloat16 xb[16][136];      // post-LN1 rows (bf16)
    __shared__ __hip_bfloat16 h[16][FF_KC + 8]; // FF1 output (bf16)

    const int t    = threadIdx.x;
    const int wave = t >> 6;
    const int lane = t & 63;
    const int lr   = lane & 15;
    const int lk   = (lane >> 4) * 8;
    const int m0   = blockIdx.x * 16;
    const int kb   = blockIdx.y * FF_KC;

    // ---- A: combine attention partials (128 units x 4 thr, 4 elems each) ----
    {
        const int unit = t >> 2;              // 0..127 = (rloc, head)
        const int rloc = unit >> 3;
        const int head = unit & 7;
        const int row  = m0 + rloc;
        const int d0   = (t & 3) * 4;

        float mg = -INFINITY;
        #pragma unroll
        for (int c = 0; c < ATT_KS; ++c)
            mg = fmaxf(mg, pm[((c * H_HEADS + head) << 10) + row]);
        float lg = 0.f;
        float O[4];
        #pragma unroll
        for (int d = 0; d < 4; ++d) O[d] = 0.f;
        #pragma unroll
        for (int c = 0; c < ATT_KS; ++c) {
            const int pidx = ((c * H_HEADS + head) << 10) + row;
            const float w = __expf(pm[pidx] - mg);
            lg += pl[pidx] * w;
            const float4 a0 = *reinterpret_cast<const float4*>(&po[(size_t)pidx * 16 + d0]);
            O[0] += w * a0.x; O[1] += w * a0.y; O[2] += w * a0.z; O[3] += w * a0.w;
        }
        const float inv = 1.f / lg;
        #pragma unroll
        for (int d = 0; d < 4; ++d)
            att[rloc][head * 16 + d0 + d] = __float2bfloat16(O[d] * inv);
    }
    __syncthreads();

    // ---- B: Wo (8 col-units of 16 over 8 waves = 1 round) ----
    {
        const int n0 = wave * 16;
        f32x4 acc = {};
        const __hip_bfloat16* Wp = Wo_i + (size_t)(n0 + lr) * 128 + lk;
        #pragma unroll
        for (int k = 0; k < 128; k += 32) {
            const bf16x8 a = *reinterpret_cast<const bf16x8*>(&att[lr][lk + k]);
            const bf16x8 bb = *reinterpret_cast<const bf16x8*>(Wp + k);
            acc = __builtin_amdgcn_mfma_f32_16x16x32_bf16(a, bb, acc, 0, 0, 0);
        }
        const int orow = (lane >> 4) * 4;
        const int col  = n0 + lr;
        #pragma unroll
        for (int j = 0; j < 4; ++j)
            lds_wo[orow + j][col] = acc[j];
    }
    __syncthreads();

    // ---- C: residual + LN1 (16 rows over 8 waves = 2 rounds) ----
    #pragma unroll
    for (int rr = 0; rr < 2; ++rr) {
        const int rloc = wave + rr * 8;
        const int d0 = lane * 2;
        const size_t i0 = (size_t)(m0 + rloc) * D_DIM + d0;
        float v0 = x_in[i0]     + lds_wo[rloc][d0]     + bo_i[d0];
        float v1 = x_in[i0 + 1] + lds_wo[rloc][d0 + 1] + bo_i[d0 + 1];
        float s = v0 + v1;
        #pragma unroll
        for (int off = 32; off >= 1; off >>= 1) s += __shfl_xor(s, off);
        const float mu = s * (1.0f / 128.0f);
        const float q0 = v0 - mu, q1 = v1 - mu;
        float qs = q0 * q0 + q1 * q1;
        #pragma unroll
        for (int off = 32; off >= 1; off >>= 1) qs += __shfl_xor(qs, off);
        const float rs = rsqrtf(qs * (1.0f / 128.0f) + LN_EPS);
        const float r0 = q0 * rs * g[d0] + b[d0];
        const float r1 = q1 * rs * g[d0 + 1] + b[d0 + 1];
        x2[i0] = r0;     x2[i0 + 1] = r1;
        xb[rloc][d0] = __float2bfloat16(r0);
        xb[rloc][d0 + 1] = __float2bfloat16(r1);
    }
    __syncthreads();

    // ---- D: FF1 (+bias+ReLU) from LDS xb -> LDS h (16 units / 8 waves) ----
    #pragma unroll
    for (int r = 0; r < 2; ++r) {
        const int n0 = kb + (wave + r * 8) * 32;
        f32x4 acc[2] = {};
        const __hip_bfloat16* Wp = W1_i + (size_t)(n0 + lr) * 128 + lk;
        #pragma unroll
        for (int k = 0; k < 128; k += 32) {
            const bf16x8 a = *reinterpret_cast<const bf16x8*>(&xb[lr][lk + k]);
            #pragma unroll
            for (int nt = 0; nt < 2; ++nt) {
                const bf16x8 bb = *reinterpret_cast<const bf16x8*>(Wp + (size_t)nt * 16 * 128 + k);
                acc[nt] = __builtin_amdgcn_mfma_f32_16x16x32_bf16(a, bb, acc[nt], 0, 0, 0);
            }
        }
        const int orow = (lane >> 4) * 4;
        #pragma unroll
        for (int hh = 0; hh < 2; ++hh) {
            const int colg = n0 + hh * 16 + lr;      // global col (bias)
            const int coll = colg - kb;              // local LDS col
            const float bv = b1_i[colg];
            #pragma unroll
            for (int j = 0; j < 4; ++j)
                h[orow + j][coll] =
                    __float2bfloat16(fmaxf(acc[hh][j] + bv, 0.f));
        }
    }
    __syncthreads();

    // ---- E: FF2 partial [16 x 128], K = FF_KC from LDS -> P[z].
    //      8 col-units of 16 over 8 waves = 1 round, NT=1. ----
    {
        const int n0 = wave * 16;
        f32x4 acc = {};
        const __hip_bfloat16* Wp = W2_i + (size_t)(n0 + lr) * FF_DIM + kb + lk;
        #pragma unroll 4
        for (int k = 0; k < FF_KC; k += 32) {
            const bf16x8 a = *reinterpret_cast<const bf16x8*>(&h[lr][lk + k]);
            const bf16x8 bb = *reinterpret_cast<const bf16x8*>(Wp + k);
            acc = __builtin_amdgcn_mfma_f32_16x16x32_bf16(a, bb, acc, 0, 0, 0);
        }
        float* Pz = P + (size_t)blockIdx.y * (S_LEN * D_DIM);
        const int orow = m0 + (lane >> 4) * 4;
        const int col  = n0 + lr;
        #pragma unroll
        for (int j = 0; j < 4; ++j)
            Pz[(size_t)(orow + j) * D_DIM + col] = acc[j];
    }
}

// ---------------------------------------------------------------------------
// LN2 (+FF2_KS partials + bias) then next-layer QKV (or out-proj if LAST).
// grid (64 m-tiles, NZ) x 256 thr; LN2 front replicated per z (cheap,
// L2-resident); each wave computes one 16x32 MFMA unit from LDS xb.
// NZ=3 (12 units) for QKV; NZ=6 (24 units) for out-proj.
// ---------------------------------------------------------------------------
template<int LAST>
__global__ __launch_bounds__(256) void ln2_qkv_kernel(
    const float* __restrict__ P, const float* __restrict__ b2_i,
    const float* __restrict__ xr, float* __restrict__ xw,
    const float* __restrict__ g, const float* __restrict__ b,
    const __hip_bfloat16* __restrict__ Wn, const float* __restrict__ bn,
    __hip_bfloat16* __restrict__ qkv_bf, float* __restrict__ out)
{
    __shared__ __hip_bfloat16 xb[16][136];

    const int tid  = threadIdx.x;
    const int wave = tid >> 6;
    const int lane = tid & 63;
    const int lr   = lane & 15;
    const int lk   = (lane >> 4) * 8;
    const int m0   = blockIdx.x * 16;

    // ---- LN2: 16 rows over 4 waves = 4 rounds ----
    #pragma unroll
    for (int rr = 0; rr < 4; ++rr) {
        const int rloc = wave + rr * 4;
        const int d0 = lane * 2;
        const size_t i0 = (size_t)(m0 + rloc) * D_DIM + d0;
        float v0 = xr[i0]     + b2_i[d0];
        float v1 = xr[i0 + 1] + b2_i[d0 + 1];
        #pragma unroll
        for (int p = 0; p < FF2_KS; ++p) {
            v0 += P[(size_t)p * (S_LEN * D_DIM) + i0];
            v1 += P[(size_t)p * (S_LEN * D_DIM) + i0 + 1];
        }
        float s = v0 + v1;
        #pragma unroll
        for (int off = 32; off >= 1; off >>= 1) s += __shfl_xor(s, off);
        const float mu = s * (1.0f / 128.0f);
        const float q0 = v0 - mu, q1 = v1 - mu;
        float qs = q0 * q0 + q1 * q1;
        #pragma unroll
        for (int off = 32; off >= 1; off >>= 1) qs += __shfl_xor(qs, off);
        const float rs = rsqrtf(qs * (1.0f / 128.0f) + LN_EPS);
        const float r0 = q0 * rs * g[d0] + b[d0];
        const float r1 = q1 * rs * g[d0 + 1] + b[d0 + 1];
        xw[i0] = r0;     xw[i0 + 1] = r1;      // replicated: identical values
        xb[rloc][d0] = __float2bfloat16(r0);
        xb[rloc][d0 + 1] = __float2bfloat16(r1);
    }
    __syncthreads();

    // ---- one 16x32 MFMA unit per wave, A from LDS ----
    const int unit = blockIdx.y * 4 + wave;   // 0..11 (QKV) or 0..23 (out)
    const int n0 = unit * 32;
    f32x4 acc[2] = {};
    {
        const __hip_bfloat16* Wp = Wn + (size_t)(n0 + lr) * 128 + lk;
        #pragma unroll
        for (int k = 0; k < 128; k += 32) {
            const bf16x8 a = *reinterpret_cast<const bf16x8*>(&xb[lr][lk + k]);
            #pragma unroll
            for (int nt = 0; nt < 2; ++nt) {
                const bf16x8 bb = *reinterpret_cast<const bf16x8*>(Wp + (size_t)nt * 16 * 128 + k);
                acc[nt] = __builtin_amdgcn_mfma_f32_16x16x32_bf16(a, bb, acc[nt], 0, 0, 0);
            }
        }
    }
    const int orow = m0 + (lane >> 4) * 4;
    if (!LAST) {
        #pragma unroll
        for (int h = 0; h < 2; ++h) {
            const int col = n0 + h * 16 + lr;
            const float bv = bn[col];
            #pragma unroll
            for (int j = 0; j < 4; ++j)
                qkv_bf[(size_t)(orow + j) * 384 + col] =
                    __float2bfloat16(acc[h][j] + bv);
        }
    } else {
        #pragma unroll
        for (int h = 0; h < 2; ++h) {
            const int col = n0 + h * 16 + lr;
            const float bv = bn[col];
            #pragma unroll
            for (int j = 0; j < 4; ++j)
                out[(size_t)(orow + j) * HID_DIM + col] = acc[h][j] + bv;
        }
        if (blockIdx.y == 0 && tid < 16)
            out[(size_t)S_LEN * HID_DIM + m0 + tid] = 0.0f;
    }
}

// ---------------------------------------------------------------------------
// Host launch: 14 dispatches.
// ---------------------------------------------------------------------------
extern "C" void kernel_launch(void* const* d_in, const int* in_sizes, int n_in,
                              void* d_out, int out_size, void* d_ws, size_t ws_size,
                              hipStream_t stream)
{
    const int*   shot    = (const int*)  d_in[0];
    const int*   cam     = (const int*)  d_in[1];
    const int*   light   = (const int*)  d_in[2];
    const int*   tone    = (const int*)  d_in[3];
    const int*   rhythm  = (const int*)  d_in[4];
    const int*   trans   = (const int*)  d_in[5];
    const float* motion  = (const float*)d_in[6];
    const float* focus   = (const float*)d_in[7];
    const float* E_shot  = (const float*)d_in[8];
    const float* E_cam   = (const float*)d_in[9];
    const float* E_light = (const float*)d_in[10];
    const float* E_tone  = (const float*)d_in[11];
    const float* E_rhyth = (const float*)d_in[12];
    const float* E_trans = (const float*)d_in[13];
    const float* W_m1    = (const float*)d_in[14];
    const float* b_m1    = (const float*)d_in[15];
    const float* W_m2    = (const float*)d_in[16];
    const float* b_m2    = (const float*)d_in[17];
    const float* W_f     = (const float*)d_in[18];
    const float* b_f     = (const float*)d_in[19];
    const float* pos     = (const float*)d_in[20];
    const float* Wqkv    = (const float*)d_in[21];
    const float* bqkv    = (const float*)d_in[22];
    const float* Wo      = (const float*)d_in[23];
    const float* bo      = (const float*)d_in[24];
    const float* W1      = (const float*)d_in[25];
    const float* b1      = (const float*)d_in[26];
    const float* W2      = (const float*)d_in[27];
    const float* b2      = (const float*)d_in[28];
    const float* ln1_g   = (const float*)d_in[29];
    const float* ln1_b   = (const float*)d_in[30];
    const float* ln2_g   = (const float*)d_in[31];
    const float* ln2_b   = (const float*)d_in[32];
    const float* W_out   = (const float*)d_in[33];
    const float* b_out   = (const float*)d_in[34];

    float* out = (float*)d_out;

    // workspace layout (ws = 256 MiB, ample)
    float* ws = (float*)d_ws;
    float* x  = ws;                                 // 131072 f32 (pre-LN1 residual)
    float* x2 = x + S_LEN * D_DIM;                  // 131072 f32 (post-LN1 residual)
    float* pm = x2 + S_LEN * D_DIM;                 // 131072
    float* pl = pm + ATT_KS * H_HEADS * S_LEN;      // 131072
    float* po = pl + ATT_KS * H_HEADS * S_LEN;      // 2097152
    float* P  = po + (size_t)ATT_KS * H_HEADS * S_LEN * 16; // 4*131072
    __hip_bfloat16* bfb = (__hip_bfloat16*)(P + FF2_KS * S_LEN * D_DIM);
    __hip_bfloat16* wqkv_bf = bfb;                  // [4][384][128]
    __hip_bfloat16* wo_bf   = wqkv_bf + 196608;     // [4][128][128]
    __hip_bfloat16* w1_bf   = wo_bf   + 65536;      // [4][2048][128]
    __hip_bfloat16* w2_bf   = w1_bf   + 1048576;    // [4][128][2048]
    __hip_bfloat16* wout_bf = w2_bf   + 1048576;    // [768][128]
    __hip_bfloat16* x_bf    = wout_bf + 98304;      // [1024][128] (embed only)
    __hip_bfloat16* qkv_bf  = x_bf    + 131072;     // [1024][384]

    // 1) weights -> bf16
    wconv_kernel<<<2400, 256, 0, stream>>>(Wqkv, Wo, W1, W2, W_out, bfb);

    // 2) embed + layer-0 qkv
    embed_qkv_kernel<<<64, 1024, 0, stream>>>(
        shot, cam, light, tone, rhythm, trans, motion, focus,
        E_shot, E_cam, E_light, E_tone, E_rhyth, E_trans,
        W_m1, b_m1, W_m2, b_m2, W_f, b_f, pos,
        wqkv_bf, bqkv, x, x_bf, qkv_bf);

    // 3) layers: 3 dispatches each
    for (int li = 0; li < L_LAYERS; ++li) {
        const __hip_bfloat16* Wo_i = wo_bf + (size_t)li * D_DIM * D_DIM;
        const __hip_bfloat16* W1_i = w1_bf + (size_t)li * FF_DIM * D_DIM;
        const __hip_bfloat16* W2_i = w2_bf + (size_t)li * D_DIM * FF_DIM;
        const float* bo_i = bo + (size_t)li * D_DIM;
        const float* b1_i = b1 + (size_t)li * FF_DIM;
        const float* b2_i = b2 + (size_t)li * D_DIM;
        const float* l1g = ln1_g + (size_t)li * D_DIM;
        const float* l1b = ln1_b + (size_t)li * D_DIM;
        const float* l2g = ln2_g + (size_t)li * D_DIM;
        const float* l2b = ln2_b + (size_t)li * D_DIM;

        attn_part_kernel<<<dim3(ATT_KS, 4, H_HEADS), 256, 0, stream>>>(
            qkv_bf, pm, pl, po);

        tail1_kernel<<<dim3(64, FF2_KS), 512, 0, stream>>>(
            pm, pl, po, Wo_i, bo_i, x, x2, l1g, l1b, W1_i, b1_i, W2_i, P);

        if (li < L_LAYERS - 1) {
            const __hip_bfloat16* Wn = wqkv_bf + (size_t)(li + 1) * 3 * D_DIM * D_DIM;
            const float* bn = bqkv + (size_t)(li + 1) * 3 * D_DIM;
            ln2_qkv_kernel<0><<<dim3(64, 3), 256, 0, stream>>>(
                P, b2_i, x2, x, l2g, l2b, Wn, bn, qkv_bf, nullptr);
        } else {
            ln2_qkv_kernel<1><<<dim3(64, 6), 256, 0, stream>>>(
                P, b2_i, x2, x, l2g, l2b, wout_bf, b_out, nullptr, out);
        }
    }
}

// Round 16
// 133.703 us; speedup vs baseline: 2.0755x; 1.4456x over previous
//
#include <hip/hip_runtime.h>
#include <hip/hip_bf16.h>
#include <cstddef>
#include <math.h>

// ---------------------------------------------------------------------------
// Model constants
// ---------------------------------------------------------------------------
#define S_LEN 1024
#define D_DIM 128
#define H_HEADS 8
#define FF_DIM 2048
#define L_LAYERS 4
#define HID_DIM 768
#define LN_EPS 1e-5f

#define FF2_KS 4                  // FF2 split-K chunks (fused kernel z-dim)
#define FF_KC (FF_DIM / FF2_KS)   // 512 h-cols per fused block

typedef __attribute__((ext_vector_type(8))) short bf16x8;
typedef __attribute__((ext_vector_type(4))) short bf16x4;
typedef __attribute__((ext_vector_type(4))) float f32x4;

// bf16 (as short bits) -> f32 : 16-bit left shift
__device__ __forceinline__ float bf16s_to_f(short s)
{
    return __uint_as_float(((unsigned int)(unsigned short)s) << 16);
}
__device__ __forceinline__ short f_to_bf16s(float v)
{
    __hip_bfloat16 hb = __float2bfloat16(v);
    return *reinterpret_cast<short*>(&hb);
}

// ---------------------------------------------------------------------------
// Wave-level MFMA tile: 16 rows x (NT*16) cols (proven fragment layout:
// A row = l&15, k-offset = (l>>4)*8; C/D row = (l>>4)*4+j, col = l&15).
// ---------------------------------------------------------------------------
template<int NT>
__device__ __forceinline__ void mfma_tile(
    const __hip_bfloat16* __restrict__ A, const __hip_bfloat16* __restrict__ W,
    int K, int m0, int n0, int kbeg, int kend, int lane, f32x4* acc)
{
    const int lr = lane & 15;
    const int lk = (lane >> 4) * 8;
    const __hip_bfloat16* Ap = A + (size_t)(m0 + lr) * K + lk;
    const __hip_bfloat16* Wp = W + (size_t)(n0 + lr) * K + lk;
    #pragma unroll 4
    for (int k = kbeg; k < kend; k += 32) {
        const bf16x8 a = *reinterpret_cast<const bf16x8*>(Ap + k);
        #pragma unroll
        for (int nt = 0; nt < NT; ++nt) {
            const bf16x8 b = *reinterpret_cast<const bf16x8*>(Wp + (size_t)nt * 16 * K + k);
            acc[nt] = __builtin_amdgcn_mfma_f32_16x16x32_bf16(a, b, acc[nt], 0, 0, 0);
        }
    }
}

// ---------------------------------------------------------------------------
// One-shot weight conversion fp32 -> bf16 (concatenated, proven).
// ---------------------------------------------------------------------------
__global__ __launch_bounds__(256) void wconv_kernel(
    const float* __restrict__ Wqkv, const float* __restrict__ Wo,
    const float* __restrict__ W1, const float* __restrict__ W2,
    const float* __restrict__ Wout, __hip_bfloat16* __restrict__ dst)
{
    const int i = blockIdx.x * 256 + threadIdx.x;   // float4 index, 0..614399
    const float* src;
    int off4;
    if (i < 49152)       { src = Wqkv; off4 = i; }
    else if (i < 65536)  { src = Wo;   off4 = i - 49152; }
    else if (i < 327680) { src = W1;   off4 = i - 65536; }
    else if (i < 589824) { src = W2;   off4 = i - 327680; }
    else                 { src = Wout; off4 = i - 589824; }
    const float4 v = reinterpret_cast<const float4*>(src)[off4];
    __hip_bfloat16* o = dst + (size_t)i * 4;
    o[0] = __float2bfloat16(v.x);
    o[1] = __float2bfloat16(v.y);
    o[2] = __float2bfloat16(v.z);
    o[3] = __float2bfloat16(v.w);
}

// ---------------------------------------------------------------------------
// embed + layer-0 QKV, fused (proven). 64 blocks x 1024 thr.
// ---------------------------------------------------------------------------
__global__ __launch_bounds__(1024, 1) void embed_qkv_kernel(
    const int* __restrict__ shot, const int* __restrict__ cam,
    const int* __restrict__ light, const int* __restrict__ tone,
    const int* __restrict__ rhythm, const int* __restrict__ trans,
    const float* __restrict__ motion, const float* __restrict__ focus,
    const float* __restrict__ E_shot, const float* __restrict__ E_cam,
    const float* __restrict__ E_light, const float* __restrict__ E_tone,
    const float* __restrict__ E_rhythm, const float* __restrict__ E_trans,
    const float* __restrict__ W_m1, const float* __restrict__ b_m1,
    const float* __restrict__ W_m2, const float* __restrict__ b_m2,
    const float* __restrict__ W_f, const float* __restrict__ b_f,
    const float* __restrict__ pos,
    const __hip_bfloat16* __restrict__ Wqkv0, const float* __restrict__ bqkv0,
    float* __restrict__ x, __hip_bfloat16* __restrict__ x_bf,
    __hip_bfloat16* __restrict__ qkv_bf)
{
    const int blk = blockIdx.x;
    const int tid = threadIdx.x;
    const int m0  = blk * 16;

    for (int e = tid; e < 16 * D_DIM; e += 1024) {
        const int s = m0 + (e >> 7);
        const int d = e & 127;
        const float4 mp = *reinterpret_cast<const float4*>(motion + s * 4);
        const float f0 = focus[s * 2 + 0], f1 = focus[s * 2 + 1];
        float acc = b_m2[d];
        const float* w2row = W_m2 + (size_t)d * 64;
        #pragma unroll 8
        for (int k2 = 0; k2 < 64; ++k2) {
            const float hk = b_m1[k2]
                + W_m1[k2 * 4 + 0] * mp.x + W_m1[k2 * 4 + 1] * mp.y
                + W_m1[k2 * 4 + 2] * mp.z + W_m1[k2 * 4 + 3] * mp.w;
            acc += w2row[k2] * fmaxf(hk, 0.0f);
        }
        acc += b_f[d] + W_f[d * 2 + 0] * f0 + W_f[d * 2 + 1] * f1;
        acc += E_shot  [(size_t)shot[s]   * D_DIM + d];
        acc += E_cam   [(size_t)cam[s]    * D_DIM + d];
        acc += E_light [(size_t)light[s]  * D_DIM + d];
        acc += E_tone  [(size_t)tone[s]   * D_DIM + d];
        acc += E_rhythm[(size_t)rhythm[s] * D_DIM + d];
        acc += E_trans [(size_t)trans[s]  * D_DIM + d];
        acc += pos[(size_t)s * D_DIM + d];
        const size_t gi = (size_t)s * D_DIM + d;
        x[gi] = acc;
        x_bf[gi] = __float2bfloat16(acc);
    }
    __syncthreads();

    const int wave = tid >> 6, lane = tid & 63;
    for (int u = wave; u < 12; u += 16) {
        const int n0 = u * 32;
        f32x4 acc[2] = {};
        mfma_tile<2>(x_bf, Wqkv0, 128, m0, n0, 0, 128, lane, acc);
        const int orow = m0 + (lane >> 4) * 4;
        #pragma unroll
        for (int h = 0; h < 2; ++h) {
            const int col = n0 + h * 16 + (lane & 15);
            const float bv = bqkv0[col];
            #pragma unroll
            for (int j = 0; j < 4; ++j)
                qkv_bf[(size_t)(orow + j) * 384 + col] =
                    __float2bfloat16(acc[h][j] + bv);
        }
    }
}

// ---------------------------------------------------------------------------
// MFMA attention (swapped QK^T, 16x16x32 intrinsic only).
// grid (64 q-tiles, 8 heads) = 512 blk x 256 thr (4 waves). Wave w owns keys
// [w*256, w*256+256) in 8 chunks of 32.
// QK: dh padded 16->32 (lanes lg>=2 hold zeros); two MFMAs per chunk give
// s[j]=S[key=lg*4+j][q=lq] for keys kb..kb+15 / kb+16..kb+31.
// PV: one K=32 MFMA per chunk; P routed through per-wave LDS tile
// pt[q][40] (stride 80B, 16B-aligned b128 reads) to match the A-fragment
// layout P[q=lq][key=lg*8+j]; V^T B-frag via coalescing scalar loads.
// Online softmax: xor-16/32 column reduce; O-rescale via shfl(corr, q').
// Final 4-wave merge via LDS -> attn_bf.
// ---------------------------------------------------------------------------
__global__ __launch_bounds__(256) void attn_mfma_kernel(
    const __hip_bfloat16* __restrict__ qkv, __hip_bfloat16* __restrict__ attn_bf)
{
    __shared__ __hip_bfloat16 pt[4][16][40];   // per-wave P tile [q][32+pad]
    __shared__ float mlds[4][2][16];
    __shared__ float Olds[4][16][17];

    const int t  = threadIdx.x;
    const int w  = t >> 6;
    const int l  = t & 63;
    const int qt = blockIdx.x;      // 16 q-rows each
    const int h  = blockIdx.y;
    const int lq = l & 15;
    const int lg = l >> 4;

    // Q B-frag (dh padded to 32): lanes lg<2 hold Q[q=lq][dh=lg*8+j] * 0.25
    bf16x8 qf = {};
    if (lg < 2) {
        const bf16x8 raw = *reinterpret_cast<const bf16x8*>(
            qkv + (size_t)(qt * 16 + lq) * 384 + h * 16 + lg * 8);
        #pragma unroll
        for (int j = 0; j < 8; ++j)
            qf[j] = f_to_bf16s(bf16s_to_f(raw[j]) * 0.25f);   // exact (pow2)
    }

    float m = -INFINITY, lsum = 0.f;
    f32x4 O = {0.f, 0.f, 0.f, 0.f};
    const f32x4 zero = {0.f, 0.f, 0.f, 0.f};

    const int kw = w * 256;
    for (int ch = 0; ch < 8; ++ch) {
        const int kb = kw + ch * 32;

        // K A-frags for the two 16-key tiles (dh padded to 32)
        bf16x8 kf0 = {}, kf1 = {};
        if (lg < 2) {
            kf0 = *reinterpret_cast<const bf16x8*>(
                qkv + (size_t)(kb + lq) * 384 + 128 + h * 16 + lg * 8);
            kf1 = *reinterpret_cast<const bf16x8*>(
                qkv + (size_t)(kb + 16 + lq) * 384 + 128 + h * 16 + lg * 8);
        }
        const f32x4 s0 = __builtin_amdgcn_mfma_f32_16x16x32_bf16(kf0, qf, zero, 0, 0, 0);
        const f32x4 s1 = __builtin_amdgcn_mfma_f32_16x16x32_bf16(kf1, qf, zero, 0, 0, 0);
        // s0[j] = S[key=kb+lg*4+j][q=lq]; s1[j] = same at +16

        // online softmax (column q = lq; spread across lg -> xor 16/32)
        float tm = fmaxf(fmaxf(s0[0], s0[1]), fmaxf(s0[2], s0[3]));
        tm = fmaxf(tm, fmaxf(fmaxf(s1[0], s1[1]), fmaxf(s1[2], s1[3])));
        tm = fmaxf(tm, __shfl_xor(tm, 16));
        tm = fmaxf(tm, __shfl_xor(tm, 32));
        const float mn = fmaxf(m, tm);
        const float corr = __expf(m - mn);
        m = mn;

        float p0[4], p1[4], ts = 0.f;
        #pragma unroll
        for (int j = 0; j < 4; ++j) {
            p0[j] = __expf(s0[j] - m);
            p1[j] = __expf(s1[j] - m);
            ts += p0[j] + p1[j];
        }
        ts += __shfl_xor(ts, 16);
        ts += __shfl_xor(ts, 32);
        lsum = lsum * corr + ts;

        // P -> LDS [q][key] (bf16), then read back as PV A-frag
        #pragma unroll
        for (int j = 0; j < 4; ++j) {
            pt[w][lq][lg * 4 + j]      = __float2bfloat16(p0[j]);
            pt[w][lq][16 + lg * 4 + j] = __float2bfloat16(p1[j]);
        }
        const bf16x8 pa = *reinterpret_cast<const bf16x8*>(&pt[w][lq][lg * 8]);

        // V^T B-frag: lane holds V[key=kb+lg*8+j][dh=lq]
        bf16x8 vf;
        #pragma unroll
        for (int j = 0; j < 8; ++j)
            vf[j] = *reinterpret_cast<const short*>(
                qkv + (size_t)(kb + lg * 8 + j) * 384 + 256 + h * 16 + lq);

        // rescale O rows (row q' = lg*4+j) by corr[q']
        #pragma unroll
        for (int j = 0; j < 4; ++j)
            O[j] *= __shfl(corr, lg * 4 + j);

        O = __builtin_amdgcn_mfma_f32_16x16x32_bf16(pa, vf, O, 0, 0, 0);
        // O[j] = O[q'=lg*4+j][dh=lq]
    }

    // wave partials
    if (l < 16) { mlds[w][0][l] = m; mlds[w][1][l] = lsum; }
    #pragma unroll
    for (int j = 0; j < 4; ++j)
        Olds[w][lg * 4 + j][lq] = O[j];
    __syncthreads();

    // merge: thread t -> (q = t>>4, dh = t&15)
    {
        const int q = t >> 4, dh = t & 15;
        float mg = -INFINITY;
        #pragma unroll
        for (int ww = 0; ww < 4; ++ww) mg = fmaxf(mg, mlds[ww][0][q]);
        float lg2 = 0.f, ov = 0.f;
        #pragma unroll
        for (int ww = 0; ww < 4; ++ww) {
            const float wgt = __expf(mlds[ww][0][q] - mg);
            lg2 += mlds[ww][1][q] * wgt;
            ov  += wgt * Olds[ww][q][dh];
        }
        attn_bf[(size_t)(qt * 16 + q) * D_DIM + h * 16 + dh] =
            __float2bfloat16(ov / lg2);
    }
}

// ---------------------------------------------------------------------------
// tail1: load attn rows + Wo + residual + LN1 + FF1 + FF2-partial.
// grid (64, FF2_KS) = 256 blocks x 512 thr (8 waves). LDS ~34 KB.
// ---------------------------------------------------------------------------
__global__ __launch_bounds__(512) void tail1_kernel(
    const __hip_bfloat16* __restrict__ attn_g,
    const __hip_bfloat16* __restrict__ Wo_i, const float* __restrict__ bo_i,
    const float* __restrict__ x_in, float* __restrict__ x2,
    const float* __restrict__ g, const float* __restrict__ b,
    const __hip_bfloat16* __restrict__ W1_i, const float* __restrict__ b1_i,
    const __hip_bfloat16* __restrict__ W2_i, float* __restrict__ P)
{
    __shared__ __hip_bfloat16 att[16][136];     // attn rows (bf16)
    __shared__ float lds_wo[16][132];           // Wo output (f32)
    __shared__ __hip_bfloat16 xb[16][136];      // post-LN1 rows (bf16)
    __shared__ __hip_bfloat16 h[16][FF_KC + 8]; // FF1 output (bf16)

    const int t    = threadIdx.x;
    const int wave = t >> 6;
    const int lane = t & 63;
    const int lr   = lane & 15;
    const int lk   = (lane >> 4) * 8;
    const int m0   = blockIdx.x * 16;
    const int kb   = blockIdx.y * FF_KC;

    // ---- A: load attn rows (16 x 128 bf16, 4 per thread) ----
    {
        const int e    = t * 4;          // 0..2044
        const int rloc = e >> 7;
        const int col  = e & 127;
        *reinterpret_cast<bf16x4*>(&att[rloc][col]) =
            *reinterpret_cast<const bf16x4*>(
                attn_g + (size_t)(m0 + rloc) * D_DIM + col);
    }
    __syncthreads();

    // ---- B: Wo (8 col-units of 16 over 8 waves = 1 round) ----
    {
        const int n0 = wave * 16;
        f32x4 acc = {};
        const __hip_bfloat16* Wp = Wo_i + (size_t)(n0 + lr) * 128 + lk;
        #pragma unroll
        for (int k = 0; k < 128; k += 32) {
            const bf16x8 a = *reinterpret_cast<const bf16x8*>(&att[lr][lk + k]);
            const bf16x8 bb = *reinterpret_cast<const bf16x8*>(Wp + k);
            acc = __builtin_amdgcn_mfma_f32_16x16x32_bf16(a, bb, acc, 0, 0, 0);
        }
        const int orow = (lane >> 4) * 4;
        const int col  = n0 + lr;
        #pragma unroll
        for (int j = 0; j < 4; ++j)
            lds_wo[orow + j][col] = acc[j];
    }
    __syncthreads();

    // ---- C: residual + LN1 (16 rows over 8 waves = 2 rounds) ----
    #pragma unroll
    for (int rr = 0; rr < 2; ++rr) {
        const int rloc = wave + rr * 8;
        const int d0 = lane * 2;
        const size_t i0 = (size_t)(m0 + rloc) * D_DIM + d0;
        float v0 = x_in[i0]     + lds_wo[rloc][d0]     + bo_i[d0];
        float v1 = x_in[i0 + 1] + lds_wo[rloc][d0 + 1] + bo_i[d0 + 1];
        float s = v0 + v1;
        #pragma unroll
        for (int off = 32; off >= 1; off >>= 1) s += __shfl_xor(s, off);
        const float mu = s * (1.0f / 128.0f);
        const float q0 = v0 - mu, q1 = v1 - mu;
        float qs = q0 * q0 + q1 * q1;
        #pragma unroll
        for (int off = 32; off >= 1; off >>= 1) qs += __shfl_xor(qs, off);
        const float rs = rsqrtf(qs * (1.0f / 128.0f) + LN_EPS);
        const float r0 = q0 * rs * g[d0] + b[d0];
        const float r1 = q1 * rs * g[d0 + 1] + b[d0 + 1];
        x2[i0] = r0;     x2[i0 + 1] = r1;
        xb[rloc][d0] = __float2bfloat16(r0);
        xb[rloc][d0 + 1] = __float2bfloat16(r1);
    }
    __syncthreads();

    // ---- D: FF1 (+bias+ReLU) from LDS xb -> LDS h (16 units / 8 waves) ----
    #pragma unroll
    for (int r = 0; r < 2; ++r) {
        const int n0 = kb + (wave + r * 8) * 32;
        f32x4 acc[2] = {};
        const __hip_bfloat16* Wp = W1_i + (size_t)(n0 + lr) * 128 + lk;
        #pragma unroll
        for (int k = 0; k < 128; k += 32) {
            const bf16x8 a = *reinterpret_cast<const bf16x8*>(&xb[lr][lk + k]);
            #pragma unroll
            for (int nt = 0; nt < 2; ++nt) {
                const bf16x8 bb = *reinterpret_cast<const bf16x8*>(Wp + (size_t)nt * 16 * 128 + k);
                acc[nt] = __builtin_amdgcn_mfma_f32_16x16x32_bf16(a, bb, acc[nt], 0, 0, 0);
            }
        }
        const int orow = (lane >> 4) * 4;
        #pragma unroll
        for (int hh = 0; hh < 2; ++hh) {
            const int colg = n0 + hh * 16 + lr;      // global col (bias)
            const int coll = colg - kb;              // local LDS col
            const float bv = b1_i[colg];
            #pragma unroll
            for (int j = 0; j < 4; ++j)
                h[orow + j][coll] =
                    __float2bfloat16(fmaxf(acc[hh][j] + bv, 0.f));
        }
    }
    __syncthreads();

    // ---- E: FF2 partial [16 x 128], K = FF_KC from LDS -> P[z] ----
    {
        const int n0 = wave * 16;
        f32x4 acc = {};
        const __hip_bfloat16* Wp = W2_i + (size_t)(n0 + lr) * FF_DIM + kb + lk;
        #pragma unroll 4
        for (int k = 0; k < FF_KC; k += 32) {
            const bf16x8 a = *reinterpret_cast<const bf16x8*>(&h[lr][lk + k]);
            const bf16x8 bb = *reinterpret_cast<const bf16x8*>(Wp + k);
            acc = __builtin_amdgcn_mfma_f32_16x16x32_bf16(a, bb, acc, 0, 0, 0);
        }
        float* Pz = P + (size_t)blockIdx.y * (S_LEN * D_DIM);
        const int orow = m0 + (lane >> 4) * 4;
        const int col  = n0 + lr;
        #pragma unroll
        for (int j = 0; j < 4; ++j)
            Pz[(size_t)(orow + j) * D_DIM + col] = acc[j];
    }
}

// ---------------------------------------------------------------------------
// LN2 (+FF2_KS partials + bias) then next-layer QKV (or out-proj if LAST).
// grid (64 m-tiles, NZ) x 256 thr (proven R14).
// ---------------------------------------------------------------------------
template<int LAST>
__global__ __launch_bounds__(256) void ln2_qkv_kernel(
    const float* __restrict__ P, const float* __restrict__ b2_i,
    const float* __restrict__ xr, float* __restrict__ xw,
    const float* __restrict__ g, const float* __restrict__ b,
    const __hip_bfloat16* __restrict__ Wn, const float* __restrict__ bn,
    __hip_bfloat16* __restrict__ qkv_bf, float* __restrict__ out)
{
    __shared__ __hip_bfloat16 xb[16][136];

    const int tid  = threadIdx.x;
    const int wave = tid >> 6;
    const int lane = tid & 63;
    const int lr   = lane & 15;
    const int lk   = (lane >> 4) * 8;
    const int m0   = blockIdx.x * 16;

    // ---- LN2: 16 rows over 4 waves = 4 rounds ----
    #pragma unroll
    for (int rr = 0; rr < 4; ++rr) {
        const int rloc = wave + rr * 4;
        const int d0 = lane * 2;
        const size_t i0 = (size_t)(m0 + rloc) * D_DIM + d0;
        float v0 = xr[i0]     + b2_i[d0];
        float v1 = xr[i0 + 1] + b2_i[d0 + 1];
        #pragma unroll
        for (int p = 0; p < FF2_KS; ++p) {
            v0 += P[(size_t)p * (S_LEN * D_DIM) + i0];
            v1 += P[(size_t)p * (S_LEN * D_DIM) + i0 + 1];
        }
        float s = v0 + v1;
        #pragma unroll
        for (int off = 32; off >= 1; off >>= 1) s += __shfl_xor(s, off);
        const float mu = s * (1.0f / 128.0f);
        const float q0 = v0 - mu, q1 = v1 - mu;
        float qs = q0 * q0 + q1 * q1;
        #pragma unroll
        for (int off = 32; off >= 1; off >>= 1) qs += __shfl_xor(qs, off);
        const float rs = rsqrtf(qs * (1.0f / 128.0f) + LN_EPS);
        const float r0 = q0 * rs * g[d0] + b[d0];
        const float r1 = q1 * rs * g[d0 + 1] + b[d0 + 1];
        xw[i0] = r0;     xw[i0 + 1] = r1;      // replicated: identical values
        xb[rloc][d0] = __float2bfloat16(r0);
        xb[rloc][d0 + 1] = __float2bfloat16(r1);
    }
    __syncthreads();

    // ---- one 16x32 MFMA unit per wave, A from LDS ----
    const int unit = blockIdx.y * 4 + wave;   // 0..11 (QKV) or 0..23 (out)
    const int n0 = unit * 32;
    f32x4 acc[2] = {};
    {
        const __hip_bfloat16* Wp = Wn + (size_t)(n0 + lr) * 128 + lk;
        #pragma unroll
        for (int k = 0; k < 128; k += 32) {
            const bf16x8 a = *reinterpret_cast<const bf16x8*>(&xb[lr][lk + k]);
            #pragma unroll
            for (int nt = 0; nt < 2; ++nt) {
                const bf16x8 bb = *reinterpret_cast<const bf16x8*>(Wp + (size_t)nt * 16 * 128 + k);
                acc[nt] = __builtin_amdgcn_mfma_f32_16x16x32_bf16(a, bb, acc[nt], 0, 0, 0);
            }
        }
    }
    const int orow = m0 + (lane >> 4) * 4;
    if (!LAST) {
        #pragma unroll
        for (int h = 0; h < 2; ++h) {
            const int col = n0 + h * 16 + lr;
            const float bv = bn[col];
            #pragma unroll
            for (int j = 0; j < 4; ++j)
                qkv_bf[(size_t)(orow + j) * 384 + col] =
                    __float2bfloat16(acc[h][j] + bv);
        }
    } else {
        #pragma unroll
        for (int h = 0; h < 2; ++h) {
            const int col = n0 + h * 16 + lr;
            const float bv = bn[col];
            #pragma unroll
            for (int j = 0; j < 4; ++j)
                out[(size_t)(orow + j) * HID_DIM + col] = acc[h][j] + bv;
        }
        if (blockIdx.y == 0 && tid < 16)
            out[(size_t)S_LEN * HID_DIM + m0 + tid] = 0.0f;
    }
}

// ---------------------------------------------------------------------------
// Host launch: 14 dispatches.
// ---------------------------------------------------------------------------
extern "C" void kernel_launch(void* const* d_in, const int* in_sizes, int n_in,
                              void* d_out, int out_size, void* d_ws, size_t ws_size,
                              hipStream_t stream)
{
    const int*   shot    = (const int*)  d_in[0];
    const int*   cam     = (const int*)  d_in[1];
    const int*   light   = (const int*)  d_in[2];
    const int*   tone    = (const int*)  d_in[3];
    const int*   rhythm  = (const int*)  d_in[4];
    const int*   trans   = (const int*)  d_in[5];
    const float* motion  = (const float*)d_in[6];
    const float* focus   = (const float*)d_in[7];
    const float* E_shot  = (const float*)d_in[8];
    const float* E_cam   = (const float*)d_in[9];
    const float* E_light = (const float*)d_in[10];
    const float* E_tone  = (const float*)d_in[11];
    const float* E_rhyth = (const float*)d_in[12];
    const float* E_trans = (const float*)d_in[13];
    const float* W_m1    = (const float*)d_in[14];
    const float* b_m1    = (const float*)d_in[15];
    const float* W_m2    = (const float*)d_in[16];
    const float* b_m2    = (const float*)d_in[17];
    const float* W_f     = (const float*)d_in[18];
    const float* b_f     = (const float*)d_in[19];
    const float* pos     = (const float*)d_in[20];
    const float* Wqkv    = (const float*)d_in[21];
    const float* bqkv    = (const float*)d_in[22];
    const float* Wo      = (const float*)d_in[23];
    const float* bo      = (const float*)d_in[24];
    const float* W1      = (const float*)d_in[25];
    const float* b1      = (const float*)d_in[26];
    const float* W2      = (const float*)d_in[27];
    const float* b2      = (const float*)d_in[28];
    const float* ln1_g   = (const float*)d_in[29];
    const float* ln1_b   = (const float*)d_in[30];
    const float* ln2_g   = (const float*)d_in[31];
    const float* ln2_b   = (const float*)d_in[32];
    const float* W_out   = (const float*)d_in[33];
    const float* b_out   = (const float*)d_in[34];

    float* out = (float*)d_out;

    // workspace layout (ws = 256 MiB, ample)
    float* ws = (float*)d_ws;
    float* x  = ws;                                 // 131072 f32 (pre-LN1 residual)
    float* x2 = x + S_LEN * D_DIM;                  // 131072 f32 (post-LN1 residual)
    float* P  = x2 + S_LEN * D_DIM;                 // 4*131072 (FF2 partials)
    __hip_bfloat16* bfb = (__hip_bfloat16*)(P + FF2_KS * S_LEN * D_DIM);
    __hip_bfloat16* wqkv_bf = bfb;                  // [4][384][128]
    __hip_bfloat16* wo_bf   = wqkv_bf + 196608;     // [4][128][128]
    __hip_bfloat16* w1_bf   = wo_bf   + 65536;      // [4][2048][128]
    __hip_bfloat16* w2_bf   = w1_bf   + 1048576;    // [4][128][2048]
    __hip_bfloat16* wout_bf = w2_bf   + 1048576;    // [768][128]
    __hip_bfloat16* x_bf    = wout_bf + 98304;      // [1024][128] (embed only)
    __hip_bfloat16* qkv_bf  = x_bf    + 131072;     // [1024][384]
    __hip_bfloat16* attn_bf = qkv_bf  + 393216;     // [1024][128]

    // 1) weights -> bf16
    wconv_kernel<<<2400, 256, 0, stream>>>(Wqkv, Wo, W1, W2, W_out, bfb);

    // 2) embed + layer-0 qkv
    embed_qkv_kernel<<<64, 1024, 0, stream>>>(
        shot, cam, light, tone, rhythm, trans, motion, focus,
        E_shot, E_cam, E_light, E_tone, E_rhyth, E_trans,
        W_m1, b_m1, W_m2, b_m2, W_f, b_f, pos,
        wqkv_bf, bqkv, x, x_bf, qkv_bf);

    // 3) layers: 3 dispatches each
    for (int li = 0; li < L_LAYERS; ++li) {
        const __hip_bfloat16* Wo_i = wo_bf + (size_t)li * D_DIM * D_DIM;
        const __hip_bfloat16* W1_i = w1_bf + (size_t)li * FF_DIM * D_DIM;
        const __hip_bfloat16* W2_i = w2_bf + (size_t)li * D_DIM * FF_DIM;
        const float* bo_i = bo + (size_t)li * D_DIM;
        const float* b1_i = b1 + (size_t)li * FF_DIM;
        const float* b2_i = b2 + (size_t)li * D_DIM;
        const float* l1g = ln1_g + (size_t)li * D_DIM;
        const float* l1b = ln1_b + (size_t)li * D_DIM;
        const float* l2g = ln2_g + (size_t)li * D_DIM;
        const float* l2b = ln2_b + (size_t)li * D_DIM;

        attn_mfma_kernel<<<dim3(64, H_HEADS), 256, 0, stream>>>(qkv_bf, attn_bf);

        tail1_kernel<<<dim3(64, FF2_KS), 512, 0, stream>>>(
            attn_bf, Wo_i, bo_i, x, x2, l1g, l1b, W1_i, b1_i, W2_i, P);

        if (li < L_LAYERS - 1) {
            const __hip_bfloat16* Wn = wqkv_bf + (size_t)(li + 1) * 3 * D_DIM * D_DIM;
            const float* bn = bqkv + (size_t)(li + 1) * 3 * D_DIM;
            ln2_qkv_kernel<0><<<dim3(64, 3), 256, 0, stream>>>(
                P, b2_i, x2, x, l2g, l2b, Wn, bn, qkv_bf, nullptr);
        } else {
            ln2_qkv_kernel<1><<<dim3(64, 6), 256, 0, stream>>>(
                P, b2_i, x2, x, l2g, l2b, wout_bf, b_out, nullptr, out);
        }
    }
}